// Round 2
// baseline (25358.597 us; speedup 1.0000x reference)
//
#include <hip/hip_runtime.h>

// ---------------- config (mirrors reference) ----------------
constexpr int NB_  = 64;    // batch
constexpr int CC   = 3;     // image channels
constexpr int IMG  = 64;    // image H=W
constexpr int Z1c  = 64;
constexpr int Z2c  = 128;
constexpr int HIDc = 128;
constexpr int S1c  = 16;    // level-1 spatial
constexpr int S2c  = 8;     // level-2 spatial
constexpr int MAXS = 12;
constexpr int MINS = 3;
constexpr float THRESH_ = 1e-3f;
constexpr float ALPHA_  = 0.1f;
constexpr float CLIP_   = 1.0f;

// tensor element counts
constexpr int N_L1 = NB_ * Z1c * S1c * S1c;   // 1,048,576
constexpr int N_L2 = NB_ * Z2c * S2c * S2c;   //   524,288
constexpr int N_FR = NB_ * CC * IMG * IMG;    //   786,432
constexpr int N_G1 = NB_ * HIDc * S1c * S1c;  // 2,097,152
constexpr int N_G2 = NB_ * HIDc * S2c * S2c;  //   524,288

// partial-sum grid sizes
constexpr int GRID_DEC = NB_ * CC * 16;       // 3072 (decode: 16 blocks per (b,c) plane)
constexpr int GRID_P1  = NB_ * Z1c;           // 4096 (16x16 convs, COUT=Z1)
constexpr int GRID_P2  = (NB_ / 4) * Z2c;     // 2048 (8x8 convs, COUT=Z2, 4 batches/block)

// ---------------- helpers ----------------
__device__ __forceinline__ void block_reduce_write(float v, float* dst) {
    __shared__ float sd[256];
    sd[threadIdx.x] = v;
    __syncthreads();
#pragma unroll
    for (int off = 128; off > 0; off >>= 1) {
        if (threadIdx.x < off) sd[threadIdx.x] += sd[threadIdx.x + off];
        __syncthreads();
    }
    if (threadIdx.x == 0) *dst = sd[0];
}

// ---------------- kernels ----------------

// init scalar state
__global__ void init_k(float* prev_e, int* conv, int* iters) {
    prev_e[0] = 1e30f;
    conv[0] = 0;
    iters[0] = 0;
}

// encode: [B,3,64,64] --conv 4x4 stride4 VALID--> [B,64,16,16]
// block = one (b,co) 16x16 plane, 256 threads
__global__ __launch_bounds__(256) void encode_k(const float* __restrict__ in,
                                                const float* __restrict__ w,
                                                const float* __restrict__ bias,
                                                float* __restrict__ out) {
    const int co = blockIdx.x % Z1c;
    const int b  = blockIdx.x / Z1c;
    const int y = threadIdx.x >> 4, x = threadIdx.x & 15;
    float acc = bias[co];
    const float* wc = w + co * CC * 16;
    for (int ci = 0; ci < CC; ++ci) {
        const float* ip = in + ((size_t)(b * CC + ci) * IMG + y * 4) * IMG + x * 4;
#pragma unroll
        for (int ky = 0; ky < 4; ++ky)
#pragma unroll
            for (int kx = 0; kx < 4; ++kx)
                acc = fmaf(ip[ky * IMG + kx], wc[ci * 16 + ky * 4 + kx], acc);
    }
    out[((b * Z1c + co) * S1c + y) * S1c + x] = acc;
}

// downsample: [B,64,16,16] --conv 3x3 stride2 SAME--> [B,128,8,8], writes 2 copies
// block = 4 batches x one co (4*64=256 threads)
__global__ __launch_bounds__(256) void down_k(const float* __restrict__ in,
                                              const float* __restrict__ w,
                                              const float* __restrict__ bias,
                                              float* __restrict__ out1,
                                              float* __restrict__ out2) {
    const int co = blockIdx.x % Z2c;
    const int bg = blockIdx.x / Z2c;
    const int bl = threadIdx.x >> 6;
    const int pos = threadIdx.x & 63;
    const int b = bg * 4 + bl;
    const int y = pos >> 3, x = pos & 7;
    float acc = bias[co];
    const float* wc = w + co * Z1c * 9;
    for (int ci = 0; ci < Z1c; ++ci) {
        const float* ip = in + (size_t)(b * Z1c + ci) * 256;
        float wv[9];
#pragma unroll
        for (int t = 0; t < 9; ++t) wv[t] = wc[t];
#pragma unroll
        for (int dy = 0; dy < 3; ++dy) {
            const int yy = 2 * y + dy;          // SAME stride2: pad_lo = 0
            if (yy < 16) {
#pragma unroll
                for (int dx = 0; dx < 3; ++dx) {
                    const int xx = 2 * x + dx;
                    if (xx < 16) acc = fmaf(ip[yy * 16 + xx], wv[dy * 3 + dx], acc);
                }
            }
        }
        wc += 9;
    }
    const int oidx = ((b * Z2c + co) * S2c + y) * S2c + x;
    out1[oidx] = acc;
    out2[oidx] = acc;
}

// decode: up(l1p,4) + conv 3x3 SAME @64x64, Z1->3. Fused: ef = frame_next - fp.
// grid = B*3*16, block 256 (16 blocks per (b,c) 4096-px plane)
template <bool TAIL>
__global__ __launch_bounds__(256) void decode_k(const float* __restrict__ l1,
                                                const float* __restrict__ w,
                                                const float* __restrict__ bias,
                                                const float* __restrict__ fnext,
                                                float* __restrict__ ef_out,
                                                float* __restrict__ fp_out,
                                                float* __restrict__ partial) {
    const int plane = blockIdx.x >> 4;   // b*3 + c
    const int rr = blockIdx.x & 15;
    const int b = plane / CC, c = plane % CC;
    const int pos = rr * 256 + threadIdx.x;   // 0..4095
    const int Y = pos >> 6, X = pos & 63;
    float acc = bias[c];
    const float* wc = w + c * Z1c * 9;
    for (int ci = 0; ci < Z1c; ++ci) {
        const float* ip = l1 + (size_t)(b * Z1c + ci) * 256;
        float wv[9];
#pragma unroll
        for (int t = 0; t < 9; ++t) wv[t] = wc[t];
#pragma unroll
        for (int dy = 0; dy < 3; ++dy) {
            const int YY = Y + dy - 1;
            if ((unsigned)YY < 64u) {
                const int sy = YY >> 2;
#pragma unroll
                for (int dx = 0; dx < 3; ++dx) {
                    const int XX = X + dx - 1;
                    if ((unsigned)XX < 64u)
                        acc = fmaf(ip[sy * 16 + (XX >> 2)], wv[dy * 3 + dx], acc);
                }
            }
        }
        wc += 9;
    }
    const size_t oidx = (size_t)plane * 4096 + pos;
    const float e = fnext[oidx] - acc;
    ef_out[oidx] = e;
    if (TAIL) fp_out[oidx] = acc;
    block_reduce_write(e * e, partial + blockIdx.x);
}

// generic 3x3 SAME conv, stride 1, optional 2x-nearest-upsampled input.
// EPI: 0 = store, 1 = relu-store, 2 = e = ref - acc (store e, partial += e^2),
//      3 = d = clip(acc); if (!converged) upd -= 0.1*d
template <int CIN, int COUT, int S, int NBK, bool UP2, bool IN2ADD, int EPI>
__global__ __launch_bounds__(256) void conv3x3_k(const float* __restrict__ in,
                                                 const float* __restrict__ in2,
                                                 const float* __restrict__ w,
                                                 const float* __restrict__ bias,
                                                 const float* __restrict__ ref,
                                                 float* __restrict__ out,
                                                 float* __restrict__ partial,
                                                 float* __restrict__ upd,
                                                 const int* __restrict__ cflag) {
    constexpr int SP  = S * S;
    constexpr int SIN = UP2 ? (S / 2) : S;
    static_assert(NBK * SP == 256, "block must be 256 threads");
    const int co = blockIdx.x % COUT;
    const int bg = blockIdx.x / COUT;
    const int bl  = threadIdx.x / SP;
    const int pos = threadIdx.x % SP;
    const int b = bg * NBK + bl;
    const int y = pos / S, x = pos % S;

    float acc = bias[co];
    const float* wc = w + (size_t)co * CIN * 9;
    for (int ci = 0; ci < CIN; ++ci) {
        const float* ip = in + (size_t)(b * CIN + ci) * (SIN * SIN);
        const float* ip2 = IN2ADD ? (in2 + (size_t)(b * CIN + ci) * SP) : nullptr;
        float wv[9];
#pragma unroll
        for (int t = 0; t < 9; ++t) wv[t] = wc[t];
#pragma unroll
        for (int dy = 0; dy < 3; ++dy) {
            const int yy = y + dy - 1;
            if ((unsigned)yy < (unsigned)S) {
                const int sy = UP2 ? (yy >> 1) : yy;
#pragma unroll
                for (int dx = 0; dx < 3; ++dx) {
                    const int xx = x + dx - 1;
                    if ((unsigned)xx < (unsigned)S) {
                        const int sx = UP2 ? (xx >> 1) : xx;
                        float v = ip[sy * SIN + sx];
                        if (IN2ADD) v += ip2[yy * S + xx];
                        acc = fmaf(v, wv[dy * 3 + dx], acc);
                    }
                }
            }
        }
        wc += 9;
    }
    const int oidx = ((b * COUT + co) * S + y) * S + x;
    if (EPI == 0) {
        out[oidx] = acc;
    } else if (EPI == 1) {
        out[oidx] = fmaxf(acc, 0.0f);
    } else if (EPI == 2) {
        const float e = ref[oidx] - acc;
        out[oidx] = e;
        block_reduce_write(e * e, partial + blockIdx.x);
    } else {  // EPI == 3
        const float d = fminf(fmaxf(acc, -CLIP_), CLIP_);
        if (*cflag == 0) upd[oidx] -= ALPHA_ * d;
    }
}

// per-step finalize: sum partials -> energy, advance scalar carry
__global__ __launch_bounds__(256) void finalize_k(const float* __restrict__ pF,
                                                  const float* __restrict__ p1,
                                                  const float* __restrict__ p2,
                                                  float* __restrict__ prev_e,
                                                  float* __restrict__ all_err,
                                                  int* __restrict__ conv,
                                                  int* __restrict__ iters,
                                                  int s) {
    __shared__ float sd[3 * 256];
    float aF = 0.f, a1 = 0.f, a2 = 0.f;
    for (int i = threadIdx.x; i < GRID_DEC; i += 256) aF += pF[i];
    for (int i = threadIdx.x; i < GRID_P1; i += 256) a1 += p1[i];
    for (int i = threadIdx.x; i < GRID_P2; i += 256) a2 += p2[i];
    sd[threadIdx.x] = aF;
    sd[256 + threadIdx.x] = a1;
    sd[512 + threadIdx.x] = a2;
    __syncthreads();
#pragma unroll
    for (int off = 128; off > 0; off >>= 1) {
        if (threadIdx.x < off) {
            sd[threadIdx.x] += sd[threadIdx.x + off];
            sd[256 + threadIdx.x] += sd[256 + threadIdx.x + off];
            sd[512 + threadIdx.x] += sd[512 + threadIdx.x + off];
        }
        __syncthreads();
    }
    if (threadIdx.x == 0) {
        const float energy = sd[0] / (float)N_FR
                           + 0.1f * (sd[256] / (float)N_L1 + sd[512] / (float)N_L2);
        const int cv = conv[s];
        const float pe = prev_e[s];
        const float rel = fabsf(energy - pe) / (pe + 1e-8f);
        const int newly = (rel < THRESH_) && (iters[s] + 1 >= MINS);
        conv[s + 1] = cv | newly;
        iters[s + 1] = iters[s] + (cv ? 0 : 1);
        prev_e[s + 1] = cv ? pe : energy;
        all_err[s] = energy;
    }
}

// copy tensor to output + accumulate sum of squares (for reg term)
__global__ __launch_bounds__(256) void copysq_k(const float* __restrict__ src,
                                                float* __restrict__ dst,
                                                float* __restrict__ partial) {
    const int i = blockIdx.x * 256 + threadIdx.x;
    const float v = src[i];
    dst[i] = v;
    block_reduce_write(v * v, partial + blockIdx.x);
}

// tail: final scalar outputs
__global__ __launch_bounds__(256) void tail_k(const float* __restrict__ pF,
                                              const float* __restrict__ p1,
                                              const float* __restrict__ p2,
                                              const float* __restrict__ pL1,
                                              const float* __restrict__ pL2,
                                              const float* __restrict__ all_err,
                                              const int* __restrict__ iters,
                                              float* __restrict__ out_sc) {
    __shared__ float sd[5 * 256];
    float aF = 0.f, a1 = 0.f, a2 = 0.f, aL1 = 0.f, aL2 = 0.f;
    for (int i = threadIdx.x; i < GRID_DEC; i += 256) aF += pF[i];
    for (int i = threadIdx.x; i < GRID_P1; i += 256) a1 += p1[i];
    for (int i = threadIdx.x; i < GRID_P2; i += 256) a2 += p2[i];
    for (int i = threadIdx.x; i < N_L1 / 256; i += 256) aL1 += pL1[i];
    for (int i = threadIdx.x; i < N_L2 / 256; i += 256) aL2 += pL2[i];
    sd[threadIdx.x] = aF;
    sd[256 + threadIdx.x] = a1;
    sd[512 + threadIdx.x] = a2;
    sd[768 + threadIdx.x] = aL1;
    sd[1024 + threadIdx.x] = aL2;
    __syncthreads();
#pragma unroll
    for (int off = 128; off > 0; off >>= 1) {
        if (threadIdx.x < off) {
            sd[threadIdx.x] += sd[threadIdx.x + off];
            sd[256 + threadIdx.x] += sd[256 + threadIdx.x + off];
            sd[512 + threadIdx.x] += sd[512 + threadIdx.x + off];
            sd[768 + threadIdx.x] += sd[768 + threadIdx.x + off];
            sd[1024 + threadIdx.x] += sd[1024 + threadIdx.x + off];
        }
        __syncthreads();
    }
    if (threadIdx.x == 0) {
        const float eF  = sd[0] / (float)N_FR;
        const float e1  = 0.1f * (sd[256] / (float)N_L1);
        const float e2  = 0.1f * (sd[512] / (float)N_L2);
        const float reg = 1e-4f * (sd[768] / (float)N_L1 + sd[1024] / (float)N_L2);
        out_sc[0] = eF + e1 + e2 + reg;  // energy_total
        out_sc[1] = eF;                  // energy_frame
        out_sc[2] = e1;                  // energy_latent1
        out_sc[3] = e2;                  // energy_latent2
        out_sc[16] = (float)iters[12];   // iters
    }
    if (threadIdx.x < 12) out_sc[4 + threadIdx.x] = all_err[threadIdx.x];
}

// ---------------- host launch ----------------
extern "C" void kernel_launch(void* const* d_in, const int* in_sizes, int n_in,
                              void* d_out, int out_size, void* d_ws, size_t ws_size,
                              hipStream_t stream) {
    const float* frame_cur = (const float*)d_in[0];
    const float* frame_nxt = (const float*)d_in[1];
    const float* enc_w = (const float*)d_in[2];
    const float* enc_b = (const float*)d_in[3];
    const float* dec_w = (const float*)d_in[4];
    const float* dec_b = (const float*)d_in[5];
    const float* dn_w  = (const float*)d_in[6];
    const float* dn_b  = (const float*)d_in[7];
    const float* up_w  = (const float*)d_in[8];
    const float* up_b  = (const float*)d_in[9];
    const float* tr_w  = (const float*)d_in[10];
    const float* tr_b  = (const float*)d_in[11];
    const float* p1_w  = (const float*)d_in[12];
    const float* p1_b  = (const float*)d_in[13];
    const float* p2_w  = (const float*)d_in[14];
    const float* p2_b  = (const float*)d_in[15];
    const float* l11w  = (const float*)d_in[16];
    const float* l11b  = (const float*)d_in[17];
    const float* l12w  = (const float*)d_in[18];
    const float* l12b  = (const float*)d_in[19];
    const float* l21w  = (const float*)d_in[20];
    const float* l21b  = (const float*)d_in[21];
    const float* l22w  = (const float*)d_in[22];
    const float* l22b  = (const float*)d_in[23];

    // workspace layout (floats)
    float* ws = (float*)d_ws;
    float* l1p   = ws;               // N_L1
    float* l2p   = l1p + N_L1;       // N_L2
    float* l2i   = l2p + N_L2;       // N_L2  (initial latent2 for tail)
    float* ef    = l2i + N_L2;       // N_FR
    float* trans = ef + N_FR;        // N_L2
    float* e2    = trans + N_L2;     // N_L2
    float* upl   = e2 + N_L2;        // N_L1
    float* e1    = upl + N_L1;       // N_L1
    float* bu    = e1 + N_L1;        // N_L1
    float* g1    = bu + N_L1;        // N_G1
    float* g2    = g1 + N_G1;        // N_G2
    float* pF    = g2 + N_G2;        // 4096
    float* p1    = pF + 4096;        // 4096
    float* p2    = p1 + 4096;        // 4096
    float* pL1   = p2 + 4096;        // 4096
    float* pL2   = pL1 + 4096;       // 4096
    float* prevE = pL2 + 4096;       // 16
    float* aerr  = prevE + 16;       // 16
    int*   conv  = (int*)(aerr + 16);   // 16 ints
    int*   iters = conv + 16;           // 16 ints

    // output layout (floats, reference return order)
    float* o_fp = (float*)d_out;         // frame_prediction
    float* o_l1 = o_fp + N_FR;           // l1p
    float* o_l2 = o_l1 + N_L1;           // l2p
    float* o_ef = o_l2 + N_L2;           // error_frame
    float* o_e1 = o_ef + N_FR;           // error_latent1
    float* o_e2 = o_e1 + N_L1;           // error_latent2
    float* o_sc = o_e2 + N_L2;           // 4 energies + 12 all_errors + iters

    init_k<<<1, 1, 0, stream>>>(prevE, conv, iters);
    encode_k<<<NB_ * Z1c, 256, 0, stream>>>(frame_cur, enc_w, enc_b, l1p);
    down_k<<<GRID_P2, 256, 0, stream>>>(l1p, dn_w, dn_b, l2i, l2p);

    for (int s = 0; s < MAXS; ++s) {
        decode_k<false><<<GRID_DEC, 256, 0, stream>>>(l1p, dec_w, dec_b, frame_nxt, ef, nullptr, pF);
        conv3x3_k<Z2c, Z2c, 8, 4, false, false, 0><<<GRID_P2, 256, 0, stream>>>(
            l2p, nullptr, tr_w, tr_b, nullptr, trans, nullptr, nullptr, nullptr);
        conv3x3_k<Z2c, Z2c, 8, 4, false, false, 2><<<GRID_P2, 256, 0, stream>>>(
            trans, nullptr, p2_w, p2_b, l2p, e2, p2, nullptr, nullptr);
        conv3x3_k<Z2c, Z1c, 16, 1, true, false, 0><<<GRID_P1, 256, 0, stream>>>(
            l2p, nullptr, up_w, up_b, nullptr, upl, nullptr, nullptr, nullptr);
        conv3x3_k<Z1c, Z1c, 16, 1, false, false, 2><<<GRID_P1, 256, 0, stream>>>(
            upl, nullptr, p1_w, p1_b, l1p, e1, p1, nullptr, nullptr);
        encode_k<<<NB_ * Z1c, 256, 0, stream>>>(ef, enc_w, enc_b, bu);
        conv3x3_k<Z1c, HIDc, 16, 1, false, true, 1><<<NB_ * HIDc, 256, 0, stream>>>(
            e1, bu, l11w, l11b, nullptr, g1, nullptr, nullptr, nullptr);
        conv3x3_k<HIDc, Z1c, 16, 1, false, false, 3><<<GRID_P1, 256, 0, stream>>>(
            g1, nullptr, l12w, l12b, nullptr, nullptr, nullptr, l1p, conv + s);
        conv3x3_k<Z2c, HIDc, 8, 4, false, false, 1><<<(NB_ / 4) * HIDc, 256, 0, stream>>>(
            e2, nullptr, l21w, l21b, nullptr, g2, nullptr, nullptr, nullptr);
        conv3x3_k<HIDc, Z2c, 8, 4, false, false, 3><<<GRID_P2, 256, 0, stream>>>(
            g2, nullptr, l22w, l22b, nullptr, nullptr, nullptr, l2p, conv + s);
        finalize_k<<<1, 256, 0, stream>>>(pF, p1, p2, prevE, aerr, conv, iters, s);
    }

    // ---- tail (mirrors reference epilogue; note latent2_hat uses INITIAL latent2) ----
    decode_k<true><<<GRID_DEC, 256, 0, stream>>>(l1p, dec_w, dec_b, frame_nxt, o_ef, o_fp, pF);
    conv3x3_k<Z2c, Z2c, 8, 4, false, false, 0><<<GRID_P2, 256, 0, stream>>>(
        l2i, nullptr, tr_w, tr_b, nullptr, trans, nullptr, nullptr, nullptr);
    conv3x3_k<Z2c, Z2c, 8, 4, false, false, 2><<<GRID_P2, 256, 0, stream>>>(
        trans, nullptr, p2_w, p2_b, l2p, o_e2, p2, nullptr, nullptr);
    conv3x3_k<Z2c, Z1c, 16, 1, true, false, 0><<<GRID_P1, 256, 0, stream>>>(
        l2p, nullptr, up_w, up_b, nullptr, upl, nullptr, nullptr, nullptr);
    conv3x3_k<Z1c, Z1c, 16, 1, false, false, 2><<<GRID_P1, 256, 0, stream>>>(
        upl, nullptr, p1_w, p1_b, l1p, o_e1, p1, nullptr, nullptr);
    copysq_k<<<N_L1 / 256, 256, 0, stream>>>(l1p, o_l1, pL1);
    copysq_k<<<N_L2 / 256, 256, 0, stream>>>(l2p, o_l2, pL2);
    tail_k<<<1, 256, 0, stream>>>(pF, p1, p2, pL1, pL2, aerr, iters, o_sc);
}

// Round 3
// 12655.029 us; speedup vs baseline: 2.0038x; 2.0038x over previous
//
#include <hip/hip_runtime.h>

// ---------------- config (mirrors reference) ----------------
constexpr int NB_  = 64;
constexpr int CC   = 3;
constexpr int IMG  = 64;
constexpr int Z1c  = 64;
constexpr int Z2c  = 128;
constexpr int HIDc = 128;
constexpr int S1c  = 16;
constexpr int S2c  = 8;
constexpr int MAXS = 12;
constexpr int MINS = 3;
constexpr float THRESH_ = 1e-3f;
constexpr float ALPHA_  = 0.1f;
constexpr float CLIP_   = 1.0f;

constexpr int N_L1 = NB_ * Z1c * S1c * S1c;   // 1,048,576
constexpr int N_L2 = NB_ * Z2c * S2c * S2c;   //   524,288
constexpr int N_FR = NB_ * CC * IMG * IMG;    //   786,432
constexpr int N_G1 = NB_ * HIDc * S1c * S1c;  // 2,097,152
constexpr int N_G2 = NB_ * HIDc * S2c * S2c;  //   524,288

// reduction grid sizes (new tiled kernels)
constexpr int GF = NB_ * CC;   // 192  decode blocks (one per (b,c) plane)
constexpr int G1 = 256;        // pred1 grid (B * 64/16)
constexpr int G2 = 256;        // pred2 grid (B * 128/32)
constexpr int GRID_DOWN = (NB_ / 4) * Z2c;  // 2048 (initial downsample, old-style)

// ---------------- helpers ----------------
__device__ __forceinline__ void block_reduce_write(float v, float* dst) {
    __shared__ float sd[256];
    sd[threadIdx.x] = v;
    __syncthreads();
#pragma unroll
    for (int off = 128; off > 0; off >>= 1) {
        if (threadIdx.x < off) sd[threadIdx.x] += sd[threadIdx.x + off];
        __syncthreads();
    }
    if (threadIdx.x == 0) *dst = sd[0];
}

// ---------------- scalar-state init ----------------
__global__ void init_k(float* prev_e, int* conv, int* iters) {
    prev_e[0] = 1e30f;
    conv[0] = 0;
    iters[0] = 0;
}

// ---------------- decode weight phase-transform ----------------
// decode = conv3x3(up4(z)). For output Y=4q+py, taps hit input rows {q-1,q} (py=0),
// {q} (py=1,2), {q,q+1} (py=3) -> fold 3x3 taps into per-phase 2x2 weights.
// we[((c*Z1+ci)*16 + py*4+px)*4 + ty*2+tx]
__global__ __launch_bounds__(256) void dec_pre_k(const float* __restrict__ dw,
                                                 float* __restrict__ we) {
    const int t = blockIdx.x * 256 + threadIdx.x;
    if (t >= CC * Z1c * 16) return;
    const int px = t & 3, py = (t >> 2) & 3;
    const int ci = (t >> 4) % Z1c, c = t / (16 * Z1c);
    float w4[4] = {0.f, 0.f, 0.f, 0.f};
#pragma unroll
    for (int dy = 0; dy < 3; ++dy)
#pragma unroll
        for (int dx = 0; dx < 3; ++dx) {
            const int r = py + dy - 1, s = px + dx - 1;
            const int ty = (py == 0) ? ((r < 0) ? 0 : 1) : ((r >= 4) ? 1 : 0);
            const int tx = (px == 0) ? ((s < 0) ? 0 : 1) : ((s >= 4) ? 1 : 0);
            w4[ty * 2 + tx] += dw[((c * Z1c + ci) * 3 + dy) * 3 + dx];
        }
#pragma unroll
    for (int k = 0; k < 4; ++k) we[(size_t)t * 4 + k] = w4[k];
}

// ---------------- decode (tiled, phase-folded) ----------------
// grid = B*3 blocks; thread = one 4x4 output tile; 64ci * (9 loads + 64 MACs).
template <bool TAIL>
__global__ __launch_bounds__(256) void decode_tile_k(const float* __restrict__ l1,
                                                     const float* __restrict__ we,
                                                     const float* __restrict__ db,
                                                     const float* __restrict__ fnext,
                                                     float* __restrict__ ef_out,
                                                     float* __restrict__ fp_out,
                                                     float* __restrict__ partial) {
    const int bid = blockIdx.x;            // b*3 + c
    const int b = bid / CC, c = bid % CC;
    const int ty = threadIdx.x >> 4, tx = threadIdx.x & 15;
    float acc[16];
#pragma unroll
    for (int k = 0; k < 16; ++k) acc[k] = 0.f;

    for (int ci = 0; ci < Z1c; ++ci) {
        const float* ip = l1 + (size_t)(b * Z1c + ci) * 256;
        float ld[3][3];
#pragma unroll
        for (int ry = 0; ry < 3; ++ry)
#pragma unroll
            for (int rx = 0; rx < 3; ++rx) {
                const int iy = ty - 1 + ry, ix = tx - 1 + rx;
                ld[ry][rx] = ((unsigned)iy < 16u && (unsigned)ix < 16u)
                                 ? ip[iy * 16 + ix] : 0.f;
            }
        const float* wb_ = we + (size_t)(c * Z1c + ci) * 64;
#pragma unroll
        for (int py = 0; py < 4; ++py) {
            const int ry0 = (py == 0) ? 0 : 1;
#pragma unroll
            for (int px = 0; px < 4; ++px) {
                const int rx0 = (px == 0) ? 0 : 1;
                const float* w4 = wb_ + (py * 4 + px) * 4;
                float a = acc[py * 4 + px];
                a = fmaf(ld[ry0][rx0],         w4[0], a);
                a = fmaf(ld[ry0][rx0 + 1],     w4[1], a);
                a = fmaf(ld[ry0 + 1][rx0],     w4[2], a);
                a = fmaf(ld[ry0 + 1][rx0 + 1], w4[3], a);
                acc[py * 4 + px] = a;
            }
        }
    }
    const float bias = db[c];
    float esum = 0.f;
#pragma unroll
    for (int py = 0; py < 4; ++py)
#pragma unroll
        for (int px = 0; px < 4; ++px) {
            const float fp = acc[py * 4 + px] + bias;
            const size_t idx = (size_t)bid * 4096 + (ty * 4 + py) * 64 + (tx * 4 + px);
            const float e = fnext[idx] - fp;
            ef_out[idx] = e;
            if (TAIL) fp_out[idx] = fp;
            esum += e * e;
        }
    block_reduce_write(esum, partial + bid);
}

// ---------------- encode (input-patch reuse across 16 co) ----------------
// grid = B * (Z1/16); thread = one 16x16 output pos; 3ci * (16 loads + 256 MACs)
__global__ __launch_bounds__(256) void encode_tile_k(const float* __restrict__ in,
                                                     const float* __restrict__ w,
                                                     const float* __restrict__ bias,
                                                     float* __restrict__ out) {
    constexpr int ECOG = 16;
    constexpr int NCG = Z1c / ECOG;
    const int b = blockIdx.x / NCG, cg = blockIdx.x % NCG;
    const int co_base = __builtin_amdgcn_readfirstlane(cg * ECOG);
    const int y = threadIdx.x >> 4, x = threadIdx.x & 15;
    float acc[ECOG];
#pragma unroll
    for (int j = 0; j < ECOG; ++j) acc[j] = bias[co_base + j];
    for (int ci = 0; ci < CC; ++ci) {
        float p[16];
        const float* ip = in + ((size_t)(b * CC + ci) * IMG + y * 4) * IMG + x * 4;
#pragma unroll
        for (int ky = 0; ky < 4; ++ky)
#pragma unroll
            for (int kx = 0; kx < 4; ++kx) p[ky * 4 + kx] = ip[ky * IMG + kx];
        const float* wp = w + (size_t)(co_base * CC + ci) * 16;
#pragma unroll
        for (int j = 0; j < ECOG; ++j) {
            const float* wj = wp + (size_t)j * CC * 16;
            float a = acc[j];
#pragma unroll
            for (int k = 0; k < 16; ++k) a = fmaf(p[k], wj[k], a);
            acc[j] = a;
        }
    }
#pragma unroll
    for (int j = 0; j < ECOG; ++j)
        out[((size_t)(b * Z1c + co_base + j) * S1c + y) * S1c + x] = acc[j];
}

// ---------------- initial downsample (runs once; old style, cheap) ----------------
__global__ __launch_bounds__(256) void down_k(const float* __restrict__ in,
                                              const float* __restrict__ w,
                                              const float* __restrict__ bias,
                                              float* __restrict__ out1,
                                              float* __restrict__ out2) {
    const int co = blockIdx.x % Z2c;
    const int bg = blockIdx.x / Z2c;
    const int bl = threadIdx.x >> 6;
    const int pos = threadIdx.x & 63;
    const int b = bg * 4 + bl;
    const int y = pos >> 3, x = pos & 7;
    float acc = bias[co];
    const float* wc = w + (size_t)co * Z1c * 9;
    for (int ci = 0; ci < Z1c; ++ci) {
        const float* ip = in + (size_t)(b * Z1c + ci) * 256;
        float wv[9];
#pragma unroll
        for (int t = 0; t < 9; ++t) wv[t] = wc[t];
#pragma unroll
        for (int dy = 0; dy < 3; ++dy) {
            const int yy = 2 * y + dy;
            if (yy < 16) {
#pragma unroll
                for (int dx = 0; dx < 3; ++dx) {
                    const int xx = 2 * x + dx;
                    if (xx < 16) acc = fmaf(ip[yy * 16 + xx], wv[dy * 3 + dx], acc);
                }
            }
        }
        wc += 9;
    }
    const int oidx = ((b * Z2c + co) * S2c + y) * S2c + x;
    out1[oidx] = acc;
    out2[oidx] = acc;
}

// ---------------- tiled 3x3 conv (the workhorse) ----------------
// Halo-padded LDS staging (no inner bounds checks), register-blocked over COG
// output channels, wave-uniform scalar weight loads.
// EPI: 0 store, 1 relu-store, 2 e=ref-acc (store e, partial+=e^2),
//      3 d=clip(acc); upd -= (converged?0:ALPHA)*d
template <int CIN, int COUT, int S, int CB, int COG, bool UP2, bool IN2ADD, int EPI>
__global__ __launch_bounds__(256) void conv_tile_k(const float* __restrict__ in,
                                                   const float* __restrict__ in2,
                                                   const float* __restrict__ w,
                                                   const float* __restrict__ bias,
                                                   const float* __restrict__ ref,
                                                   float* __restrict__ out,
                                                   float* __restrict__ partial,
                                                   float* __restrict__ upd,
                                                   const int* __restrict__ cflag) {
    constexpr int SP  = S * S;
    constexpr int SUB = 256 / SP;        // thread subgroups sharing spatial plane
    constexpr int ACCN = COG / SUB;      // accumulators per thread
    constexpr int HS  = S + 2;
    constexpr int HSP = HS * HS;
    constexpr int SIN = UP2 ? (S / 2) : S;
    constexpr int NCG = COUT / COG;
    static_assert(SUB * SP == 256 && ACCN * SUB == COG, "bad blocking");

    __shared__ float lds[CB * HSP];

    const int b  = blockIdx.x / NCG;
    const int cg = blockIdx.x % NCG;
    const int tid = threadIdx.x;
    const int pos = tid % SP;
    const int g   = tid / SP;
    const int y = pos / S, x = pos % S;
    int co_base = cg * COG + g * ACCN;
    co_base = __builtin_amdgcn_readfirstlane(co_base);   // wave-uniform -> scalar loads

    float acc[ACCN];
#pragma unroll
    for (int j = 0; j < ACCN; ++j) acc[j] = bias[co_base + j];

    int cf = 0;
    if (EPI == 3) cf = *cflag;           // uniform scalar load at entry

#pragma unroll 1
    for (int cb = 0; cb < CIN; cb += CB) {
        // ---- stage CB channels with zero halo ----
        for (int e = tid; e < CB * HSP; e += 256) {
            const int c = e / HSP, r = e % HSP;
            const int iy = r / HS - 1, ix = r % HS - 1;
            float v = 0.f;
            if ((unsigned)iy < (unsigned)S && (unsigned)ix < (unsigned)S) {
                const int ci = cb + c;
                if (UP2)
                    v = in[(size_t)(b * CIN + ci) * (SIN * SIN) + (iy >> 1) * SIN + (ix >> 1)];
                else
                    v = in[(size_t)(b * CIN + ci) * (SIN * SIN) + iy * S + ix];
                if (IN2ADD)
                    v += in2[(size_t)(b * CIN + ci) * SP + iy * S + ix];
            }
            lds[e] = v;
        }
        __syncthreads();

        const float* wp = w + ((size_t)co_base * CIN + cb) * 9;
#pragma unroll 2
        for (int c = 0; c < CB; ++c) {
            const float* lp = lds + c * HSP + y * HS + x;
            const float v0 = lp[0],          v1 = lp[1],          v2 = lp[2];
            const float v3 = lp[HS],         v4 = lp[HS + 1],     v5 = lp[HS + 2];
            const float v6 = lp[2 * HS],     v7 = lp[2 * HS + 1], v8 = lp[2 * HS + 2];
#pragma unroll
            for (int j = 0; j < ACCN; ++j) {
                const float* wj = wp + ((size_t)j * CIN + c) * 9;
                float a = acc[j];
                a = fmaf(v0, wj[0], a); a = fmaf(v1, wj[1], a); a = fmaf(v2, wj[2], a);
                a = fmaf(v3, wj[3], a); a = fmaf(v4, wj[4], a); a = fmaf(v5, wj[5], a);
                a = fmaf(v6, wj[6], a); a = fmaf(v7, wj[7], a); a = fmaf(v8, wj[8], a);
                acc[j] = a;
            }
        }
        __syncthreads();
    }

    // ---- epilogue ----
    float esum = 0.f;
#pragma unroll
    for (int j = 0; j < ACCN; ++j) {
        const int co = co_base + j;
        const size_t oidx = (size_t)(b * COUT + co) * SP + pos;
        if (EPI == 0) {
            out[oidx] = acc[j];
        } else if (EPI == 1) {
            out[oidx] = fmaxf(acc[j], 0.f);
        } else if (EPI == 2) {
            const float e = ref[oidx] - acc[j];
            out[oidx] = e;
            esum += e * e;
        } else {
            const float d = fminf(fmaxf(acc[j], -CLIP_), CLIP_);
            upd[oidx] -= (cf ? 0.f : ALPHA_) * d;
        }
    }
    if (EPI == 2) block_reduce_write(esum, partial + blockIdx.x);
}

// ---------------- per-step finalize ----------------
__global__ __launch_bounds__(256) void finalize_k(const float* __restrict__ pF,
                                                  const float* __restrict__ p1,
                                                  const float* __restrict__ p2,
                                                  float* __restrict__ prev_e,
                                                  float* __restrict__ all_err,
                                                  int* __restrict__ conv,
                                                  int* __restrict__ iters,
                                                  int s) {
    __shared__ float sd[3 * 256];
    float aF = 0.f, a1 = 0.f, a2 = 0.f;
    for (int i = threadIdx.x; i < GF; i += 256) aF += pF[i];
    for (int i = threadIdx.x; i < G1; i += 256) a1 += p1[i];
    for (int i = threadIdx.x; i < G2; i += 256) a2 += p2[i];
    sd[threadIdx.x] = aF;
    sd[256 + threadIdx.x] = a1;
    sd[512 + threadIdx.x] = a2;
    __syncthreads();
#pragma unroll
    for (int off = 128; off > 0; off >>= 1) {
        if (threadIdx.x < off) {
            sd[threadIdx.x] += sd[threadIdx.x + off];
            sd[256 + threadIdx.x] += sd[256 + threadIdx.x + off];
            sd[512 + threadIdx.x] += sd[512 + threadIdx.x + off];
        }
        __syncthreads();
    }
    if (threadIdx.x == 0) {
        const float energy = sd[0] / (float)N_FR
                           + 0.1f * (sd[256] / (float)N_L1 + sd[512] / (float)N_L2);
        const int cv = conv[s];
        const float pe = prev_e[s];
        const float rel = fabsf(energy - pe) / (pe + 1e-8f);
        const int newly = (rel < THRESH_) && (iters[s] + 1 >= MINS);
        conv[s + 1] = cv | newly;
        iters[s + 1] = iters[s] + (cv ? 0 : 1);
        prev_e[s + 1] = cv ? pe : energy;
        all_err[s] = energy;
    }
}

// copy tensor to output + sum of squares (reg term)
__global__ __launch_bounds__(256) void copysq_k(const float* __restrict__ src,
                                                float* __restrict__ dst,
                                                float* __restrict__ partial) {
    const int i = blockIdx.x * 256 + threadIdx.x;
    const float v = src[i];
    dst[i] = v;
    block_reduce_write(v * v, partial + blockIdx.x);
}

// tail scalars
__global__ __launch_bounds__(256) void tail_k(const float* __restrict__ pF,
                                              const float* __restrict__ p1,
                                              const float* __restrict__ p2,
                                              const float* __restrict__ pL1,
                                              const float* __restrict__ pL2,
                                              const float* __restrict__ all_err,
                                              const int* __restrict__ iters,
                                              float* __restrict__ out_sc) {
    __shared__ float sd[5 * 256];
    float aF = 0.f, a1 = 0.f, a2 = 0.f, aL1 = 0.f, aL2 = 0.f;
    for (int i = threadIdx.x; i < GF; i += 256) aF += pF[i];
    for (int i = threadIdx.x; i < G1; i += 256) a1 += p1[i];
    for (int i = threadIdx.x; i < G2; i += 256) a2 += p2[i];
    for (int i = threadIdx.x; i < N_L1 / 256; i += 256) aL1 += pL1[i];
    for (int i = threadIdx.x; i < N_L2 / 256; i += 256) aL2 += pL2[i];
    sd[threadIdx.x] = aF;
    sd[256 + threadIdx.x] = a1;
    sd[512 + threadIdx.x] = a2;
    sd[768 + threadIdx.x] = aL1;
    sd[1024 + threadIdx.x] = aL2;
    __syncthreads();
#pragma unroll
    for (int off = 128; off > 0; off >>= 1) {
        if (threadIdx.x < off) {
            sd[threadIdx.x] += sd[threadIdx.x + off];
            sd[256 + threadIdx.x] += sd[256 + threadIdx.x + off];
            sd[512 + threadIdx.x] += sd[512 + threadIdx.x + off];
            sd[768 + threadIdx.x] += sd[768 + threadIdx.x + off];
            sd[1024 + threadIdx.x] += sd[1024 + threadIdx.x + off];
        }
        __syncthreads();
    }
    if (threadIdx.x == 0) {
        const float eF  = sd[0] / (float)N_FR;
        const float e1  = 0.1f * (sd[256] / (float)N_L1);
        const float e2  = 0.1f * (sd[512] / (float)N_L2);
        const float reg = 1e-4f * (sd[768] / (float)N_L1 + sd[1024] / (float)N_L2);
        out_sc[0] = eF + e1 + e2 + reg;
        out_sc[1] = eF;
        out_sc[2] = e1;
        out_sc[3] = e2;
        out_sc[16] = (float)iters[12];
    }
    if (threadIdx.x < 12) out_sc[4 + threadIdx.x] = all_err[threadIdx.x];
}

// ---------------- host launch ----------------
extern "C" void kernel_launch(void* const* d_in, const int* in_sizes, int n_in,
                              void* d_out, int out_size, void* d_ws, size_t ws_size,
                              hipStream_t stream) {
    const float* frame_cur = (const float*)d_in[0];
    const float* frame_nxt = (const float*)d_in[1];
    const float* enc_w = (const float*)d_in[2];
    const float* enc_b = (const float*)d_in[3];
    const float* dec_w = (const float*)d_in[4];
    const float* dec_b = (const float*)d_in[5];
    const float* dn_w  = (const float*)d_in[6];
    const float* dn_b  = (const float*)d_in[7];
    const float* up_w  = (const float*)d_in[8];
    const float* up_b  = (const float*)d_in[9];
    const float* tr_w  = (const float*)d_in[10];
    const float* tr_b  = (const float*)d_in[11];
    const float* p1_w  = (const float*)d_in[12];
    const float* p1_b  = (const float*)d_in[13];
    const float* p2_w  = (const float*)d_in[14];
    const float* p2_b  = (const float*)d_in[15];
    const float* l11w  = (const float*)d_in[16];
    const float* l11b  = (const float*)d_in[17];
    const float* l12w  = (const float*)d_in[18];
    const float* l12b  = (const float*)d_in[19];
    const float* l21w  = (const float*)d_in[20];
    const float* l21b  = (const float*)d_in[21];
    const float* l22w  = (const float*)d_in[22];
    const float* l22b  = (const float*)d_in[23];

    // workspace layout (floats)
    float* ws = (float*)d_ws;
    float* l1p   = ws;               // N_L1
    float* l2p   = l1p + N_L1;       // N_L2
    float* l2i   = l2p + N_L2;       // N_L2
    float* ef    = l2i + N_L2;       // N_FR
    float* trans = ef + N_FR;        // N_L2
    float* e2    = trans + N_L2;     // N_L2
    float* upl   = e2 + N_L2;        // N_L1
    float* e1    = upl + N_L1;       // N_L1
    float* bu    = e1 + N_L1;        // N_L1
    float* g1    = bu + N_L1;        // N_G1
    float* g2    = g1 + N_G1;        // N_G2
    float* pF    = g2 + N_G2;        // 4096
    float* p1    = pF + 4096;        // 4096
    float* p2    = p1 + 4096;        // 4096
    float* pL1   = p2 + 4096;        // 4096
    float* pL2   = pL1 + 4096;       // 4096
    float* we    = pL2 + 4096;       // 12288 (decode phase-folded weights)
    float* prevE = we + 12288;       // 16
    float* aerr  = prevE + 16;       // 16
    int*   conv  = (int*)(aerr + 16);
    int*   iters = conv + 16;

    // output layout (reference return order)
    float* o_fp = (float*)d_out;
    float* o_l1 = o_fp + N_FR;
    float* o_l2 = o_l1 + N_L1;
    float* o_ef = o_l2 + N_L2;
    float* o_e1 = o_ef + N_FR;
    float* o_e2 = o_e1 + N_L1;
    float* o_sc = o_e2 + N_L2;

    init_k<<<1, 1, 0, stream>>>(prevE, conv, iters);
    dec_pre_k<<<12, 256, 0, stream>>>(dec_w, we);
    encode_tile_k<<<NB_ * (Z1c / 16), 256, 0, stream>>>(frame_cur, enc_w, enc_b, l1p);
    down_k<<<GRID_DOWN, 256, 0, stream>>>(l1p, dn_w, dn_b, l2i, l2p);

    for (int s = 0; s < MAXS; ++s) {
        decode_tile_k<false><<<GF, 256, 0, stream>>>(l1p, we, dec_b, frame_nxt, ef, nullptr, pF);
        // trans = transition(l2p)
        conv_tile_k<Z2c, Z2c, 8, 32, 32, false, false, 0><<<NB_ * 4, 256, 0, stream>>>(
            l2p, nullptr, tr_w, tr_b, nullptr, trans, nullptr, nullptr, nullptr);
        // e2 = l2p - pred2(trans)
        conv_tile_k<Z2c, Z2c, 8, 32, 32, false, false, 2><<<NB_ * 4, 256, 0, stream>>>(
            trans, nullptr, p2_w, p2_b, l2p, e2, p2, nullptr, nullptr);
        // upl = up_l2_to_l1(l2p)
        conv_tile_k<Z2c, Z1c, 16, 16, 16, true, false, 0><<<NB_ * 4, 256, 0, stream>>>(
            l2p, nullptr, up_w, up_b, nullptr, upl, nullptr, nullptr, nullptr);
        // e1 = l1p - pred1(upl)
        conv_tile_k<Z1c, Z1c, 16, 16, 16, false, false, 2><<<NB_ * 4, 256, 0, stream>>>(
            upl, nullptr, p1_w, p1_b, l1p, e1, p1, nullptr, nullptr);
        // bu = encode(ef)
        encode_tile_k<<<NB_ * (Z1c / 16), 256, 0, stream>>>(ef, enc_w, enc_b, bu);
        // g1 = relu(conv(e1 + bu))
        conv_tile_k<Z1c, HIDc, 16, 16, 16, false, true, 1><<<NB_ * 8, 256, 0, stream>>>(
            e1, bu, l11w, l11b, nullptr, g1, nullptr, nullptr, nullptr);
        // l1p -= 0.1*clip(conv(g1)) if active
        conv_tile_k<HIDc, Z1c, 16, 16, 16, false, false, 3><<<NB_ * 4, 256, 0, stream>>>(
            g1, nullptr, l12w, l12b, nullptr, nullptr, nullptr, l1p, conv + s);
        // g2 = relu(conv(e2))
        conv_tile_k<Z2c, HIDc, 8, 32, 32, false, false, 1><<<NB_ * 4, 256, 0, stream>>>(
            e2, nullptr, l21w, l21b, nullptr, g2, nullptr, nullptr, nullptr);
        // l2p -= 0.1*clip(conv(g2)) if active
        conv_tile_k<HIDc, Z2c, 8, 32, 32, false, false, 3><<<NB_ * 4, 256, 0, stream>>>(
            g2, nullptr, l22w, l22b, nullptr, nullptr, nullptr, l2p, conv + s);
        finalize_k<<<1, 256, 0, stream>>>(pF, p1, p2, prevE, aerr, conv, iters, s);
    }

    // ---- tail (latent2_hat uses INITIAL latent2 = l2i) ----
    decode_tile_k<true><<<GF, 256, 0, stream>>>(l1p, we, dec_b, frame_nxt, o_ef, o_fp, pF);
    conv_tile_k<Z2c, Z2c, 8, 32, 32, false, false, 0><<<NB_ * 4, 256, 0, stream>>>(
        l2i, nullptr, tr_w, tr_b, nullptr, trans, nullptr, nullptr, nullptr);
    conv_tile_k<Z2c, Z2c, 8, 32, 32, false, false, 2><<<NB_ * 4, 256, 0, stream>>>(
        trans, nullptr, p2_w, p2_b, l2p, o_e2, p2, nullptr, nullptr);
    conv_tile_k<Z2c, Z1c, 16, 16, 16, true, false, 0><<<NB_ * 4, 256, 0, stream>>>(
        l2p, nullptr, up_w, up_b, nullptr, upl, nullptr, nullptr, nullptr);
    conv_tile_k<Z1c, Z1c, 16, 16, 16, false, false, 2><<<NB_ * 4, 256, 0, stream>>>(
        upl, nullptr, p1_w, p1_b, l1p, o_e1, p1, nullptr, nullptr);
    copysq_k<<<N_L1 / 256, 256, 0, stream>>>(l1p, o_l1, pL1);
    copysq_k<<<N_L2 / 256, 256, 0, stream>>>(l2p, o_l2, pL2);
    tail_k<<<1, 256, 0, stream>>>(pF, p1, p2, pL1, pL2, aerr, iters, o_sc);
}

// Round 4
// 12626.710 us; speedup vs baseline: 2.0083x; 1.0022x over previous
//
#include <hip/hip_runtime.h>

// ---------------- config (mirrors reference) ----------------
constexpr int NB_  = 64;
constexpr int CC   = 3;
constexpr int IMG  = 64;
constexpr int Z1c  = 64;
constexpr int Z2c  = 128;
constexpr int HIDc = 128;
constexpr int S1c  = 16;
constexpr int S2c  = 8;
constexpr int MAXS = 12;
constexpr int MINS = 3;
constexpr float THRESH_ = 1e-3f;
constexpr float ALPHA_  = 0.1f;
constexpr float CLIP_   = 1.0f;

constexpr int N_L1 = NB_ * Z1c * S1c * S1c;   // 1,048,576
constexpr int N_L2 = NB_ * Z2c * S2c * S2c;   //   524,288
constexpr int N_FR = NB_ * CC * IMG * IMG;    //   786,432
constexpr int N_G1 = NB_ * HIDc * S1c * S1c;  // 2,097,152
constexpr int N_G2 = NB_ * HIDc * S2c * S2c;  //   524,288

// reduction grid sizes
constexpr int GF = NB_ * CC;   // 192 decode blocks
constexpr int G1 = 512;        // pred1 grid (COUT=64, COG=8)
constexpr int G2 = 512;        // pred2 grid (COUT=128, COG=16)
constexpr int GRID_DOWN = (NB_ / 4) * Z2c;

// ---------------- helpers ----------------
__device__ __forceinline__ void block_reduce_write(float v, float* dst) {
    __shared__ float sd[256];
    sd[threadIdx.x] = v;
    __syncthreads();
#pragma unroll
    for (int off = 128; off > 0; off >>= 1) {
        if (threadIdx.x < off) sd[threadIdx.x] += sd[threadIdx.x + off];
        __syncthreads();
    }
    if (threadIdx.x == 0) *dst = sd[0];
}

__global__ void init_k(float* prev_e, int* conv, int* iters) {
    prev_e[0] = 1e30f;
    conv[0] = 0;
    iters[0] = 0;
}

// ---------------- weight transpose: [COUT][CIN][3][3] -> [CIN][9][COUT] ----------------
__global__ __launch_bounds__(256) void wt_k(const float* __restrict__ src,
                                            float* __restrict__ dst,
                                            int cin, int cout) {
    const int t = blockIdx.x * 256 + threadIdx.x;
    if (t >= cin * cout * 9) return;
    const int k  = t % 9;
    const int ci = (t / 9) % cin;
    const int co = t / (9 * cin);
    dst[(ci * 9 + k) * cout + co] = src[t];
}

// ---------------- decode weight phase-transform (as round 3) ----------------
__global__ __launch_bounds__(256) void dec_pre_k(const float* __restrict__ dw,
                                                 float* __restrict__ we) {
    const int t = blockIdx.x * 256 + threadIdx.x;
    if (t >= CC * Z1c * 16) return;
    const int px = t & 3, py = (t >> 2) & 3;
    const int ci = (t >> 4) % Z1c, c = t / (16 * Z1c);
    float w4[4] = {0.f, 0.f, 0.f, 0.f};
#pragma unroll
    for (int dy = 0; dy < 3; ++dy)
#pragma unroll
        for (int dx = 0; dx < 3; ++dx) {
            const int r = py + dy - 1, s = px + dx - 1;
            const int ty = (py == 0) ? ((r < 0) ? 0 : 1) : ((r >= 4) ? 1 : 0);
            const int tx = (px == 0) ? ((s < 0) ? 0 : 1) : ((s >= 4) ? 1 : 0);
            w4[ty * 2 + tx] += dw[((c * Z1c + ci) * 3 + dy) * 3 + dx];
        }
#pragma unroll
    for (int k = 0; k < 4; ++k) we[(size_t)t * 4 + k] = w4[k];
}

// ---------------- decode (tiled, phase-folded) ----------------
template <bool TAIL>
__global__ __launch_bounds__(256) void decode_tile_k(const float* __restrict__ l1,
                                                     const float* __restrict__ we,
                                                     const float* __restrict__ db,
                                                     const float* __restrict__ fnext,
                                                     float* __restrict__ ef_out,
                                                     float* __restrict__ fp_out,
                                                     float* __restrict__ partial) {
    const int bid = blockIdx.x;            // b*3 + c
    const int b = bid / CC, c = bid % CC;
    const int ty = threadIdx.x >> 4, tx = threadIdx.x & 15;
    float acc[16];
#pragma unroll
    for (int k = 0; k < 16; ++k) acc[k] = 0.f;

    for (int ci = 0; ci < Z1c; ++ci) {
        const float* ip = l1 + (size_t)(b * Z1c + ci) * 256;
        float ld[3][3];
#pragma unroll
        for (int ry = 0; ry < 3; ++ry)
#pragma unroll
            for (int rx = 0; rx < 3; ++rx) {
                const int iy = ty - 1 + ry, ix = tx - 1 + rx;
                ld[ry][rx] = ((unsigned)iy < 16u && (unsigned)ix < 16u)
                                 ? ip[iy * 16 + ix] : 0.f;
            }
        const float* wb_ = we + (size_t)(c * Z1c + ci) * 64;
#pragma unroll
        for (int py = 0; py < 4; ++py) {
            const int ry0 = (py == 0) ? 0 : 1;
#pragma unroll
            for (int px = 0; px < 4; ++px) {
                const int rx0 = (px == 0) ? 0 : 1;
                const float* w4 = wb_ + (py * 4 + px) * 4;
                float a = acc[py * 4 + px];
                a = fmaf(ld[ry0][rx0],         w4[0], a);
                a = fmaf(ld[ry0][rx0 + 1],     w4[1], a);
                a = fmaf(ld[ry0 + 1][rx0],     w4[2], a);
                a = fmaf(ld[ry0 + 1][rx0 + 1], w4[3], a);
                acc[py * 4 + px] = a;
            }
        }
    }
    const float bias = db[c];
    float esum = 0.f;
#pragma unroll
    for (int py = 0; py < 4; ++py)
#pragma unroll
        for (int px = 0; px < 4; ++px) {
            const float fp = acc[py * 4 + px] + bias;
            const size_t idx = (size_t)bid * 4096 + (ty * 4 + py) * 64 + (tx * 4 + px);
            const float e = fnext[idx] - fp;
            ef_out[idx] = e;
            if (TAIL) fp_out[idx] = fp;
            esum += e * e;
        }
    block_reduce_write(esum, partial + bid);
}

// ---------------- encode ----------------
__global__ __launch_bounds__(256) void encode_tile_k(const float* __restrict__ in,
                                                     const float* __restrict__ w,
                                                     const float* __restrict__ bias,
                                                     float* __restrict__ out) {
    constexpr int ECOG = 16;
    constexpr int NCG = Z1c / ECOG;
    const int b = blockIdx.x / NCG, cg = blockIdx.x % NCG;
    const int co_base = cg * ECOG;
    const int y = threadIdx.x >> 4, x = threadIdx.x & 15;
    float acc[ECOG];
#pragma unroll
    for (int j = 0; j < ECOG; ++j) acc[j] = bias[co_base + j];
    for (int ci = 0; ci < CC; ++ci) {
        float p[16];
        const float* ip = in + ((size_t)(b * CC + ci) * IMG + y * 4) * IMG + x * 4;
#pragma unroll
        for (int ky = 0; ky < 4; ++ky)
#pragma unroll
            for (int kx = 0; kx < 4; ++kx) p[ky * 4 + kx] = ip[ky * IMG + kx];
        const float* wp = w + (size_t)(co_base * CC + ci) * 16;
#pragma unroll
        for (int j = 0; j < ECOG; ++j) {
            const float* wj = wp + (size_t)j * CC * 16;
            float a = acc[j];
#pragma unroll
            for (int k = 0; k < 16; ++k) a = fmaf(p[k], wj[k], a);
            acc[j] = a;
        }
    }
#pragma unroll
    for (int j = 0; j < ECOG; ++j)
        out[((size_t)(b * Z1c + co_base + j) * S1c + y) * S1c + x] = acc[j];
}

// ---------------- initial downsample (once) ----------------
__global__ __launch_bounds__(256) void down_k(const float* __restrict__ in,
                                              const float* __restrict__ w,
                                              const float* __restrict__ bias,
                                              float* __restrict__ out1,
                                              float* __restrict__ out2) {
    const int co = blockIdx.x % Z2c;
    const int bg = blockIdx.x / Z2c;
    const int bl = threadIdx.x >> 6;
    const int pos = threadIdx.x & 63;
    const int b = bg * 4 + bl;
    const int y = pos >> 3, x = pos & 7;
    float acc = bias[co];
    const float* wc = w + (size_t)co * Z1c * 9;
    for (int ci = 0; ci < Z1c; ++ci) {
        const float* ip = in + (size_t)(b * Z1c + ci) * 256;
        float wv[9];
#pragma unroll
        for (int t = 0; t < 9; ++t) wv[t] = wc[t];
#pragma unroll
        for (int dy = 0; dy < 3; ++dy) {
            const int yy = 2 * y + dy;
            if (yy < 16) {
#pragma unroll
                for (int dx = 0; dx < 3; ++dx) {
                    const int xx = 2 * x + dx;
                    if (xx < 16) acc = fmaf(ip[yy * 16 + xx], wv[dy * 3 + dx], acc);
                }
            }
        }
        wc += 9;
    }
    const int oidx = ((b * Z2c + co) * S2c + y) * S2c + x;
    out1[oidx] = acc;
    out2[oidx] = acc;
}

// ---------------- GEMM-style tiled 3x3 conv ----------------
// wt layout [CIN][9][COUT]; inner loop: LDS input reads (2-way-max bank
// conflicts via padded stride) + float4 VMEM broadcast weight loads (vmcnt,
// overlaps LDS lgkmcnt). FP accumulation order identical to round 3.
// EPI: 0 store, 1 relu, 2 e=ref-acc (+partial), 3 clip-update
template <int CIN, int COUT, int S, int CB, int COG, bool UP2, bool IN2ADD, int EPI>
__global__ __launch_bounds__(256) void conv_gemm_k(const float* __restrict__ in,
                                                   const float* __restrict__ in2,
                                                   const float* __restrict__ wt,
                                                   const float* __restrict__ bias,
                                                   const float* __restrict__ ref,
                                                   float* __restrict__ out,
                                                   float* __restrict__ partial,
                                                   float* __restrict__ upd,
                                                   const int* __restrict__ cflag) {
    constexpr int SP   = S * S;
    constexpr int SUB  = 256 / SP;
    constexpr int ACCN = COG / SUB;
    constexpr int HR   = S + 2;
    constexpr int HSW  = (S == 16) ? 24 : 12;   // padded row stride: 2-way max conflicts
    constexpr int SIN  = UP2 ? (S / 2) : S;
    constexpr int NCG  = COUT / COG;
    static_assert(SUB * SP == 256 && ACCN * SUB == COG && (ACCN % 4) == 0, "bad blocking");

    __shared__ float lds[CB * HR * HSW];

    const int b  = blockIdx.x / NCG;
    const int cg = blockIdx.x % NCG;
    const int tid = threadIdx.x;
    const int pos = tid % SP;
    const int g   = tid / SP;
    const int y = pos / S, x = pos % S;
    const int co_base = cg * COG + g * ACCN;

    const float* wp = wt + co_base;
    asm volatile("" : "+v"(wp));   // force VGPR addressing -> VMEM (vmcnt) loads

    float acc[ACCN];
#pragma unroll
    for (int j = 0; j < ACCN; ++j) acc[j] = bias[co_base + j];

    int cf = 0;
    if (EPI == 3) cf = *cflag;

#pragma unroll 1
    for (int cb = 0; cb < CIN; cb += CB) {
        // ---- stage CB channels with zero halo into padded LDS ----
        for (int e = tid; e < CB * HR * HR; e += 256) {
            const int c  = e / (HR * HR);
            const int rr = e - c * (HR * HR);
            const int r  = rr / HR, col = rr - r * HR;
            const int iy = r - 1, ix = col - 1;
            float v = 0.f;
            if ((unsigned)iy < (unsigned)S && (unsigned)ix < (unsigned)S) {
                const int ci = cb + c;
                if (UP2)
                    v = in[(size_t)(b * CIN + ci) * (SIN * SIN) + (iy >> 1) * SIN + (ix >> 1)];
                else
                    v = in[(size_t)(b * CIN + ci) * SP + iy * S + ix];
                if (IN2ADD)
                    v += in2[(size_t)(b * CIN + ci) * SP + iy * S + ix];
            }
            lds[c * (HR * HSW) + r * HSW + col] = v;
        }
        __syncthreads();

#pragma unroll 2
        for (int c = 0; c < CB; ++c) {
            const float* lp = lds + c * (HR * HSW) + y * HSW + x;
            float vv[9];
            vv[0] = lp[0];           vv[1] = lp[1];           vv[2] = lp[2];
            vv[3] = lp[HSW];         vv[4] = lp[HSW + 1];     vv[5] = lp[HSW + 2];
            vv[6] = lp[2 * HSW];     vv[7] = lp[2 * HSW + 1]; vv[8] = lp[2 * HSW + 2];
            const float* wr = wp + (size_t)(cb + c) * (9 * COUT);
#pragma unroll
            for (int k = 0; k < 9; ++k) {
                const float4* w4p = reinterpret_cast<const float4*>(wr + k * COUT);
#pragma unroll
                for (int q = 0; q < ACCN / 4; ++q) {
                    const float4 w4 = w4p[q];
                    acc[q * 4 + 0] = fmaf(vv[k], w4.x, acc[q * 4 + 0]);
                    acc[q * 4 + 1] = fmaf(vv[k], w4.y, acc[q * 4 + 1]);
                    acc[q * 4 + 2] = fmaf(vv[k], w4.z, acc[q * 4 + 2]);
                    acc[q * 4 + 3] = fmaf(vv[k], w4.w, acc[q * 4 + 3]);
                }
            }
        }
        __syncthreads();
    }

    // ---- epilogue ----
    float esum = 0.f;
#pragma unroll
    for (int j = 0; j < ACCN; ++j) {
        const int co = co_base + j;
        const size_t oidx = (size_t)(b * COUT + co) * SP + pos;
        if (EPI == 0) {
            out[oidx] = acc[j];
        } else if (EPI == 1) {
            out[oidx] = fmaxf(acc[j], 0.f);
        } else if (EPI == 2) {
            const float e = ref[oidx] - acc[j];
            out[oidx] = e;
            esum += e * e;
        } else {
            const float d = fminf(fmaxf(acc[j], -CLIP_), CLIP_);
            upd[oidx] -= (cf ? 0.f : ALPHA_) * d;
        }
    }
    if (EPI == 2) block_reduce_write(esum, partial + blockIdx.x);
}

// ---------------- per-step finalize ----------------
__global__ __launch_bounds__(256) void finalize_k(const float* __restrict__ pF,
                                                  const float* __restrict__ p1,
                                                  const float* __restrict__ p2,
                                                  float* __restrict__ prev_e,
                                                  float* __restrict__ all_err,
                                                  int* __restrict__ conv,
                                                  int* __restrict__ iters,
                                                  int s) {
    __shared__ float sd[3 * 256];
    float aF = 0.f, a1 = 0.f, a2 = 0.f;
    for (int i = threadIdx.x; i < GF; i += 256) aF += pF[i];
    for (int i = threadIdx.x; i < G1; i += 256) a1 += p1[i];
    for (int i = threadIdx.x; i < G2; i += 256) a2 += p2[i];
    sd[threadIdx.x] = aF;
    sd[256 + threadIdx.x] = a1;
    sd[512 + threadIdx.x] = a2;
    __syncthreads();
#pragma unroll
    for (int off = 128; off > 0; off >>= 1) {
        if (threadIdx.x < off) {
            sd[threadIdx.x] += sd[threadIdx.x + off];
            sd[256 + threadIdx.x] += sd[256 + threadIdx.x + off];
            sd[512 + threadIdx.x] += sd[512 + threadIdx.x + off];
        }
        __syncthreads();
    }
    if (threadIdx.x == 0) {
        const float energy = sd[0] / (float)N_FR
                           + 0.1f * (sd[256] / (float)N_L1 + sd[512] / (float)N_L2);
        const int cv = conv[s];
        const float pe = prev_e[s];
        const float rel = fabsf(energy - pe) / (pe + 1e-8f);
        const int newly = (rel < THRESH_) && (iters[s] + 1 >= MINS);
        conv[s + 1] = cv | newly;
        iters[s + 1] = iters[s] + (cv ? 0 : 1);
        prev_e[s + 1] = cv ? pe : energy;
        all_err[s] = energy;
    }
}

__global__ __launch_bounds__(256) void copysq_k(const float* __restrict__ src,
                                                float* __restrict__ dst,
                                                float* __restrict__ partial) {
    const int i = blockIdx.x * 256 + threadIdx.x;
    const float v = src[i];
    dst[i] = v;
    block_reduce_write(v * v, partial + blockIdx.x);
}

__global__ __launch_bounds__(256) void tail_k(const float* __restrict__ pF,
                                              const float* __restrict__ p1,
                                              const float* __restrict__ p2,
                                              const float* __restrict__ pL1,
                                              const float* __restrict__ pL2,
                                              const float* __restrict__ all_err,
                                              const int* __restrict__ iters,
                                              float* __restrict__ out_sc) {
    __shared__ float sd[5 * 256];
    float aF = 0.f, a1 = 0.f, a2 = 0.f, aL1 = 0.f, aL2 = 0.f;
    for (int i = threadIdx.x; i < GF; i += 256) aF += pF[i];
    for (int i = threadIdx.x; i < G1; i += 256) a1 += p1[i];
    for (int i = threadIdx.x; i < G2; i += 256) a2 += p2[i];
    for (int i = threadIdx.x; i < N_L1 / 256; i += 256) aL1 += pL1[i];
    for (int i = threadIdx.x; i < N_L2 / 256; i += 256) aL2 += pL2[i];
    sd[threadIdx.x] = aF;
    sd[256 + threadIdx.x] = a1;
    sd[512 + threadIdx.x] = a2;
    sd[768 + threadIdx.x] = aL1;
    sd[1024 + threadIdx.x] = aL2;
    __syncthreads();
#pragma unroll
    for (int off = 128; off > 0; off >>= 1) {
        if (threadIdx.x < off) {
            sd[threadIdx.x] += sd[threadIdx.x + off];
            sd[256 + threadIdx.x] += sd[256 + threadIdx.x + off];
            sd[512 + threadIdx.x] += sd[512 + threadIdx.x + off];
            sd[768 + threadIdx.x] += sd[768 + threadIdx.x + off];
            sd[1024 + threadIdx.x] += sd[1024 + threadIdx.x + off];
        }
        __syncthreads();
    }
    if (threadIdx.x == 0) {
        const float eF  = sd[0] / (float)N_FR;
        const float e1  = 0.1f * (sd[256] / (float)N_L1);
        const float e2  = 0.1f * (sd[512] / (float)N_L2);
        const float reg = 1e-4f * (sd[768] / (float)N_L1 + sd[1024] / (float)N_L2);
        out_sc[0] = eF + e1 + e2 + reg;
        out_sc[1] = eF;
        out_sc[2] = e1;
        out_sc[3] = e2;
        out_sc[16] = (float)iters[12];
    }
    if (threadIdx.x < 12) out_sc[4 + threadIdx.x] = all_err[threadIdx.x];
}

// ---------------- host launch ----------------
extern "C" void kernel_launch(void* const* d_in, const int* in_sizes, int n_in,
                              void* d_out, int out_size, void* d_ws, size_t ws_size,
                              hipStream_t stream) {
    const float* frame_cur = (const float*)d_in[0];
    const float* frame_nxt = (const float*)d_in[1];
    const float* enc_w = (const float*)d_in[2];
    const float* enc_b = (const float*)d_in[3];
    const float* dec_w = (const float*)d_in[4];
    const float* dec_b = (const float*)d_in[5];
    const float* dn_w  = (const float*)d_in[6];
    const float* dn_b  = (const float*)d_in[7];
    const float* up_w  = (const float*)d_in[8];
    const float* up_b  = (const float*)d_in[9];
    const float* tr_w  = (const float*)d_in[10];
    const float* tr_b  = (const float*)d_in[11];
    const float* p1_w  = (const float*)d_in[12];
    const float* p1_b  = (const float*)d_in[13];
    const float* p2_w  = (const float*)d_in[14];
    const float* p2_b  = (const float*)d_in[15];
    const float* l11w  = (const float*)d_in[16];
    const float* l11b  = (const float*)d_in[17];
    const float* l12w  = (const float*)d_in[18];
    const float* l12b  = (const float*)d_in[19];
    const float* l21w  = (const float*)d_in[20];
    const float* l21b  = (const float*)d_in[21];
    const float* l22w  = (const float*)d_in[22];
    const float* l22b  = (const float*)d_in[23];

    // workspace layout (floats)
    float* ws = (float*)d_ws;
    float* l1p   = ws;               // N_L1
    float* l2p   = l1p + N_L1;       // N_L2
    float* l2i   = l2p + N_L2;       // N_L2
    float* ef    = l2i + N_L2;       // N_FR
    float* trans = ef + N_FR;        // N_L2
    float* e2    = trans + N_L2;     // N_L2
    float* upl   = e2 + N_L2;        // N_L1
    float* e1    = upl + N_L1;       // N_L1
    float* bu    = e1 + N_L1;        // N_L1
    float* g1    = bu + N_L1;        // N_G1
    float* g2    = g1 + N_G1;        // N_G2
    float* pF    = g2 + N_G2;        // 4096
    float* p1    = pF + 4096;        // 4096
    float* p2    = p1 + 4096;        // 4096
    float* pL1   = p2 + 4096;        // 4096
    float* pL2   = pL1 + 4096;       // 4096
    float* we    = pL2 + 4096;       // 12288 (decode folded weights)
    // transposed conv weights [CIN][9][COUT]
    float* wt_tr  = we + 12288;       // 128*9*128 = 147456
    float* wt_p2  = wt_tr + 147456;   // 147456
    float* wt_up  = wt_p2 + 147456;   // 128*9*64 = 73728
    float* wt_p1  = wt_up + 73728;    // 64*9*64  = 36864
    float* wt_l11 = wt_p1 + 36864;    // 64*9*128 = 73728
    float* wt_l12 = wt_l11 + 73728;   // 128*9*64 = 73728
    float* wt_l21 = wt_l12 + 73728;   // 128*9*128= 147456
    float* wt_l22 = wt_l21 + 147456;  // 147456
    float* prevE = wt_l22 + 147456;   // 16
    float* aerr  = prevE + 16;        // 16
    int*   conv  = (int*)(aerr + 16);
    int*   iters = conv + 16;

    // output layout (reference return order)
    float* o_fp = (float*)d_out;
    float* o_l1 = o_fp + N_FR;
    float* o_l2 = o_l1 + N_L1;
    float* o_ef = o_l2 + N_L2;
    float* o_e1 = o_ef + N_FR;
    float* o_e2 = o_e1 + N_L1;
    float* o_sc = o_e2 + N_L2;

    init_k<<<1, 1, 0, stream>>>(prevE, conv, iters);
    dec_pre_k<<<12, 256, 0, stream>>>(dec_w, we);
    wt_k<<<576, 256, 0, stream>>>(tr_w,  wt_tr,  128, 128);
    wt_k<<<576, 256, 0, stream>>>(p2_w,  wt_p2,  128, 128);
    wt_k<<<288, 256, 0, stream>>>(up_w,  wt_up,  128, 64);
    wt_k<<<144, 256, 0, stream>>>(p1_w,  wt_p1,  64,  64);
    wt_k<<<288, 256, 0, stream>>>(l11w,  wt_l11, 64,  128);
    wt_k<<<288, 256, 0, stream>>>(l12w,  wt_l12, 128, 64);
    wt_k<<<576, 256, 0, stream>>>(l21w,  wt_l21, 128, 128);
    wt_k<<<576, 256, 0, stream>>>(l22w,  wt_l22, 128, 128);

    encode_tile_k<<<NB_ * (Z1c / 16), 256, 0, stream>>>(frame_cur, enc_w, enc_b, l1p);
    down_k<<<GRID_DOWN, 256, 0, stream>>>(l1p, dn_w, dn_b, l2i, l2p);

    for (int s = 0; s < MAXS; ++s) {
        decode_tile_k<false><<<GF, 256, 0, stream>>>(l1p, we, dec_b, frame_nxt, ef, nullptr, pF);
        // trans = transition(l2p)
        conv_gemm_k<Z2c, Z2c, 8, 32, 16, false, false, 0><<<NB_ * 8, 256, 0, stream>>>(
            l2p, nullptr, wt_tr, tr_b, nullptr, trans, nullptr, nullptr, nullptr);
        // e2 = l2p - pred2(trans)
        conv_gemm_k<Z2c, Z2c, 8, 32, 16, false, false, 2><<<NB_ * 8, 256, 0, stream>>>(
            trans, nullptr, wt_p2, p2_b, l2p, e2, p2, nullptr, nullptr);
        // upl = up_l2_to_l1(l2p)
        conv_gemm_k<Z2c, Z1c, 16, 16, 8, true, false, 0><<<NB_ * 8, 256, 0, stream>>>(
            l2p, nullptr, wt_up, up_b, nullptr, upl, nullptr, nullptr, nullptr);
        // e1 = l1p - pred1(upl)
        conv_gemm_k<Z1c, Z1c, 16, 16, 8, false, false, 2><<<NB_ * 8, 256, 0, stream>>>(
            upl, nullptr, wt_p1, p1_b, l1p, e1, p1, nullptr, nullptr);
        // bu = encode(ef)
        encode_tile_k<<<NB_ * (Z1c / 16), 256, 0, stream>>>(ef, enc_w, enc_b, bu);
        // g1 = relu(conv(e1 + bu))
        conv_gemm_k<Z1c, HIDc, 16, 16, 8, false, true, 1><<<NB_ * 16, 256, 0, stream>>>(
            e1, bu, wt_l11, l11b, nullptr, g1, nullptr, nullptr, nullptr);
        // l1p -= 0.1*clip(conv(g1)) if active
        conv_gemm_k<HIDc, Z1c, 16, 16, 8, false, false, 3><<<NB_ * 8, 256, 0, stream>>>(
            g1, nullptr, wt_l12, l12b, nullptr, nullptr, nullptr, l1p, conv + s);
        // g2 = relu(conv(e2))
        conv_gemm_k<Z2c, HIDc, 8, 32, 16, false, false, 1><<<NB_ * 8, 256, 0, stream>>>(
            e2, nullptr, wt_l21, l21b, nullptr, g2, nullptr, nullptr, nullptr);
        // l2p -= 0.1*clip(conv(g2)) if active
        conv_gemm_k<HIDc, Z2c, 8, 32, 16, false, false, 3><<<NB_ * 8, 256, 0, stream>>>(
            g2, nullptr, wt_l22, l22b, nullptr, nullptr, nullptr, l2p, conv + s);
        finalize_k<<<1, 256, 0, stream>>>(pF, p1, p2, prevE, aerr, conv, iters, s);
    }

    // ---- tail (latent2_hat uses INITIAL latent2 = l2i) ----
    decode_tile_k<true><<<GF, 256, 0, stream>>>(l1p, we, dec_b, frame_nxt, o_ef, o_fp, pF);
    conv_gemm_k<Z2c, Z2c, 8, 32, 16, false, false, 0><<<NB_ * 8, 256, 0, stream>>>(
        l2i, nullptr, wt_tr, tr_b, nullptr, trans, nullptr, nullptr, nullptr);
    conv_gemm_k<Z2c, Z2c, 8, 32, 16, false, false, 2><<<NB_ * 8, 256, 0, stream>>>(
        trans, nullptr, wt_p2, p2_b, l2p, o_e2, p2, nullptr, nullptr);
    conv_gemm_k<Z2c, Z1c, 16, 16, 8, true, false, 0><<<NB_ * 8, 256, 0, stream>>>(
        l2p, nullptr, wt_up, up_b, nullptr, upl, nullptr, nullptr, nullptr);
    conv_gemm_k<Z1c, Z1c, 16, 16, 8, false, false, 2><<<NB_ * 8, 256, 0, stream>>>(
        upl, nullptr, wt_p1, p1_b, l1p, o_e1, p1, nullptr, nullptr);
    copysq_k<<<N_L1 / 256, 256, 0, stream>>>(l1p, o_l1, pL1);
    copysq_k<<<N_L2 / 256, 256, 0, stream>>>(l2p, o_l2, pL2);
    tail_k<<<1, 256, 0, stream>>>(pF, p1, p2, pL1, pL2, aerr, iters, o_sc);
}

// Round 5
// 10062.478 us; speedup vs baseline: 2.5201x; 1.2548x over previous
//
#include <hip/hip_runtime.h>

// ---------------- config (mirrors reference) ----------------
constexpr int NB_  = 64;
constexpr int CC   = 3;
constexpr int IMG  = 64;
constexpr int Z1c  = 64;
constexpr int Z2c  = 128;
constexpr int HIDc = 128;
constexpr int S1c  = 16;
constexpr int S2c  = 8;
constexpr int MAXS = 12;
constexpr int MINS = 3;
constexpr float THRESH_ = 1e-3f;
constexpr float ALPHA_  = 0.1f;
constexpr float CLIP_   = 1.0f;

constexpr int N_L1 = NB_ * Z1c * S1c * S1c;   // 1,048,576
constexpr int N_L2 = NB_ * Z2c * S2c * S2c;   //   524,288
constexpr int N_FR = NB_ * CC * IMG * IMG;    //   786,432
constexpr int N_G1 = NB_ * HIDc * S1c * S1c;  // 2,097,152
constexpr int N_G2 = NB_ * HIDc * S2c * S2c;  //   524,288

// reduction grid sizes (must match launch grids of EPI=2 kernels)
constexpr int GF = NB_ * CC;   // 192 decode blocks
constexpr int G1 = 256;        // p1 conv grid (COUT=64, COG=16 -> NCG=4)
constexpr int G2 = 256;        // p2 conv grid (COUT=128, COG=32 -> NCG=4)
constexpr int GRID_DOWN = (NB_ / 4) * Z2c;

// ---------------- helpers ----------------
__device__ __forceinline__ void block_reduce_write(float v, float* dst) {
    __shared__ float sd[256];
    sd[threadIdx.x] = v;
    __syncthreads();
#pragma unroll
    for (int off = 128; off > 0; off >>= 1) {
        if (threadIdx.x < off) sd[threadIdx.x] += sd[threadIdx.x + off];
        __syncthreads();
    }
    if (threadIdx.x == 0) *dst = sd[0];
}

__global__ void init_k(float* prev_e, int* conv, int* iters) {
    prev_e[0] = 1e30f;
    conv[0] = 0;
    iters[0] = 0;
}

// ---------------- weight transpose: [COUT][CIN][3][3] -> [CIN][9][COUT] ----------------
__global__ __launch_bounds__(256) void wt_k(const float* __restrict__ src,
                                            float* __restrict__ dst,
                                            int cin, int cout) {
    const int t = blockIdx.x * 256 + threadIdx.x;
    if (t >= cin * cout * 9) return;
    const int k  = t % 9;
    const int ci = (t / 9) % cin;
    const int co = t / (9 * cin);
    dst[(ci * 9 + k) * cout + co] = src[t];
}

// ---------------- decode weight phase-transform ----------------
__global__ __launch_bounds__(256) void dec_pre_k(const float* __restrict__ dw,
                                                 float* __restrict__ we) {
    const int t = blockIdx.x * 256 + threadIdx.x;
    if (t >= CC * Z1c * 16) return;
    const int px = t & 3, py = (t >> 2) & 3;
    const int ci = (t >> 4) % Z1c, c = t / (16 * Z1c);
    float w4[4] = {0.f, 0.f, 0.f, 0.f};
#pragma unroll
    for (int dy = 0; dy < 3; ++dy)
#pragma unroll
        for (int dx = 0; dx < 3; ++dx) {
            const int r = py + dy - 1, s = px + dx - 1;
            const int ty = (py == 0) ? ((r < 0) ? 0 : 1) : ((r >= 4) ? 1 : 0);
            const int tx = (px == 0) ? ((s < 0) ? 0 : 1) : ((s >= 4) ? 1 : 0);
            w4[ty * 2 + tx] += dw[((c * Z1c + ci) * 3 + dy) * 3 + dx];
        }
#pragma unroll
    for (int k = 0; k < 4; ++k) we[(size_t)t * 4 + k] = w4[k];
}

// ---------------- decode (tiled, phase-folded) ----------------
template <bool TAIL>
__global__ __launch_bounds__(256) void decode_tile_k(const float* __restrict__ l1,
                                                     const float* __restrict__ we,
                                                     const float* __restrict__ db,
                                                     const float* __restrict__ fnext,
                                                     float* __restrict__ ef_out,
                                                     float* __restrict__ fp_out,
                                                     float* __restrict__ partial) {
    const int bid = blockIdx.x;            // b*3 + c
    const int b = bid / CC, c = bid % CC;
    const int ty = threadIdx.x >> 4, tx = threadIdx.x & 15;
    float acc[16];
#pragma unroll
    for (int k = 0; k < 16; ++k) acc[k] = 0.f;

    for (int ci = 0; ci < Z1c; ++ci) {
        const float* ip = l1 + (size_t)(b * Z1c + ci) * 256;
        float ld[3][3];
#pragma unroll
        for (int ry = 0; ry < 3; ++ry)
#pragma unroll
            for (int rx = 0; rx < 3; ++rx) {
                const int iy = ty - 1 + ry, ix = tx - 1 + rx;
                ld[ry][rx] = ((unsigned)iy < 16u && (unsigned)ix < 16u)
                                 ? ip[iy * 16 + ix] : 0.f;
            }
        const float* wb_ = we + (size_t)(c * Z1c + ci) * 64;
#pragma unroll
        for (int py = 0; py < 4; ++py) {
            const int ry0 = (py == 0) ? 0 : 1;
#pragma unroll
            for (int px = 0; px < 4; ++px) {
                const int rx0 = (px == 0) ? 0 : 1;
                const float* w4 = wb_ + (py * 4 + px) * 4;
                float a = acc[py * 4 + px];
                a = fmaf(ld[ry0][rx0],         w4[0], a);
                a = fmaf(ld[ry0][rx0 + 1],     w4[1], a);
                a = fmaf(ld[ry0 + 1][rx0],     w4[2], a);
                a = fmaf(ld[ry0 + 1][rx0 + 1], w4[3], a);
                acc[py * 4 + px] = a;
            }
        }
    }
    const float bias = db[c];
    float esum = 0.f;
#pragma unroll
    for (int py = 0; py < 4; ++py)
#pragma unroll
        for (int px = 0; px < 4; ++px) {
            const float fp = acc[py * 4 + px] + bias;
            const size_t idx = (size_t)bid * 4096 + (ty * 4 + py) * 64 + (tx * 4 + px);
            const float e = fnext[idx] - fp;
            ef_out[idx] = e;
            if (TAIL) fp_out[idx] = fp;
            esum += e * e;
        }
    block_reduce_write(esum, partial + bid);
}

// ---------------- encode ----------------
__global__ __launch_bounds__(256) void encode_tile_k(const float* __restrict__ in,
                                                     const float* __restrict__ w,
                                                     const float* __restrict__ bias,
                                                     float* __restrict__ out) {
    constexpr int ECOG = 16;
    constexpr int NCG = Z1c / ECOG;
    const int b = blockIdx.x / NCG, cg = blockIdx.x % NCG;
    const int co_base = cg * ECOG;
    const int y = threadIdx.x >> 4, x = threadIdx.x & 15;
    float acc[ECOG];
#pragma unroll
    for (int j = 0; j < ECOG; ++j) acc[j] = bias[co_base + j];
    for (int ci = 0; ci < CC; ++ci) {
        float p[16];
        const float* ip = in + ((size_t)(b * CC + ci) * IMG + y * 4) * IMG + x * 4;
#pragma unroll
        for (int ky = 0; ky < 4; ++ky)
#pragma unroll
            for (int kx = 0; kx < 4; ++kx) p[ky * 4 + kx] = ip[ky * IMG + kx];
        const float* wp = w + (size_t)(co_base * CC + ci) * 16;
#pragma unroll
        for (int j = 0; j < ECOG; ++j) {
            const float* wj = wp + (size_t)j * CC * 16;
            float a = acc[j];
#pragma unroll
            for (int k = 0; k < 16; ++k) a = fmaf(p[k], wj[k], a);
            acc[j] = a;
        }
    }
#pragma unroll
    for (int j = 0; j < ECOG; ++j)
        out[((size_t)(b * Z1c + co_base + j) * S1c + y) * S1c + x] = acc[j];
}

// ---------------- initial downsample (once) ----------------
__global__ __launch_bounds__(256) void down_k(const float* __restrict__ in,
                                              const float* __restrict__ w,
                                              const float* __restrict__ bias,
                                              float* __restrict__ out1,
                                              float* __restrict__ out2) {
    const int co = blockIdx.x % Z2c;
    const int bg = blockIdx.x / Z2c;
    const int bl = threadIdx.x >> 6;
    const int pos = threadIdx.x & 63;
    const int b = bg * 4 + bl;
    const int y = pos >> 3, x = pos & 7;
    float acc = bias[co];
    const float* wc = w + (size_t)co * Z1c * 9;
    for (int ci = 0; ci < Z1c; ++ci) {
        const float* ip = in + (size_t)(b * Z1c + ci) * 256;
        float wv[9];
#pragma unroll
        for (int t = 0; t < 9; ++t) wv[t] = wc[t];
#pragma unroll
        for (int dy = 0; dy < 3; ++dy) {
            const int yy = 2 * y + dy;
            if (yy < 16) {
#pragma unroll
                for (int dx = 0; dx < 3; ++dx) {
                    const int xx = 2 * x + dx;
                    if (xx < 16) acc = fmaf(ip[yy * 16 + xx], wv[dy * 3 + dx], acc);
                }
            }
        }
        wc += 9;
    }
    const int oidx = ((b * Z2c + co) * S2c + y) * S2c + x;
    out1[oidx] = acc;
    out2[oidx] = acc;
}

// ---------------- register-tiled 3x3 conv ----------------
// Thread computes ACCN=4 output channels x P x-positions. Per input channel:
// 6 vectorized LDS reads + 9 float4 broadcast weight loads serve 9*4*P FMAs.
// XCD swizzle: all co-groups of a batch on one XCD (input fetched once/XCD).
// EPI: 0 store, 1 relu, 2 e=ref-acc (+partial), 3 clip-update
template <int CIN, int COUT, int S, int CB, int P, bool UP2, bool IN2ADD, int EPI>
__global__ __launch_bounds__(256) void conv_blk_k(const float* __restrict__ in,
                                                  const float* __restrict__ in2,
                                                  const float* __restrict__ wt,
                                                  const float* __restrict__ bias,
                                                  const float* __restrict__ ref,
                                                  float* __restrict__ out,
                                                  float* __restrict__ partial,
                                                  float* __restrict__ upd,
                                                  const int* __restrict__ cflag) {
    constexpr int ACCN = 4;
    constexpr int SP  = S * S;
    constexpr int XB  = S / P;           // x-blocks per row
    constexpr int TPP = S * XB;          // threads per (b,plane)
    constexpr int NG  = 256 / TPP;       // co-groups per block
    constexpr int COG = NG * ACCN;
    constexpr int NCG = COUT / COG;
    constexpr int HR  = S + 2;
    constexpr int HSW = (S == 16) ? 24 : 12;  // padded LDS row stride
    constexpr int SIN = UP2 ? (S / 2) : S;
    static_assert(TPP * NG == 256 && COG * NCG == COUT && S % P == 0, "bad blocking");
    static_assert(CIN % CB == 0, "CB must divide CIN");

    __shared__ float lds[CB * HR * HSW];

    // XCD-locality swizzle: grid = 64 * NCG; XCD x owns batches {x, x+8, ...}
    const int l  = blockIdx.x;
    const int j8 = l >> 3;
    const int b  = (l & 7) + 8 * (j8 / NCG);
    const int cg = j8 % NCG;

    const int tid = threadIdx.x;
    const int local = tid % TPP;
    const int g     = tid / TPP;
    const int y  = local / XB;
    const int x0 = (local % XB) * P;
    const int co_base = cg * COG + g * ACCN;

    const float* wp = wt + co_base;
    asm volatile("" : "+v"(wp));   // keep weight loads on the VMEM (vmcnt) path

    float acc[ACCN][P];
#pragma unroll
    for (int j = 0; j < ACCN; ++j)
#pragma unroll
        for (int p = 0; p < P; ++p) acc[j][p] = bias[co_base + j];

    int cf = 0;
    if (EPI == 3) cf = *cflag;

#pragma unroll 1
    for (int cb = 0; cb < CIN; cb += CB) {
        // ---- stage CB channels with zero halo into padded LDS ----
        for (int e = tid; e < CB * HR * HR; e += 256) {
            const int c  = e / (HR * HR);
            const int rr = e - c * (HR * HR);
            const int r  = rr / HR, col = rr - r * HR;
            const int iy = r - 1, ix = col - 1;
            float v = 0.f;
            if ((unsigned)iy < (unsigned)S && (unsigned)ix < (unsigned)S) {
                const int ci = cb + c;
                if (UP2)
                    v = in[(size_t)(b * CIN + ci) * (SIN * SIN) + (iy >> 1) * SIN + (ix >> 1)];
                else
                    v = in[(size_t)(b * CIN + ci) * SP + iy * S + ix];
                if (IN2ADD)
                    v += in2[(size_t)(b * CIN + ci) * SP + iy * S + ix];
            }
            lds[c * (HR * HSW) + r * HSW + col] = v;
        }
        __syncthreads();

#pragma unroll 2
        for (int c = 0; c < CB; ++c) {
            const float* lp = lds + c * (HR * HSW) + y * HSW + x0;
            float w[3][P + 2];
            if constexpr (P == 4) {
#pragma unroll
                for (int dy = 0; dy < 3; ++dy) {
                    const float4 a  = *reinterpret_cast<const float4*>(lp + dy * HSW);
                    const float2 b2 = *reinterpret_cast<const float2*>(lp + dy * HSW + 4);
                    w[dy][0] = a.x; w[dy][1] = a.y; w[dy][2] = a.z;
                    w[dy][3] = a.w; w[dy][4] = b2.x; w[dy][5] = b2.y;
                }
            } else {
#pragma unroll
                for (int dy = 0; dy < 3; ++dy) {
                    const float2 a  = *reinterpret_cast<const float2*>(lp + dy * HSW);
                    const float2 b2 = *reinterpret_cast<const float2*>(lp + dy * HSW + 2);
                    w[dy][0] = a.x; w[dy][1] = a.y; w[dy][2] = b2.x; w[dy][3] = b2.y;
                }
            }
            const float* wr = wp + (size_t)(cb + c) * (9 * COUT);
#pragma unroll
            for (int k = 0; k < 9; ++k) {
                const int dy = k / 3, dx = k % 3;
                const float4 wv = *reinterpret_cast<const float4*>(wr + k * COUT);
#pragma unroll
                for (int p = 0; p < P; ++p) {
                    const float v = w[dy][dx + p];
                    acc[0][p] = fmaf(v, wv.x, acc[0][p]);
                    acc[1][p] = fmaf(v, wv.y, acc[1][p]);
                    acc[2][p] = fmaf(v, wv.z, acc[2][p]);
                    acc[3][p] = fmaf(v, wv.w, acc[3][p]);
                }
            }
        }
        __syncthreads();
    }

    // ---- vectorized epilogue ----
    float esum = 0.f;
#pragma unroll
    for (int j = 0; j < ACCN; ++j) {
        const int co = co_base + j;
        const size_t ob = (size_t)(b * COUT + co) * SP + y * S + x0;
        if constexpr (EPI == 0 || EPI == 1) {
            if constexpr (P == 4) {
                float4 v;
                v.x = acc[j][0]; v.y = acc[j][1]; v.z = acc[j][2]; v.w = acc[j][3];
                if (EPI == 1) {
                    v.x = fmaxf(v.x, 0.f); v.y = fmaxf(v.y, 0.f);
                    v.z = fmaxf(v.z, 0.f); v.w = fmaxf(v.w, 0.f);
                }
                *reinterpret_cast<float4*>(out + ob) = v;
            } else {
                float2 v;
                v.x = acc[j][0]; v.y = acc[j][1];
                if (EPI == 1) { v.x = fmaxf(v.x, 0.f); v.y = fmaxf(v.y, 0.f); }
                *reinterpret_cast<float2*>(out + ob) = v;
            }
        } else if constexpr (EPI == 2) {
            if constexpr (P == 4) {
                const float4 r = *reinterpret_cast<const float4*>(ref + ob);
                float4 e;
                e.x = r.x - acc[j][0]; e.y = r.y - acc[j][1];
                e.z = r.z - acc[j][2]; e.w = r.w - acc[j][3];
                *reinterpret_cast<float4*>(out + ob) = e;
                esum += e.x * e.x + e.y * e.y + e.z * e.z + e.w * e.w;
            } else {
                const float2 r = *reinterpret_cast<const float2*>(ref + ob);
                float2 e;
                e.x = r.x - acc[j][0]; e.y = r.y - acc[j][1];
                *reinterpret_cast<float2*>(out + ob) = e;
                esum += e.x * e.x + e.y * e.y;
            }
        } else {  // EPI == 3
            const float s = cf ? 0.f : ALPHA_;
            if constexpr (P == 4) {
                float4 u = *reinterpret_cast<float4*>(upd + ob);
                u.x -= s * fminf(fmaxf(acc[j][0], -CLIP_), CLIP_);
                u.y -= s * fminf(fmaxf(acc[j][1], -CLIP_), CLIP_);
                u.z -= s * fminf(fmaxf(acc[j][2], -CLIP_), CLIP_);
                u.w -= s * fminf(fmaxf(acc[j][3], -CLIP_), CLIP_);
                *reinterpret_cast<float4*>(upd + ob) = u;
            } else {
                float2 u = *reinterpret_cast<float2*>(upd + ob);
                u.x -= s * fminf(fmaxf(acc[j][0], -CLIP_), CLIP_);
                u.y -= s * fminf(fmaxf(acc[j][1], -CLIP_), CLIP_);
                *reinterpret_cast<float2*>(upd + ob) = u;
            }
        }
    }
    if (EPI == 2) block_reduce_write(esum, partial + blockIdx.x);
}

// ---------------- per-step finalize ----------------
__global__ __launch_bounds__(256) void finalize_k(const float* __restrict__ pF,
                                                  const float* __restrict__ p1,
                                                  const float* __restrict__ p2,
                                                  float* __restrict__ prev_e,
                                                  float* __restrict__ all_err,
                                                  int* __restrict__ conv,
                                                  int* __restrict__ iters,
                                                  int s) {
    __shared__ float sd[3 * 256];
    float aF = 0.f, a1 = 0.f, a2 = 0.f;
    for (int i = threadIdx.x; i < GF; i += 256) aF += pF[i];
    for (int i = threadIdx.x; i < G1; i += 256) a1 += p1[i];
    for (int i = threadIdx.x; i < G2; i += 256) a2 += p2[i];
    sd[threadIdx.x] = aF;
    sd[256 + threadIdx.x] = a1;
    sd[512 + threadIdx.x] = a2;
    __syncthreads();
#pragma unroll
    for (int off = 128; off > 0; off >>= 1) {
        if (threadIdx.x < off) {
            sd[threadIdx.x] += sd[threadIdx.x + off];
            sd[256 + threadIdx.x] += sd[256 + threadIdx.x + off];
            sd[512 + threadIdx.x] += sd[512 + threadIdx.x + off];
        }
        __syncthreads();
    }
    if (threadIdx.x == 0) {
        const float energy = sd[0] / (float)N_FR
                           + 0.1f * (sd[256] / (float)N_L1 + sd[512] / (float)N_L2);
        const int cv = conv[s];
        const float pe = prev_e[s];
        const float rel = fabsf(energy - pe) / (pe + 1e-8f);
        const int newly = (rel < THRESH_) && (iters[s] + 1 >= MINS);
        conv[s + 1] = cv | newly;
        iters[s + 1] = iters[s] + (cv ? 0 : 1);
        prev_e[s + 1] = cv ? pe : energy;
        all_err[s] = energy;
    }
}

__global__ __launch_bounds__(256) void copysq_k(const float* __restrict__ src,
                                                float* __restrict__ dst,
                                                float* __restrict__ partial) {
    const int i = blockIdx.x * 256 + threadIdx.x;
    const float v = src[i];
    dst[i] = v;
    block_reduce_write(v * v, partial + blockIdx.x);
}

__global__ __launch_bounds__(256) void tail_k(const float* __restrict__ pF,
                                              const float* __restrict__ p1,
                                              const float* __restrict__ p2,
                                              const float* __restrict__ pL1,
                                              const float* __restrict__ pL2,
                                              const float* __restrict__ all_err,
                                              const int* __restrict__ iters,
                                              float* __restrict__ out_sc) {
    __shared__ float sd[5 * 256];
    float aF = 0.f, a1 = 0.f, a2 = 0.f, aL1 = 0.f, aL2 = 0.f;
    for (int i = threadIdx.x; i < GF; i += 256) aF += pF[i];
    for (int i = threadIdx.x; i < G1; i += 256) a1 += p1[i];
    for (int i = threadIdx.x; i < G2; i += 256) a2 += p2[i];
    for (int i = threadIdx.x; i < N_L1 / 256; i += 256) aL1 += pL1[i];
    for (int i = threadIdx.x; i < N_L2 / 256; i += 256) aL2 += pL2[i];
    sd[threadIdx.x] = aF;
    sd[256 + threadIdx.x] = a1;
    sd[512 + threadIdx.x] = a2;
    sd[768 + threadIdx.x] = aL1;
    sd[1024 + threadIdx.x] = aL2;
    __syncthreads();
#pragma unroll
    for (int off = 128; off > 0; off >>= 1) {
        if (threadIdx.x < off) {
            sd[threadIdx.x] += sd[threadIdx.x + off];
            sd[256 + threadIdx.x] += sd[256 + threadIdx.x + off];
            sd[512 + threadIdx.x] += sd[512 + threadIdx.x + off];
            sd[768 + threadIdx.x] += sd[768 + threadIdx.x + off];
            sd[1024 + threadIdx.x] += sd[1024 + threadIdx.x + off];
        }
        __syncthreads();
    }
    if (threadIdx.x == 0) {
        const float eF  = sd[0] / (float)N_FR;
        const float e1  = 0.1f * (sd[256] / (float)N_L1);
        const float e2  = 0.1f * (sd[512] / (float)N_L2);
        const float reg = 1e-4f * (sd[768] / (float)N_L1 + sd[1024] / (float)N_L2);
        out_sc[0] = eF + e1 + e2 + reg;
        out_sc[1] = eF;
        out_sc[2] = e1;
        out_sc[3] = e2;
        out_sc[16] = (float)iters[12];
    }
    if (threadIdx.x < 12) out_sc[4 + threadIdx.x] = all_err[threadIdx.x];
}

// ---------------- host launch ----------------
extern "C" void kernel_launch(void* const* d_in, const int* in_sizes, int n_in,
                              void* d_out, int out_size, void* d_ws, size_t ws_size,
                              hipStream_t stream) {
    const float* frame_cur = (const float*)d_in[0];
    const float* frame_nxt = (const float*)d_in[1];
    const float* enc_w = (const float*)d_in[2];
    const float* enc_b = (const float*)d_in[3];
    const float* dec_w = (const float*)d_in[4];
    const float* dec_b = (const float*)d_in[5];
    const float* dn_w  = (const float*)d_in[6];
    const float* dn_b  = (const float*)d_in[7];
    const float* up_w  = (const float*)d_in[8];
    const float* up_b  = (const float*)d_in[9];
    const float* tr_w  = (const float*)d_in[10];
    const float* tr_b  = (const float*)d_in[11];
    const float* p1_w  = (const float*)d_in[12];
    const float* p1_b  = (const float*)d_in[13];
    const float* p2_w  = (const float*)d_in[14];
    const float* p2_b  = (const float*)d_in[15];
    const float* l11w  = (const float*)d_in[16];
    const float* l11b  = (const float*)d_in[17];
    const float* l12w  = (const float*)d_in[18];
    const float* l12b  = (const float*)d_in[19];
    const float* l21w  = (const float*)d_in[20];
    const float* l21b  = (const float*)d_in[21];
    const float* l22w  = (const float*)d_in[22];
    const float* l22b  = (const float*)d_in[23];

    // workspace layout (floats)
    float* ws = (float*)d_ws;
    float* l1p   = ws;               // N_L1
    float* l2p   = l1p + N_L1;       // N_L2
    float* l2i   = l2p + N_L2;       // N_L2
    float* ef    = l2i + N_L2;       // N_FR
    float* trans = ef + N_FR;        // N_L2
    float* e2    = trans + N_L2;     // N_L2
    float* upl   = e2 + N_L2;        // N_L1
    float* e1    = upl + N_L1;       // N_L1
    float* bu    = e1 + N_L1;        // N_L1
    float* g1    = bu + N_L1;        // N_G1
    float* g2    = g1 + N_G1;        // N_G2
    float* pF    = g2 + N_G2;        // 4096
    float* p1    = pF + 4096;        // 4096
    float* p2    = p1 + 4096;        // 4096
    float* pL1   = p2 + 4096;        // 4096
    float* pL2   = pL1 + 4096;       // 4096
    float* we    = pL2 + 4096;       // 12288 (decode folded weights)
    float* wt_tr  = we + 12288;       // 147456
    float* wt_p2  = wt_tr + 147456;   // 147456
    float* wt_up  = wt_p2 + 147456;   // 73728
    float* wt_p1  = wt_up + 73728;    // 36864
    float* wt_l11 = wt_p1 + 36864;    // 73728
    float* wt_l12 = wt_l11 + 73728;   // 73728
    float* wt_l21 = wt_l12 + 73728;   // 147456
    float* wt_l22 = wt_l21 + 147456;  // 147456
    float* prevE = wt_l22 + 147456;   // 16
    float* aerr  = prevE + 16;        // 16
    int*   conv  = (int*)(aerr + 16);
    int*   iters = conv + 16;

    // output layout (reference return order)
    float* o_fp = (float*)d_out;
    float* o_l1 = o_fp + N_FR;
    float* o_l2 = o_l1 + N_L1;
    float* o_ef = o_l2 + N_L2;
    float* o_e1 = o_ef + N_FR;
    float* o_e2 = o_e1 + N_L1;
    float* o_sc = o_e2 + N_L2;

    init_k<<<1, 1, 0, stream>>>(prevE, conv, iters);
    dec_pre_k<<<12, 256, 0, stream>>>(dec_w, we);
    wt_k<<<576, 256, 0, stream>>>(tr_w,  wt_tr,  128, 128);
    wt_k<<<576, 256, 0, stream>>>(p2_w,  wt_p2,  128, 128);
    wt_k<<<288, 256, 0, stream>>>(up_w,  wt_up,  128, 64);
    wt_k<<<144, 256, 0, stream>>>(p1_w,  wt_p1,  64,  64);
    wt_k<<<288, 256, 0, stream>>>(l11w,  wt_l11, 64,  128);
    wt_k<<<288, 256, 0, stream>>>(l12w,  wt_l12, 128, 64);
    wt_k<<<576, 256, 0, stream>>>(l21w,  wt_l21, 128, 128);
    wt_k<<<576, 256, 0, stream>>>(l22w,  wt_l22, 128, 128);

    encode_tile_k<<<NB_ * (Z1c / 16), 256, 0, stream>>>(frame_cur, enc_w, enc_b, l1p);
    down_k<<<GRID_DOWN, 256, 0, stream>>>(l1p, dn_w, dn_b, l2i, l2p);

    // grids: S=16 -> COG=16 (NCG = COUT/16); S=8 -> COG=32 (NCG = COUT/32)
    for (int s = 0; s < MAXS; ++s) {
        decode_tile_k<false><<<GF, 256, 0, stream>>>(l1p, we, dec_b, frame_nxt, ef, nullptr, pF);
        // trans = transition(l2p)
        conv_blk_k<Z2c, Z2c, 8, 32, 2, false, false, 0><<<NB_ * 4, 256, 0, stream>>>(
            l2p, nullptr, wt_tr, tr_b, nullptr, trans, nullptr, nullptr, nullptr);
        // e2 = l2p - pred2(trans)
        conv_blk_k<Z2c, Z2c, 8, 32, 2, false, false, 2><<<NB_ * 4, 256, 0, stream>>>(
            trans, nullptr, wt_p2, p2_b, l2p, e2, p2, nullptr, nullptr);
        // upl = up_l2_to_l1(l2p)
        conv_blk_k<Z2c, Z1c, 16, 16, 4, true, false, 0><<<NB_ * 4, 256, 0, stream>>>(
            l2p, nullptr, wt_up, up_b, nullptr, upl, nullptr, nullptr, nullptr);
        // e1 = l1p - pred1(upl)
        conv_blk_k<Z1c, Z1c, 16, 16, 4, false, false, 2><<<NB_ * 4, 256, 0, stream>>>(
            upl, nullptr, wt_p1, p1_b, l1p, e1, p1, nullptr, nullptr);
        // bu = encode(ef)
        encode_tile_k<<<NB_ * (Z1c / 16), 256, 0, stream>>>(ef, enc_w, enc_b, bu);
        // g1 = relu(conv(e1 + bu))
        conv_blk_k<Z1c, HIDc, 16, 16, 4, false, true, 1><<<NB_ * 8, 256, 0, stream>>>(
            e1, bu, wt_l11, l11b, nullptr, g1, nullptr, nullptr, nullptr);
        // l1p -= 0.1*clip(conv(g1)) if active
        conv_blk_k<HIDc, Z1c, 16, 16, 4, false, false, 3><<<NB_ * 4, 256, 0, stream>>>(
            g1, nullptr, wt_l12, l12b, nullptr, nullptr, nullptr, l1p, conv + s);
        // g2 = relu(conv(e2))
        conv_blk_k<Z2c, HIDc, 8, 32, 2, false, false, 1><<<NB_ * 4, 256, 0, stream>>>(
            e2, nullptr, wt_l21, l21b, nullptr, g2, nullptr, nullptr, nullptr);
        // l2p -= 0.1*clip(conv(g2)) if active
        conv_blk_k<HIDc, Z2c, 8, 32, 2, false, false, 3><<<NB_ * 4, 256, 0, stream>>>(
            g2, nullptr, wt_l22, l22b, nullptr, nullptr, nullptr, l2p, conv + s);
        finalize_k<<<1, 256, 0, stream>>>(pF, p1, p2, prevE, aerr, conv, iters, s);
    }

    // ---- tail (latent2_hat uses INITIAL latent2 = l2i) ----
    decode_tile_k<true><<<GF, 256, 0, stream>>>(l1p, we, dec_b, frame_nxt, o_ef, o_fp, pF);
    conv_blk_k<Z2c, Z2c, 8, 32, 2, false, false, 0><<<NB_ * 4, 256, 0, stream>>>(
        l2i, nullptr, wt_tr, tr_b, nullptr, trans, nullptr, nullptr, nullptr);
    conv_blk_k<Z2c, Z2c, 8, 32, 2, false, false, 2><<<NB_ * 4, 256, 0, stream>>>(
        trans, nullptr, wt_p2, p2_b, l2p, o_e2, p2, nullptr, nullptr);
    conv_blk_k<Z2c, Z1c, 16, 16, 4, true, false, 0><<<NB_ * 4, 256, 0, stream>>>(
        l2p, nullptr, wt_up, up_b, nullptr, upl, nullptr, nullptr, nullptr);
    conv_blk_k<Z1c, Z1c, 16, 16, 4, false, false, 2><<<NB_ * 4, 256, 0, stream>>>(
        upl, nullptr, wt_p1, p1_b, l1p, o_e1, p1, nullptr, nullptr);
    copysq_k<<<N_L1 / 256, 256, 0, stream>>>(l1p, o_l1, pL1);
    copysq_k<<<N_L2 / 256, 256, 0, stream>>>(l2p, o_l2, pL2);
    tail_k<<<1, 256, 0, stream>>>(pF, p1, p2, pL1, pL2, aerr, iters, o_sc);
}

// Round 7
// 5896.067 us; speedup vs baseline: 4.3009x; 1.7066x over previous
//
#include <hip/hip_runtime.h>

// ---------------- config (mirrors reference) ----------------
constexpr int NB_  = 64;
constexpr int CC   = 3;
constexpr int IMG  = 64;
constexpr int Z1c  = 64;
constexpr int Z2c  = 128;
constexpr int HIDc = 128;
constexpr int S1c  = 16;
constexpr int S2c  = 8;
constexpr int MAXS = 12;
constexpr int MINS = 3;
constexpr float THRESH_ = 1e-3f;
constexpr float ALPHA_  = 0.1f;
constexpr float CLIP_   = 1.0f;

constexpr int N_L1 = NB_ * Z1c * S1c * S1c;   // 1,048,576
constexpr int N_L2 = NB_ * Z2c * S2c * S2c;   //   524,288
constexpr int N_FR = NB_ * CC * IMG * IMG;    //   786,432
constexpr int N_G1 = NB_ * HIDc * S1c * S1c;  // 2,097,152
constexpr int N_G2 = NB_ * HIDc * S2c * S2c;  //   524,288

// reduction grid sizes (must match launch grids of EPI=2 kernels)
constexpr int GF = NB_ * CC;   // 192 decode blocks
constexpr int G1 = 256;        // p1 conv grid
constexpr int G2 = 256;        // p2 conv grid
constexpr int GRID_DOWN = (NB_ / 4) * Z2c;

// ---------------- helpers ----------------
__device__ __forceinline__ void block_reduce_write(float v, float* dst) {
    __shared__ float sd[256];
    sd[threadIdx.x] = v;
    __syncthreads();
#pragma unroll
    for (int off = 128; off > 0; off >>= 1) {
        if (threadIdx.x < off) sd[threadIdx.x] += sd[threadIdx.x + off];
        __syncthreads();
    }
    if (threadIdx.x == 0) *dst = sd[0];
}

__global__ void init_k(float* prev_e, int* conv, int* iters) {
    prev_e[0] = 1e30f;
    conv[0] = 0;
    iters[0] = 0;
}

// ---------------- weight transpose: [COUT][CIN][3][3] -> [CIN][9][COUT] ----------------
__global__ __launch_bounds__(256) void wt_k(const float* __restrict__ src,
                                            float* __restrict__ dst,
                                            int cin, int cout) {
    const int t = blockIdx.x * 256 + threadIdx.x;
    if (t >= cin * cout * 9) return;
    const int k  = t % 9;
    const int ci = (t / 9) % cin;
    const int co = t / (9 * cin);
    dst[(ci * 9 + k) * cout + co] = src[t];
}

// ---------------- decode weight phase-transform ----------------
__global__ __launch_bounds__(256) void dec_pre_k(const float* __restrict__ dw,
                                                 float* __restrict__ we) {
    const int t = blockIdx.x * 256 + threadIdx.x;
    if (t >= CC * Z1c * 16) return;
    const int px = t & 3, py = (t >> 2) & 3;
    const int ci = (t >> 4) % Z1c, c = t / (16 * Z1c);
    float w4[4] = {0.f, 0.f, 0.f, 0.f};
#pragma unroll
    for (int dy = 0; dy < 3; ++dy)
#pragma unroll
        for (int dx = 0; dx < 3; ++dx) {
            const int r = py + dy - 1, s = px + dx - 1;
            const int ty = (py == 0) ? ((r < 0) ? 0 : 1) : ((r >= 4) ? 1 : 0);
            const int tx = (px == 0) ? ((s < 0) ? 0 : 1) : ((s >= 4) ? 1 : 0);
            w4[ty * 2 + tx] += dw[((c * Z1c + ci) * 3 + dy) * 3 + dx];
        }
#pragma unroll
    for (int k = 0; k < 4; ++k) we[(size_t)t * 4 + k] = w4[k];
}

// ---------------- decode (LDS-staged, reg-prefetch, phase-folded) ----------------
template <bool TAIL>
__global__ __launch_bounds__(256) void decode_tile_k(const float* __restrict__ l1,
                                                     const float* __restrict__ we,
                                                     const float* __restrict__ db,
                                                     const float* __restrict__ fnext,
                                                     float* __restrict__ ef_out,
                                                     float* __restrict__ fp_out,
                                                     float* __restrict__ partial) {
    constexpr int CB = 16, HR = 18, HSW = 25;
    constexpr int TOT = CB * HR * HR;        // 5184
    constexpr int NLD = (TOT + 255) / 256;   // 21
    __shared__ __align__(16) float lds_in[CB * HR * HSW];
    __shared__ __align__(16) float lds_w[CB * 64];

    const int bid = blockIdx.x;            // b*3 + c
    const int b = bid / CC, c = bid % CC;
    const int tid = threadIdx.x;
    const int ty = tid >> 4, tx = tid & 15;
    const float* ibase = l1 + (size_t)b * Z1c * 256;

    float pf[NLD];
    auto fetch = [&](int cb) {
#pragma unroll
        for (int i = 0; i < NLD; ++i) {
            const int e = tid + i * 256;
            float v = 0.f;
            if (e < TOT) {
                const int cc2 = e / (HR * HR);
                const int rr = e - cc2 * (HR * HR);
                const int r = rr / HR, col = rr - r * HR;
                const int iy = r - 1, ix = col - 1;
                if ((unsigned)iy < 16u && (unsigned)ix < 16u)
                    v = ibase[(size_t)(cb + cc2) * 256 + iy * 16 + ix];
            }
            pf[i] = v;
        }
    };

    float acc[16];
#pragma unroll
    for (int k = 0; k < 16; ++k) acc[k] = 0.f;

    fetch(0);
#pragma unroll 1
    for (int cb = 0; cb < Z1c; cb += CB) {
        // write staged inputs
#pragma unroll
        for (int i = 0; i < NLD; ++i) {
            const int e = tid + i * 256;
            if (e < TOT) {
                const int cc2 = e / (HR * HR);
                const int rr = e - cc2 * (HR * HR);
                const int r = rr / HR, col = rr - r * HR;
                lds_in[cc2 * (HR * HSW) + r * HSW + col] = pf[i];
            }
        }
        // stage weight slice (contiguous CB*64 floats)
        {
            const float* wsrc = we + (size_t)(c * Z1c + cb) * 64;
#pragma unroll
            for (int i = 0; i < CB * 64 / 256; ++i) lds_w[tid + i * 256] = wsrc[tid + i * 256];
        }
        __syncthreads();
        if (cb + CB < Z1c) fetch(cb + CB);

#pragma unroll 2
        for (int c2 = 0; c2 < CB; ++c2) {
            const float* lp = lds_in + c2 * (HR * HSW);
            float ld[3][3];
#pragma unroll
            for (int ry = 0; ry < 3; ++ry)
#pragma unroll
                for (int rx = 0; rx < 3; ++rx)
                    ld[ry][rx] = lp[(ty + ry) * HSW + (tx + rx)];
            const float* wb_ = lds_w + c2 * 64;
#pragma unroll
            for (int py = 0; py < 4; ++py) {
                const int ry0 = (py == 0) ? 0 : 1;
#pragma unroll
                for (int px = 0; px < 4; ++px) {
                    const int rx0 = (px == 0) ? 0 : 1;
                    const float4 w4 = *reinterpret_cast<const float4*>(wb_ + (py * 4 + px) * 4);
                    float a = acc[py * 4 + px];
                    a = fmaf(ld[ry0][rx0],         w4.x, a);
                    a = fmaf(ld[ry0][rx0 + 1],     w4.y, a);
                    a = fmaf(ld[ry0 + 1][rx0],     w4.z, a);
                    a = fmaf(ld[ry0 + 1][rx0 + 1], w4.w, a);
                    acc[py * 4 + px] = a;
                }
            }
        }
        __syncthreads();
    }

    const float bias = db[c];
    float esum = 0.f;
#pragma unroll
    for (int py = 0; py < 4; ++py)
#pragma unroll
        for (int px = 0; px < 4; ++px) {
            const float fp = acc[py * 4 + px] + bias;
            const size_t idx = (size_t)bid * 4096 + (ty * 4 + py) * 64 + (tx * 4 + px);
            const float e = fnext[idx] - fp;
            ef_out[idx] = e;
            if (TAIL) fp_out[idx] = fp;
            esum += e * e;
        }
    block_reduce_write(esum, partial + bid);
}

// ---------------- encode ----------------
__global__ __launch_bounds__(256) void encode_tile_k(const float* __restrict__ in,
                                                     const float* __restrict__ w,
                                                     const float* __restrict__ bias,
                                                     float* __restrict__ out) {
    constexpr int ECOG = 16;
    constexpr int NCG = Z1c / ECOG;
    const int b = blockIdx.x / NCG, cg = blockIdx.x % NCG;
    const int co_base = cg * ECOG;
    const int y = threadIdx.x >> 4, x = threadIdx.x & 15;
    float acc[ECOG];
#pragma unroll
    for (int j = 0; j < ECOG; ++j) acc[j] = bias[co_base + j];
    for (int ci = 0; ci < CC; ++ci) {
        float p[16];
        const float* ip = in + ((size_t)(b * CC + ci) * IMG + y * 4) * IMG + x * 4;
#pragma unroll
        for (int ky = 0; ky < 4; ++ky)
#pragma unroll
            for (int kx = 0; kx < 4; ++kx) p[ky * 4 + kx] = ip[ky * IMG + kx];
        const float* wp = w + (size_t)(co_base * CC + ci) * 16;
#pragma unroll
        for (int j = 0; j < ECOG; ++j) {
            const float* wj = wp + (size_t)j * CC * 16;
            float a = acc[j];
#pragma unroll
            for (int k = 0; k < 16; ++k) a = fmaf(p[k], wj[k], a);
            acc[j] = a;
        }
    }
#pragma unroll
    for (int j = 0; j < ECOG; ++j)
        out[((size_t)(b * Z1c + co_base + j) * S1c + y) * S1c + x] = acc[j];
}

// ---------------- initial downsample (once) ----------------
__global__ __launch_bounds__(256) void down_k(const float* __restrict__ in,
                                              const float* __restrict__ w,
                                              const float* __restrict__ bias,
                                              float* __restrict__ out1,
                                              float* __restrict__ out2) {
    const int co = blockIdx.x % Z2c;
    const int bg = blockIdx.x / Z2c;
    const int bl = threadIdx.x >> 6;
    const int pos = threadIdx.x & 63;
    const int b = bg * 4 + bl;
    const int y = pos >> 3, x = pos & 7;
    float acc = bias[co];
    const float* wc = w + (size_t)co * Z1c * 9;
    for (int ci = 0; ci < Z1c; ++ci) {
        const float* ip = in + (size_t)(b * Z1c + ci) * 256;
        float wv[9];
#pragma unroll
        for (int t = 0; t < 9; ++t) wv[t] = wc[t];
#pragma unroll
        for (int dy = 0; dy < 3; ++dy) {
            const int yy = 2 * y + dy;
            if (yy < 16) {
#pragma unroll
                for (int dx = 0; dx < 3; ++dx) {
                    const int xx = 2 * x + dx;
                    if (xx < 16) acc = fmaf(ip[yy * 16 + xx], wv[dy * 3 + dx], acc);
                }
            }
        }
        wc += 9;
    }
    const int oidx = ((b * Z2c + co) * S2c + y) * S2c + x;
    out1[oidx] = acc;
    out2[oidx] = acc;
}

// ---------------- register-tiled 3x3 conv, reg-prefetch + LDS weights ----------------
// Thread: ACCN=4 co x P x-positions. Per cb-iteration: write prefetched input
// regs -> LDS, stage weight slice -> LDS, barrier, issue next input prefetch,
// compute (scalar b32 LDS input reads at stride 25/13 = <=2-way conflicts,
// broadcast b128 LDS weight reads). Accumulation order identical to round 5.
// EPI: 0 store, 1 relu, 2 e=ref-acc (+partial), 3 clip-update
template <int CIN, int COUT, int S, int CB, int P, bool UP2, bool IN2ADD, int EPI>
__global__ __launch_bounds__(256) void conv_blk_k(const float* __restrict__ in,
                                                  const float* __restrict__ in2,
                                                  const float* __restrict__ wt,
                                                  const float* __restrict__ bias,
                                                  const float* __restrict__ ref,
                                                  float* __restrict__ out,
                                                  float* __restrict__ partial,
                                                  float* __restrict__ upd,
                                                  const int* __restrict__ cflag) {
    constexpr int ACCN = 4;
    constexpr int SP  = S * S;
    constexpr int XB  = S / P;
    constexpr int TPP = S * XB;
    constexpr int NG  = 256 / TPP;
    constexpr int COG = NG * ACCN;
    constexpr int NCG = COUT / COG;
    constexpr int HR  = S + 2;
    constexpr int HSW = (S == 16) ? 25 : 13;   // co-prime with 32 -> conflict-free b32
    constexpr int SIN = UP2 ? (S / 2) : S;
    constexpr int TOT = CB * HR * HR;
    constexpr int NLD = (TOT + 255) / 256;
    constexpr int WTOT = CB * 9 * COG;
    static_assert(TPP * NG == 256 && COG * NCG == COUT && S % P == 0, "bad blocking");
    static_assert(CIN % CB == 0 && (WTOT % 256) == 0, "bad blocking");

    __shared__ __align__(16) float lds_in[CB * HR * HSW];
    __shared__ __align__(16) float lds_w[WTOT];

    // XCD-locality swizzle: grid = 64 * NCG; XCD x owns batches {x, x+8, ...}
    const int l  = blockIdx.x;
    const int j8 = l >> 3;
    const int b  = (l & 7) + 8 * (j8 / NCG);
    const int cg = j8 % NCG;

    const int tid = threadIdx.x;
    const int local = tid % TPP;
    const int g     = tid / TPP;
    const int y  = local / XB;
    const int x0 = (local % XB) * P;
    const int co_base = cg * COG + g * ACCN;

    float pf[NLD];
    auto fetch = [&](int cb) {
#pragma unroll
        for (int i = 0; i < NLD; ++i) {
            const int e = tid + i * 256;
            float v = 0.f;
            if (e < TOT) {
                const int c  = e / (HR * HR);
                const int rr = e - c * (HR * HR);
                const int r  = rr / HR, col = rr - r * HR;
                const int iy = r - 1, ix = col - 1;
                if ((unsigned)iy < (unsigned)S && (unsigned)ix < (unsigned)S) {
                    const int ci = cb + c;
                    if (UP2)
                        v = in[(size_t)(b * CIN + ci) * (SIN * SIN) + (iy >> 1) * SIN + (ix >> 1)];
                    else
                        v = in[(size_t)(b * CIN + ci) * SP + iy * S + ix];
                    if (IN2ADD)
                        v += in2[(size_t)(b * CIN + ci) * SP + iy * S + ix];
                }
            }
            pf[i] = v;
        }
    };

    float acc[ACCN][P];
#pragma unroll
    for (int j = 0; j < ACCN; ++j)
#pragma unroll
        for (int p = 0; p < P; ++p) acc[j][p] = bias[co_base + j];

    int cf = 0;
    if (EPI == 3) cf = *cflag;

    fetch(0);
#pragma unroll 1
    for (int cb = 0; cb < CIN; cb += CB) {
        // write prefetched inputs to LDS
#pragma unroll
        for (int i = 0; i < NLD; ++i) {
            const int e = tid + i * 256;
            if (e < TOT) {
                const int c  = e / (HR * HR);
                const int rr = e - c * (HR * HR);
                const int r  = rr / HR, col = rr - r * HR;
                lds_in[c * (HR * HSW) + r * HSW + col] = pf[i];
            }
        }
        // stage weight slice: rows (cb*9 .. cb*9+CB*9) x [cg*COG, +COG)
        {
            const float* wsrc = wt + (size_t)cb * 9 * COUT + cg * COG;
#pragma unroll
            for (int i = 0; i < WTOT / 256; ++i) {
                const int e = tid + i * 256;
                const int row = e / COG;
                const int col = e - row * COG;
                lds_w[e] = wsrc[(size_t)row * COUT + col];
            }
        }
        __syncthreads();
        if (cb + CB < CIN) fetch(cb + CB);

#pragma unroll 2
        for (int c = 0; c < CB; ++c) {
            const float* lp = lds_in + c * (HR * HSW) + y * HSW + x0;
            float w[3][P + 2];
#pragma unroll
            for (int dy = 0; dy < 3; ++dy)
#pragma unroll
                for (int j = 0; j < P + 2; ++j) w[dy][j] = lp[dy * HSW + j];
            const float* wr = lds_w + c * 9 * COG + g * ACCN;
#pragma unroll
            for (int k = 0; k < 9; ++k) {
                const int dy = k / 3, dx = k % 3;
                const float4 wv = *reinterpret_cast<const float4*>(wr + k * COG);
#pragma unroll
                for (int p = 0; p < P; ++p) {
                    const float v = w[dy][dx + p];
                    acc[0][p] = fmaf(v, wv.x, acc[0][p]);
                    acc[1][p] = fmaf(v, wv.y, acc[1][p]);
                    acc[2][p] = fmaf(v, wv.z, acc[2][p]);
                    acc[3][p] = fmaf(v, wv.w, acc[3][p]);
                }
            }
        }
        __syncthreads();
    }

    // ---- vectorized epilogue ----
    float esum = 0.f;
#pragma unroll
    for (int j = 0; j < ACCN; ++j) {
        const int co = co_base + j;
        const size_t ob = (size_t)(b * COUT + co) * SP + y * S + x0;
        if constexpr (EPI == 0 || EPI == 1) {
            if constexpr (P == 4) {
                float4 v;
                v.x = acc[j][0]; v.y = acc[j][1]; v.z = acc[j][2]; v.w = acc[j][3];
                if (EPI == 1) {
                    v.x = fmaxf(v.x, 0.f); v.y = fmaxf(v.y, 0.f);
                    v.z = fmaxf(v.z, 0.f); v.w = fmaxf(v.w, 0.f);
                }
                *reinterpret_cast<float4*>(out + ob) = v;
            } else {
                float2 v;
                v.x = acc[j][0]; v.y = acc[j][1];
                if (EPI == 1) { v.x = fmaxf(v.x, 0.f); v.y = fmaxf(v.y, 0.f); }
                *reinterpret_cast<float2*>(out + ob) = v;
            }
        } else if constexpr (EPI == 2) {
            if constexpr (P == 4) {
                const float4 r = *reinterpret_cast<const float4*>(ref + ob);
                float4 e;
                e.x = r.x - acc[j][0]; e.y = r.y - acc[j][1];
                e.z = r.z - acc[j][2]; e.w = r.w - acc[j][3];
                *reinterpret_cast<float4*>(out + ob) = e;
                esum += e.x * e.x + e.y * e.y + e.z * e.z + e.w * e.w;
            } else {
                const float2 r = *reinterpret_cast<const float2*>(ref + ob);
                float2 e;
                e.x = r.x - acc[j][0]; e.y = r.y - acc[j][1];
                *reinterpret_cast<float2*>(out + ob) = e;
                esum += e.x * e.x + e.y * e.y;
            }
        } else {  // EPI == 3
            const float s = cf ? 0.f : ALPHA_;
            if constexpr (P == 4) {
                float4 u = *reinterpret_cast<float4*>(upd + ob);
                u.x -= s * fminf(fmaxf(acc[j][0], -CLIP_), CLIP_);
                u.y -= s * fminf(fmaxf(acc[j][1], -CLIP_), CLIP_);
                u.z -= s * fminf(fmaxf(acc[j][2], -CLIP_), CLIP_);
                u.w -= s * fminf(fmaxf(acc[j][3], -CLIP_), CLIP_);
                *reinterpret_cast<float4*>(upd + ob) = u;
            } else {
                float2 u = *reinterpret_cast<float2*>(upd + ob);
                u.x -= s * fminf(fmaxf(acc[j][0], -CLIP_), CLIP_);
                u.y -= s * fminf(fmaxf(acc[j][1], -CLIP_), CLIP_);
                *reinterpret_cast<float2*>(upd + ob) = u;
            }
        }
    }
    if (EPI == 2) block_reduce_write(esum, partial + blockIdx.x);
}

// ---------------- per-step finalize ----------------
__global__ __launch_bounds__(256) void finalize_k(const float* __restrict__ pF,
                                                  const float* __restrict__ p1,
                                                  const float* __restrict__ p2,
                                                  float* __restrict__ prev_e,
                                                  float* __restrict__ all_err,
                                                  int* __restrict__ conv,
                                                  int* __restrict__ iters,
                                                  int s) {
    __shared__ float sd[3 * 256];
    float aF = 0.f, a1 = 0.f, a2 = 0.f;
    for (int i = threadIdx.x; i < GF; i += 256) aF += pF[i];
    for (int i = threadIdx.x; i < G1; i += 256) a1 += p1[i];
    for (int i = threadIdx.x; i < G2; i += 256) a2 += p2[i];
    sd[threadIdx.x] = aF;
    sd[256 + threadIdx.x] = a1;
    sd[512 + threadIdx.x] = a2;
    __syncthreads();
#pragma unroll
    for (int off = 128; off > 0; off >>= 1) {
        if (threadIdx.x < off) {
            sd[threadIdx.x] += sd[threadIdx.x + off];
            sd[256 + threadIdx.x] += sd[256 + threadIdx.x + off];
            sd[512 + threadIdx.x] += sd[512 + threadIdx.x + off];
        }
        __syncthreads();
    }
    if (threadIdx.x == 0) {
        const float energy = sd[0] / (float)N_FR
                           + 0.1f * (sd[256] / (float)N_L1 + sd[512] / (float)N_L2);
        const int cv = conv[s];
        const float pe = prev_e[s];
        const float rel = fabsf(energy - pe) / (pe + 1e-8f);
        const int newly = (rel < THRESH_) && (iters[s] + 1 >= MINS);
        conv[s + 1] = cv | newly;
        iters[s + 1] = iters[s] + (cv ? 0 : 1);
        prev_e[s + 1] = cv ? pe : energy;
        all_err[s] = energy;
    }
}

__global__ __launch_bounds__(256) void copysq_k(const float* __restrict__ src,
                                                float* __restrict__ dst,
                                                float* __restrict__ partial) {
    const int i = blockIdx.x * 256 + threadIdx.x;
    const float v = src[i];
    dst[i] = v;
    block_reduce_write(v * v, partial + blockIdx.x);
}

__global__ __launch_bounds__(256) void tail_k(const float* __restrict__ pF,
                                              const float* __restrict__ p1,
                                              const float* __restrict__ p2,
                                              const float* __restrict__ pL1,
                                              const float* __restrict__ pL2,
                                              const float* __restrict__ all_err,
                                              const int* __restrict__ iters,
                                              float* __restrict__ out_sc) {
    __shared__ float sd[5 * 256];
    float aF = 0.f, a1 = 0.f, a2 = 0.f, aL1 = 0.f, aL2 = 0.f;
    for (int i = threadIdx.x; i < GF; i += 256) aF += pF[i];
    for (int i = threadIdx.x; i < G1; i += 256) a1 += p1[i];
    for (int i = threadIdx.x; i < G2; i += 256) a2 += p2[i];
    for (int i = threadIdx.x; i < N_L1 / 256; i += 256) aL1 += pL1[i];
    for (int i = threadIdx.x; i < N_L2 / 256; i += 256) aL2 += pL2[i];
    sd[threadIdx.x] = aF;
    sd[256 + threadIdx.x] = a1;
    sd[512 + threadIdx.x] = a2;
    sd[768 + threadIdx.x] = aL1;
    sd[1024 + threadIdx.x] = aL2;
    __syncthreads();
#pragma unroll
    for (int off = 128; off > 0; off >>= 1) {
        if (threadIdx.x < off) {
            sd[threadIdx.x] += sd[threadIdx.x + off];
            sd[256 + threadIdx.x] += sd[256 + threadIdx.x + off];
            sd[512 + threadIdx.x] += sd[512 + threadIdx.x + off];
            sd[768 + threadIdx.x] += sd[768 + threadIdx.x + off];
            sd[1024 + threadIdx.x] += sd[1024 + threadIdx.x + off];
        }
        __syncthreads();
    }
    if (threadIdx.x == 0) {
        const float eF  = sd[0] / (float)N_FR;
        const float e1  = 0.1f * (sd[256] / (float)N_L1);
        const float e2  = 0.1f * (sd[512] / (float)N_L2);
        const float reg = 1e-4f * (sd[768] / (float)N_L1 + sd[1024] / (float)N_L2);
        out_sc[0] = eF + e1 + e2 + reg;
        out_sc[1] = eF;
        out_sc[2] = e1;
        out_sc[3] = e2;
        out_sc[16] = (float)iters[12];
    }
    if (threadIdx.x < 12) out_sc[4 + threadIdx.x] = all_err[threadIdx.x];
}

// ---------------- host launch ----------------
extern "C" void kernel_launch(void* const* d_in, const int* in_sizes, int n_in,
                              void* d_out, int out_size, void* d_ws, size_t ws_size,
                              hipStream_t stream) {
    const float* frame_cur = (const float*)d_in[0];
    const float* frame_nxt = (const float*)d_in[1];
    const float* enc_w = (const float*)d_in[2];
    const float* enc_b = (const float*)d_in[3];
    const float* dec_w = (const float*)d_in[4];
    const float* dec_b = (const float*)d_in[5];
    const float* dn_w  = (const float*)d_in[6];
    const float* dn_b  = (const float*)d_in[7];
    const float* up_w  = (const float*)d_in[8];
    const float* up_b  = (const float*)d_in[9];
    const float* tr_w  = (const float*)d_in[10];
    const float* tr_b  = (const float*)d_in[11];
    const float* p1_w  = (const float*)d_in[12];
    const float* p1_b  = (const float*)d_in[13];
    const float* p2_w  = (const float*)d_in[14];
    const float* p2_b  = (const float*)d_in[15];
    const float* l11w  = (const float*)d_in[16];
    const float* l11b  = (const float*)d_in[17];
    const float* l12w  = (const float*)d_in[18];
    const float* l12b  = (const float*)d_in[19];
    const float* l21w  = (const float*)d_in[20];
    const float* l21b  = (const float*)d_in[21];
    const float* l22w  = (const float*)d_in[22];
    const float* l22b  = (const float*)d_in[23];

    // workspace layout (floats)
    float* ws = (float*)d_ws;
    float* l1p   = ws;               // N_L1
    float* l2p   = l1p + N_L1;       // N_L2
    float* l2i   = l2p + N_L2;       // N_L2
    float* ef    = l2i + N_L2;       // N_FR
    float* trans = ef + N_FR;        // N_L2
    float* e2    = trans + N_L2;     // N_L2
    float* upl   = e2 + N_L2;        // N_L1
    float* e1    = upl + N_L1;       // N_L1
    float* bu    = e1 + N_L1;        // N_L1
    float* g1    = bu + N_L1;        // N_G1
    float* g2    = g1 + N_G1;        // N_G2
    float* pF    = g2 + N_G2;        // 4096
    float* p1    = pF + 4096;        // 4096
    float* p2    = p1 + 4096;        // 4096
    float* pL1   = p2 + 4096;        // 4096
    float* pL2   = pL1 + 4096;       // 4096
    float* we    = pL2 + 4096;       // 12288 (decode folded weights)
    float* wt_tr  = we + 12288;       // 147456
    float* wt_p2  = wt_tr + 147456;   // 147456
    float* wt_up  = wt_p2 + 147456;   // 73728
    float* wt_p1  = wt_up + 73728;    // 36864
    float* wt_l11 = wt_p1 + 36864;    // 73728
    float* wt_l12 = wt_l11 + 73728;   // 73728
    float* wt_l21 = wt_l12 + 73728;   // 147456
    float* wt_l22 = wt_l21 + 147456;  // 147456
    float* prevE = wt_l22 + 147456;   // 16
    float* aerr  = prevE + 16;        // 16
    int*   conv  = (int*)(aerr + 16);
    int*   iters = conv + 16;

    // output layout (reference return order)
    float* o_fp = (float*)d_out;
    float* o_l1 = o_fp + N_FR;
    float* o_l2 = o_l1 + N_L1;
    float* o_ef = o_l2 + N_L2;
    float* o_e1 = o_ef + N_FR;
    float* o_e2 = o_e1 + N_L1;
    float* o_sc = o_e2 + N_L2;

    init_k<<<1, 1, 0, stream>>>(prevE, conv, iters);
    dec_pre_k<<<12, 256, 0, stream>>>(dec_w, we);
    wt_k<<<576, 256, 0, stream>>>(tr_w,  wt_tr,  128, 128);
    wt_k<<<576, 256, 0, stream>>>(p2_w,  wt_p2,  128, 128);
    wt_k<<<288, 256, 0, stream>>>(up_w,  wt_up,  128, 64);
    wt_k<<<144, 256, 0, stream>>>(p1_w,  wt_p1,  64,  64);
    wt_k<<<288, 256, 0, stream>>>(l11w,  wt_l11, 64,  128);
    wt_k<<<288, 256, 0, stream>>>(l12w,  wt_l12, 128, 64);
    wt_k<<<576, 256, 0, stream>>>(l21w,  wt_l21, 128, 128);
    wt_k<<<576, 256, 0, stream>>>(l22w,  wt_l22, 128, 128);

    encode_tile_k<<<NB_ * (Z1c / 16), 256, 0, stream>>>(frame_cur, enc_w, enc_b, l1p);
    down_k<<<GRID_DOWN, 256, 0, stream>>>(l1p, dn_w, dn_b, l2i, l2p);

    for (int s = 0; s < MAXS; ++s) {
        decode_tile_k<false><<<GF, 256, 0, stream>>>(l1p, we, dec_b, frame_nxt, ef, nullptr, pF);
        // trans = transition(l2p)
        conv_blk_k<Z2c, Z2c, 8, 32, 2, false, false, 0><<<NB_ * 4, 256, 0, stream>>>(
            l2p, nullptr, wt_tr, tr_b, nullptr, trans, nullptr, nullptr, nullptr);
        // e2 = l2p - pred2(trans)
        conv_blk_k<Z2c, Z2c, 8, 32, 2, false, false, 2><<<NB_ * 4, 256, 0, stream>>>(
            trans, nullptr, wt_p2, p2_b, l2p, e2, p2, nullptr, nullptr);
        // upl = up_l2_to_l1(l2p)
        conv_blk_k<Z2c, Z1c, 16, 16, 4, true, false, 0><<<NB_ * 4, 256, 0, stream>>>(
            l2p, nullptr, wt_up, up_b, nullptr, upl, nullptr, nullptr, nullptr);
        // e1 = l1p - pred1(upl)
        conv_blk_k<Z1c, Z1c, 16, 16, 4, false, false, 2><<<NB_ * 4, 256, 0, stream>>>(
            upl, nullptr, wt_p1, p1_b, l1p, e1, p1, nullptr, nullptr);
        // bu = encode(ef)
        encode_tile_k<<<NB_ * (Z1c / 16), 256, 0, stream>>>(ef, enc_w, enc_b, bu);
        // g1 = relu(conv(e1 + bu))
        conv_blk_k<Z1c, HIDc, 16, 16, 4, false, true, 1><<<NB_ * 8, 256, 0, stream>>>(
            e1, bu, wt_l11, l11b, nullptr, g1, nullptr, nullptr, nullptr);
        // l1p -= 0.1*clip(conv(g1)) if active
        conv_blk_k<HIDc, Z1c, 16, 16, 4, false, false, 3><<<NB_ * 4, 256, 0, stream>>>(
            g1, nullptr, wt_l12, l12b, nullptr, nullptr, nullptr, l1p, conv + s);
        // g2 = relu(conv(e2))
        conv_blk_k<Z2c, HIDc, 8, 32, 2, false, false, 1><<<NB_ * 4, 256, 0, stream>>>(
            e2, nullptr, wt_l21, l21b, nullptr, g2, nullptr, nullptr, nullptr);
        // l2p -= 0.1*clip(conv(g2)) if active
        conv_blk_k<HIDc, Z2c, 8, 32, 2, false, false, 3><<<NB_ * 4, 256, 0, stream>>>(
            g2, nullptr, wt_l22, l22b, nullptr, nullptr, nullptr, l2p, conv + s);
        finalize_k<<<1, 256, 0, stream>>>(pF, p1, p2, prevE, aerr, conv, iters, s);
    }

    // ---- tail (latent2_hat uses INITIAL latent2 = l2i) ----
    decode_tile_k<true><<<GF, 256, 0, stream>>>(l1p, we, dec_b, frame_nxt, o_ef, o_fp, pF);
    conv_blk_k<Z2c, Z2c, 8, 32, 2, false, false, 0><<<NB_ * 4, 256, 0, stream>>>(
        l2i, nullptr, wt_tr, tr_b, nullptr, trans, nullptr, nullptr, nullptr);
    conv_blk_k<Z2c, Z2c, 8, 32, 2, false, false, 2><<<NB_ * 4, 256, 0, stream>>>(
        trans, nullptr, wt_p2, p2_b, l2p, o_e2, p2, nullptr, nullptr);
    conv_blk_k<Z2c, Z1c, 16, 16, 4, true, false, 0><<<NB_ * 4, 256, 0, stream>>>(
        l2p, nullptr, wt_up, up_b, nullptr, upl, nullptr, nullptr, nullptr);
    conv_blk_k<Z1c, Z1c, 16, 16, 4, false, false, 2><<<NB_ * 4, 256, 0, stream>>>(
        upl, nullptr, wt_p1, p1_b, l1p, o_e1, p1, nullptr, nullptr);
    copysq_k<<<N_L1 / 256, 256, 0, stream>>>(l1p, o_l1, pL1);
    copysq_k<<<N_L2 / 256, 256, 0, stream>>>(l2p, o_l2, pL2);
    tail_k<<<1, 256, 0, stream>>>(pF, p1, p2, pL1, pL2, aerr, iters, o_sc);
}

// Round 8
// 4087.140 us; speedup vs baseline: 6.2045x; 1.4426x over previous
//
#include <hip/hip_runtime.h>

// ---------------- config (mirrors reference) ----------------
constexpr int NB_  = 64;
constexpr int CC   = 3;
constexpr int IMG  = 64;
constexpr int Z1c  = 64;
constexpr int Z2c  = 128;
constexpr int HIDc = 128;
constexpr int S1c  = 16;
constexpr int S2c  = 8;
constexpr int MAXS = 12;
constexpr int MINS = 3;
constexpr float THRESH_ = 1e-3f;
constexpr float ALPHA_  = 0.1f;
constexpr float CLIP_   = 1.0f;

constexpr int N_L1 = NB_ * Z1c * S1c * S1c;   // 1,048,576
constexpr int N_L2 = NB_ * Z2c * S2c * S2c;   //   524,288
constexpr int N_FR = NB_ * CC * IMG * IMG;    //   786,432
constexpr int N_G1 = NB_ * HIDc * S1c * S1c;  // 2,097,152
constexpr int N_G2 = NB_ * HIDc * S2c * S2c;  //   524,288

constexpr int GF  = NB_ * CC;   // 192 decode blocks
constexpr int G1  = 256;        // p1 partial count
constexpr int G2  = 256;        // p2 partial count
constexpr int GL1 = 1024;       // copysq4 l1 partial count
constexpr int GL2 = 512;        // copysq4 l2 partial count
constexpr int GRID_DOWN = (NB_ / 4) * Z2c;

constexpr int SMEM_MAX = 53504; // max over all fused bodies (S=8 conv, CB=32)

// ---------------- reduction (uses caller-provided scratch) ----------------
__device__ __forceinline__ void reduce_write(float* sd, float v, float* dst) {
    sd[threadIdx.x] = v;
    __syncthreads();
#pragma unroll
    for (int off = 128; off > 0; off >>= 1) {
        if (threadIdx.x < off) sd[threadIdx.x] += sd[threadIdx.x + off];
        __syncthreads();
    }
    if (threadIdx.x == 0) *dst = sd[0];
}

// ---------------- prep bodies ----------------
__device__ __forceinline__ void init_body(float* prev_e, int* conv, int* iters) {
    if (threadIdx.x == 0) { prev_e[0] = 1e30f; conv[0] = 0; iters[0] = 0; }
}

__device__ __forceinline__ void wt_body(int vbid, const float* __restrict__ src,
                                        float* __restrict__ dst, int cin, int cout) {
    const int t = vbid * 256 + threadIdx.x;   // grid sized exactly: no bound check
    const int k  = t % 9;
    const int ci = (t / 9) % cin;
    const int co = t / (9 * cin);
    dst[(ci * 9 + k) * cout + co] = src[t];
}

__device__ __forceinline__ void dec_pre_body(int vbid, const float* __restrict__ dw,
                                             float* __restrict__ we) {
    const int t = vbid * 256 + threadIdx.x;   // exactly 12*256 = 3072
    const int px = t & 3, py = (t >> 2) & 3;
    const int ci = (t >> 4) % Z1c, c = t / (16 * Z1c);
    float w4[4] = {0.f, 0.f, 0.f, 0.f};
#pragma unroll
    for (int dy = 0; dy < 3; ++dy)
#pragma unroll
        for (int dx = 0; dx < 3; ++dx) {
            const int r = py + dy - 1, s = px + dx - 1;
            const int ty = (py == 0) ? ((r < 0) ? 0 : 1) : ((r >= 4) ? 1 : 0);
            const int tx = (px == 0) ? ((s < 0) ? 0 : 1) : ((s >= 4) ? 1 : 0);
            w4[ty * 2 + tx] += dw[((c * Z1c + ci) * 3 + dy) * 3 + dx];
        }
#pragma unroll
    for (int k = 0; k < 4; ++k) we[(size_t)t * 4 + k] = w4[k];
}

// ---------------- decode body (LDS-staged, reg-prefetch, phase-folded) ----------------
template <bool TAIL>
__device__ __forceinline__ void decode_body(char* smem, int bid,
                                            const float* __restrict__ l1,
                                            const float* __restrict__ we,
                                            const float* __restrict__ db,
                                            const float* __restrict__ fnext,
                                            float* __restrict__ ef_out,
                                            float* __restrict__ fp_out,
                                            float* __restrict__ partial) {
    constexpr int CB = 16, HR = 18, HSW = 25;
    constexpr int TOT = CB * HR * HR;        // 5184
    constexpr int NLD = (TOT + 255) / 256;   // 21
    float* lds_in = (float*)smem;                 // 16*18*25*4 = 28800 B
    float* lds_w  = (float*)(smem + CB * HR * HSW * 4);  // 4096 B

    const int b = bid / CC, c = bid % CC;
    const int tid = threadIdx.x;
    const int ty = tid >> 4, tx = tid & 15;
    const float* ibase = l1 + (size_t)b * Z1c * 256;

    float pf[NLD];
    auto fetch = [&](int cb) {
#pragma unroll
        for (int i = 0; i < NLD; ++i) {
            const int e = tid + i * 256;
            float v = 0.f;
            if (e < TOT) {
                const int cc2 = e / (HR * HR);
                const int rr = e - cc2 * (HR * HR);
                const int r = rr / HR, col = rr - r * HR;
                const int iy = r - 1, ix = col - 1;
                if ((unsigned)iy < 16u && (unsigned)ix < 16u)
                    v = ibase[(size_t)(cb + cc2) * 256 + iy * 16 + ix];
            }
            pf[i] = v;
        }
    };

    float acc[16];
#pragma unroll
    for (int k = 0; k < 16; ++k) acc[k] = 0.f;

    fetch(0);
#pragma unroll 1
    for (int cb = 0; cb < Z1c; cb += CB) {
#pragma unroll
        for (int i = 0; i < NLD; ++i) {
            const int e = tid + i * 256;
            if (e < TOT) {
                const int cc2 = e / (HR * HR);
                const int rr = e - cc2 * (HR * HR);
                const int r = rr / HR, col = rr - r * HR;
                lds_in[cc2 * (HR * HSW) + r * HSW + col] = pf[i];
            }
        }
        {
            const float* wsrc = we + (size_t)(c * Z1c + cb) * 64;
#pragma unroll
            for (int i = 0; i < CB * 64 / 256; ++i) lds_w[tid + i * 256] = wsrc[tid + i * 256];
        }
        __syncthreads();
        if (cb + CB < Z1c) fetch(cb + CB);

#pragma unroll 2
        for (int c2 = 0; c2 < CB; ++c2) {
            const float* lp = lds_in + c2 * (HR * HSW);
            float ld[3][3];
#pragma unroll
            for (int ry = 0; ry < 3; ++ry)
#pragma unroll
                for (int rx = 0; rx < 3; ++rx)
                    ld[ry][rx] = lp[(ty + ry) * HSW + (tx + rx)];
            const float* wb_ = lds_w + c2 * 64;
#pragma unroll
            for (int py = 0; py < 4; ++py) {
                const int ry0 = (py == 0) ? 0 : 1;
#pragma unroll
                for (int px = 0; px < 4; ++px) {
                    const int rx0 = (px == 0) ? 0 : 1;
                    const float4 w4 = *reinterpret_cast<const float4*>(wb_ + (py * 4 + px) * 4);
                    float a = acc[py * 4 + px];
                    a = fmaf(ld[ry0][rx0],         w4.x, a);
                    a = fmaf(ld[ry0][rx0 + 1],     w4.y, a);
                    a = fmaf(ld[ry0 + 1][rx0],     w4.z, a);
                    a = fmaf(ld[ry0 + 1][rx0 + 1], w4.w, a);
                    acc[py * 4 + px] = a;
                }
            }
        }
        __syncthreads();
    }

    const float bias = db[c];
    float esum = 0.f;
#pragma unroll
    for (int py = 0; py < 4; ++py)
#pragma unroll
        for (int px = 0; px < 4; ++px) {
            const float fp = acc[py * 4 + px] + bias;
            const size_t idx = (size_t)bid * 4096 + (ty * 4 + py) * 64 + (tx * 4 + px);
            const float e = fnext[idx] - fp;
            ef_out[idx] = e;
            if (TAIL) fp_out[idx] = fp;
            esum += e * e;
        }
    reduce_write((float*)smem, esum, partial + bid);
}

// ---------------- encode body ----------------
__device__ __forceinline__ void encode_body(int bid, const float* __restrict__ in,
                                            const float* __restrict__ w,
                                            const float* __restrict__ bias,
                                            float* __restrict__ out) {
    constexpr int ECOG = 16;
    constexpr int NCG = Z1c / ECOG;
    const int b = bid / NCG, cg = bid % NCG;
    const int co_base = cg * ECOG;
    const int y = threadIdx.x >> 4, x = threadIdx.x & 15;
    float acc[ECOG];
#pragma unroll
    for (int j = 0; j < ECOG; ++j) acc[j] = bias[co_base + j];
    for (int ci = 0; ci < CC; ++ci) {
        float p[16];
        const float* ip = in + ((size_t)(b * CC + ci) * IMG + y * 4) * IMG + x * 4;
#pragma unroll
        for (int ky = 0; ky < 4; ++ky)
#pragma unroll
            for (int kx = 0; kx < 4; ++kx) p[ky * 4 + kx] = ip[ky * IMG + kx];
        const float* wp = w + (size_t)(co_base * CC + ci) * 16;
#pragma unroll
        for (int j = 0; j < ECOG; ++j) {
            const float* wj = wp + (size_t)j * CC * 16;
            float a = acc[j];
#pragma unroll
            for (int k = 0; k < 16; ++k) a = fmaf(p[k], wj[k], a);
            acc[j] = a;
        }
    }
#pragma unroll
    for (int j = 0; j < ECOG; ++j)
        out[((size_t)(b * Z1c + co_base + j) * S1c + y) * S1c + x] = acc[j];
}

// ---------------- conv body (register-tiled, reg-prefetch + LDS weights) ----------------
template <int CIN, int COUT, int S, int CB, int P, bool UP2, bool IN2ADD, int EPI>
__device__ __forceinline__ void conv_body(char* smem, int bid,
                                          const float* __restrict__ in,
                                          const float* __restrict__ in2,
                                          const float* __restrict__ wt,
                                          const float* __restrict__ bias,
                                          const float* __restrict__ ref,
                                          float* __restrict__ out,
                                          float* __restrict__ partial,
                                          float* __restrict__ upd,
                                          const int* __restrict__ cflag) {
    constexpr int ACCN = 4;
    constexpr int SP  = S * S;
    constexpr int XB  = S / P;
    constexpr int TPP = S * XB;
    constexpr int NG  = 256 / TPP;
    constexpr int COG = NG * ACCN;
    constexpr int NCG = COUT / COG;
    constexpr int HR  = S + 2;
    constexpr int HSW = (S == 16) ? 25 : 13;   // co-prime with 32 -> conflict-free b32
    constexpr int SIN = UP2 ? (S / 2) : S;
    constexpr int TOT = CB * HR * HR;
    constexpr int NLD = (TOT + 255) / 256;
    constexpr int WTOT = CB * 9 * COG;
    static_assert(TPP * NG == 256 && COG * NCG == COUT && S % P == 0, "bad blocking");
    static_assert(CIN % CB == 0 && (WTOT % 256) == 0, "bad blocking");

    float* lds_in = (float*)smem;
    float* lds_w  = (float*)(smem + (size_t)CB * HR * HSW * 4);

    // XCD-locality swizzle: sub-grid = 64 * NCG (offsets are multiples of 8)
    const int j8 = bid >> 3;
    const int b  = (bid & 7) + 8 * (j8 / NCG);
    const int cg = j8 % NCG;

    const int tid = threadIdx.x;
    const int local = tid % TPP;
    const int g     = tid / TPP;
    const int y  = local / XB;
    const int x0 = (local % XB) * P;
    const int co_base = cg * COG + g * ACCN;

    float pf[NLD];
    auto fetch = [&](int cb) {
#pragma unroll
        for (int i = 0; i < NLD; ++i) {
            const int e = tid + i * 256;
            float v = 0.f;
            if (e < TOT) {
                const int c  = e / (HR * HR);
                const int rr = e - c * (HR * HR);
                const int r  = rr / HR, col = rr - r * HR;
                const int iy = r - 1, ix = col - 1;
                if ((unsigned)iy < (unsigned)S && (unsigned)ix < (unsigned)S) {
                    const int ci = cb + c;
                    if (UP2)
                        v = in[(size_t)(b * CIN + ci) * (SIN * SIN) + (iy >> 1) * SIN + (ix >> 1)];
                    else
                        v = in[(size_t)(b * CIN + ci) * SP + iy * S + ix];
                    if (IN2ADD)
                        v += in2[(size_t)(b * CIN + ci) * SP + iy * S + ix];
                }
            }
            pf[i] = v;
        }
    };

    float acc[ACCN][P];
#pragma unroll
    for (int j = 0; j < ACCN; ++j)
#pragma unroll
        for (int p = 0; p < P; ++p) acc[j][p] = bias[co_base + j];

    int cf = 0;
    if (EPI == 3) cf = *cflag;

    fetch(0);
#pragma unroll 1
    for (int cb = 0; cb < CIN; cb += CB) {
#pragma unroll
        for (int i = 0; i < NLD; ++i) {
            const int e = tid + i * 256;
            if (e < TOT) {
                const int c  = e / (HR * HR);
                const int rr = e - c * (HR * HR);
                const int r  = rr / HR, col = rr - r * HR;
                lds_in[c * (HR * HSW) + r * HSW + col] = pf[i];
            }
        }
        {
            const float* wsrc = wt + (size_t)cb * 9 * COUT + cg * COG;
#pragma unroll
            for (int i = 0; i < WTOT / 256; ++i) {
                const int e = tid + i * 256;
                const int row = e / COG;
                const int col = e - row * COG;
                lds_w[e] = wsrc[(size_t)row * COUT + col];
            }
        }
        __syncthreads();
        if (cb + CB < CIN) fetch(cb + CB);

#pragma unroll 2
        for (int c = 0; c < CB; ++c) {
            const float* lp = lds_in + c * (HR * HSW) + y * HSW + x0;
            float w[3][P + 2];
#pragma unroll
            for (int dy = 0; dy < 3; ++dy)
#pragma unroll
                for (int j = 0; j < P + 2; ++j) w[dy][j] = lp[dy * HSW + j];
            const float* wr = lds_w + c * 9 * COG + g * ACCN;
#pragma unroll
            for (int k = 0; k < 9; ++k) {
                const int dy = k / 3, dx = k % 3;
                const float4 wv = *reinterpret_cast<const float4*>(wr + k * COG);
#pragma unroll
                for (int p = 0; p < P; ++p) {
                    const float v = w[dy][dx + p];
                    acc[0][p] = fmaf(v, wv.x, acc[0][p]);
                    acc[1][p] = fmaf(v, wv.y, acc[1][p]);
                    acc[2][p] = fmaf(v, wv.z, acc[2][p]);
                    acc[3][p] = fmaf(v, wv.w, acc[3][p]);
                }
            }
        }
        __syncthreads();
    }

    float esum = 0.f;
#pragma unroll
    for (int j = 0; j < ACCN; ++j) {
        const int co = co_base + j;
        const size_t ob = (size_t)(b * COUT + co) * SP + y * S + x0;
        if constexpr (EPI == 0 || EPI == 1) {
            if constexpr (P == 4) {
                float4 v;
                v.x = acc[j][0]; v.y = acc[j][1]; v.z = acc[j][2]; v.w = acc[j][3];
                if (EPI == 1) {
                    v.x = fmaxf(v.x, 0.f); v.y = fmaxf(v.y, 0.f);
                    v.z = fmaxf(v.z, 0.f); v.w = fmaxf(v.w, 0.f);
                }
                *reinterpret_cast<float4*>(out + ob) = v;
            } else {
                float2 v;
                v.x = acc[j][0]; v.y = acc[j][1];
                if (EPI == 1) { v.x = fmaxf(v.x, 0.f); v.y = fmaxf(v.y, 0.f); }
                *reinterpret_cast<float2*>(out + ob) = v;
            }
        } else if constexpr (EPI == 2) {
            if constexpr (P == 4) {
                const float4 r = *reinterpret_cast<const float4*>(ref + ob);
                float4 e;
                e.x = r.x - acc[j][0]; e.y = r.y - acc[j][1];
                e.z = r.z - acc[j][2]; e.w = r.w - acc[j][3];
                *reinterpret_cast<float4*>(out + ob) = e;
                esum += e.x * e.x + e.y * e.y + e.z * e.z + e.w * e.w;
            } else {
                const float2 r = *reinterpret_cast<const float2*>(ref + ob);
                float2 e;
                e.x = r.x - acc[j][0]; e.y = r.y - acc[j][1];
                *reinterpret_cast<float2*>(out + ob) = e;
                esum += e.x * e.x + e.y * e.y;
            }
        } else {  // EPI == 3
            const float s = cf ? 0.f : ALPHA_;
            if constexpr (P == 4) {
                float4 u = *reinterpret_cast<float4*>(upd + ob);
                u.x -= s * fminf(fmaxf(acc[j][0], -CLIP_), CLIP_);
                u.y -= s * fminf(fmaxf(acc[j][1], -CLIP_), CLIP_);
                u.z -= s * fminf(fmaxf(acc[j][2], -CLIP_), CLIP_);
                u.w -= s * fminf(fmaxf(acc[j][3], -CLIP_), CLIP_);
                *reinterpret_cast<float4*>(upd + ob) = u;
            } else {
                float2 u = *reinterpret_cast<float2*>(upd + ob);
                u.x -= s * fminf(fmaxf(acc[j][0], -CLIP_), CLIP_);
                u.y -= s * fminf(fmaxf(acc[j][1], -CLIP_), CLIP_);
                *reinterpret_cast<float2*>(upd + ob) = u;
            }
        }
    }
    if (EPI == 2) reduce_write((float*)smem, esum, partial + bid);
}

// ---------------- copysq (float4) ----------------
__device__ __forceinline__ void copysq4_body(char* smem, int bid,
                                             const float* __restrict__ src,
                                             float* __restrict__ dst,
                                             float* __restrict__ partial) {
    const int i = bid * 256 + threadIdx.x;
    const float4 v = reinterpret_cast<const float4*>(src)[i];
    reinterpret_cast<float4*>(dst)[i] = v;
    reduce_write((float*)smem, v.x * v.x + v.y * v.y + v.z * v.z + v.w * v.w,
                 partial + bid);
}

// ---------------- finalize body ----------------
__device__ __forceinline__ void finalize_body(char* smem,
                                              const float* __restrict__ pF,
                                              const float* __restrict__ p1,
                                              const float* __restrict__ p2,
                                              float* __restrict__ prev_e,
                                              float* __restrict__ all_err,
                                              int* __restrict__ conv,
                                              int* __restrict__ iters, int s) {
    float* sd = (float*)smem;   // 3*256 floats
    float aF = 0.f, a1 = 0.f, a2 = 0.f;
    for (int i = threadIdx.x; i < GF; i += 256) aF += pF[i];
    for (int i = threadIdx.x; i < G1; i += 256) a1 += p1[i];
    for (int i = threadIdx.x; i < G2; i += 256) a2 += p2[i];
    sd[threadIdx.x] = aF;
    sd[256 + threadIdx.x] = a1;
    sd[512 + threadIdx.x] = a2;
    __syncthreads();
#pragma unroll
    for (int off = 128; off > 0; off >>= 1) {
        if (threadIdx.x < off) {
            sd[threadIdx.x] += sd[threadIdx.x + off];
            sd[256 + threadIdx.x] += sd[256 + threadIdx.x + off];
            sd[512 + threadIdx.x] += sd[512 + threadIdx.x + off];
        }
        __syncthreads();
    }
    if (threadIdx.x == 0) {
        const float energy = sd[0] / (float)N_FR
                           + 0.1f * (sd[256] / (float)N_L1 + sd[512] / (float)N_L2);
        const int cv = conv[s];
        const float pe = prev_e[s];
        const float rel = fabsf(energy - pe) / (pe + 1e-8f);
        const int newly = (rel < THRESH_) && (iters[s] + 1 >= MINS);
        conv[s + 1] = cv | newly;
        iters[s + 1] = iters[s] + (cv ? 0 : 1);
        prev_e[s + 1] = cv ? pe : energy;
        all_err[s] = energy;
    }
}

// ---------------- fused kernels ----------------
__global__ __launch_bounds__(256) void prep_k(const float* dec_w, float* we,
                                              const float* tr_w, float* wt_tr,
                                              const float* p2_w, float* wt_p2,
                                              const float* up_w, float* wt_up,
                                              const float* p1_w, float* wt_p1,
                                              const float* l11w, float* wt_l11,
                                              const float* l12w, float* wt_l12,
                                              const float* l21w, float* wt_l21,
                                              const float* l22w, float* wt_l22,
                                              float* prevE, int* conv, int* iters) {
    const int b = blockIdx.x;
    if      (b < 576)  wt_body(b,        tr_w,  wt_tr,  128, 128);
    else if (b < 1152) wt_body(b - 576,  p2_w,  wt_p2,  128, 128);
    else if (b < 1440) wt_body(b - 1152, up_w,  wt_up,  128, 64);
    else if (b < 1584) wt_body(b - 1440, p1_w,  wt_p1,  64,  64);
    else if (b < 1872) wt_body(b - 1584, l11w,  wt_l11, 64,  128);
    else if (b < 2160) wt_body(b - 1872, l12w,  wt_l12, 128, 64);
    else if (b < 2736) wt_body(b - 2160, l21w,  wt_l21, 128, 128);
    else if (b < 3312) wt_body(b - 2736, l22w,  wt_l22, 128, 128);
    else if (b < 3324) dec_pre_body(b - 3312, dec_w, we);
    else               init_body(prevE, conv, iters);
}

__global__ __launch_bounds__(256) void encode_g(const float* in, const float* w,
                                                const float* bias, float* out) {
    encode_body(blockIdx.x, in, w, bias, out);
}

__global__ __launch_bounds__(256) void down_k(const float* __restrict__ in,
                                              const float* __restrict__ w,
                                              const float* __restrict__ bias,
                                              float* __restrict__ out1,
                                              float* __restrict__ out2) {
    const int co = blockIdx.x % Z2c;
    const int bg = blockIdx.x / Z2c;
    const int bl = threadIdx.x >> 6;
    const int pos = threadIdx.x & 63;
    const int b = bg * 4 + bl;
    const int y = pos >> 3, x = pos & 7;
    float acc = bias[co];
    const float* wc = w + (size_t)co * Z1c * 9;
    for (int ci = 0; ci < Z1c; ++ci) {
        const float* ip = in + (size_t)(b * Z1c + ci) * 256;
        float wv[9];
#pragma unroll
        for (int t = 0; t < 9; ++t) wv[t] = wc[t];
#pragma unroll
        for (int dy = 0; dy < 3; ++dy) {
            const int yy = 2 * y + dy;
            if (yy < 16) {
#pragma unroll
                for (int dx = 0; dx < 3; ++dx) {
                    const int xx = 2 * x + dx;
                    if (xx < 16) acc = fmaf(ip[yy * 16 + xx], wv[dy * 3 + dx], acc);
                }
            }
        }
        wc += 9;
    }
    const int oidx = ((b * Z2c + co) * S2c + y) * S2c + x;
    out1[oidx] = acc;
    out2[oidx] = acc;
}

// Phase A: decode(192) || transition(256) || upsample(256)  -> grid 704
template <bool TAIL>
__global__ __launch_bounds__(256) void phaseA_k(const float* dec_in, const float* we,
                                                const float* dec_b, const float* fnext,
                                                float* ef_out, float* fp_out, float* pF,
                                                const float* trans_in, const float* wt_tr,
                                                const float* tr_b, float* trans_out,
                                                const float* up_in, const float* wt_up,
                                                const float* up_b, float* upl_out) {
    __shared__ __align__(16) char smem[SMEM_MAX];
    const int b = blockIdx.x;
    if (b < GF)
        decode_body<TAIL>(smem, b, dec_in, we, dec_b, fnext, ef_out, fp_out, pF);
    else if (b < GF + 256)
        conv_body<Z2c, Z2c, 8, 32, 2, false, false, 0>(smem, b - GF, trans_in, nullptr,
            wt_tr, tr_b, nullptr, trans_out, nullptr, nullptr, nullptr);
    else
        conv_body<Z2c, Z1c, 16, 16, 4, true, false, 0>(smem, b - GF - 256, up_in, nullptr,
            wt_up, up_b, nullptr, upl_out, nullptr, nullptr, nullptr);
}

// Phase B: p2/e2(256) || p1/e1(256) || encode bu(256) -> grid 768
__global__ __launch_bounds__(256) void phaseB_k(const float* trans, const float* wt_p2,
                                                const float* p2_b, const float* l2p,
                                                float* e2, float* p2,
                                                const float* upl, const float* wt_p1,
                                                const float* p1_b, const float* l1p,
                                                float* e1, float* p1,
                                                const float* ef, const float* enc_w,
                                                const float* enc_b, float* bu) {
    __shared__ __align__(16) char smem[SMEM_MAX];
    const int b = blockIdx.x;
    if (b < 256)
        conv_body<Z2c, Z2c, 8, 32, 2, false, false, 2>(smem, b, trans, nullptr,
            wt_p2, p2_b, l2p, e2, p2, nullptr, nullptr);
    else if (b < 512)
        conv_body<Z1c, Z1c, 16, 16, 4, false, false, 2>(smem, b - 256, upl, nullptr,
            wt_p1, p1_b, l1p, e1, p1, nullptr, nullptr);
    else
        encode_body(b - 512, ef, enc_w, enc_b, bu);
}

// Phase C: l11 relu(512) || l21 relu(256) -> grid 768
__global__ __launch_bounds__(256) void phaseC_k(const float* e1, const float* bu,
                                                const float* wt_l11, const float* l11b,
                                                float* g1,
                                                const float* e2, const float* wt_l21,
                                                const float* l21b, float* g2) {
    __shared__ __align__(16) char smem[SMEM_MAX];
    const int b = blockIdx.x;
    if (b < 512)
        conv_body<Z1c, HIDc, 16, 16, 4, false, true, 1>(smem, b, e1, bu,
            wt_l11, l11b, nullptr, g1, nullptr, nullptr, nullptr);
    else
        conv_body<Z2c, HIDc, 8, 32, 2, false, false, 1>(smem, b - 512, e2, nullptr,
            wt_l21, l21b, nullptr, g2, nullptr, nullptr, nullptr);
}

// Phase D: l12 update(256) || l22 update(256) || finalize(1) -> grid 513
__global__ __launch_bounds__(256) void phaseD_k(const float* g1, const float* wt_l12,
                                                const float* l12b, float* l1p,
                                                const float* g2, const float* wt_l22,
                                                const float* l22b, float* l2p,
                                                const float* pF, const float* p1,
                                                const float* p2, float* prevE,
                                                float* aerr, int* conv, int* iters,
                                                int s) {
    __shared__ __align__(16) char smem[SMEM_MAX];
    const int b = blockIdx.x;
    if (b < 256)
        conv_body<HIDc, Z1c, 16, 16, 4, false, false, 3>(smem, b, g1, nullptr,
            wt_l12, l12b, nullptr, nullptr, nullptr, l1p, conv + s);
    else if (b < 512)
        conv_body<HIDc, Z2c, 8, 32, 2, false, false, 3>(smem, b - 256, g2, nullptr,
            wt_l22, l22b, nullptr, nullptr, nullptr, l2p, conv + s);
    else
        finalize_body(smem, pF, p1, p2, prevE, aerr, conv, iters, s);
}

// Tail B: e2->out(256) || e1->out(256) || copysq l1(1024) || copysq l2(512) -> 2048
__global__ __launch_bounds__(256) void tailB_k(const float* trans, const float* wt_p2,
                                               const float* p2_b, const float* l2p,
                                               float* o_e2, float* p2,
                                               const float* upl, const float* wt_p1,
                                               const float* p1_b, const float* l1p,
                                               float* o_e1, float* p1,
                                               float* o_l1, float* pL1,
                                               float* o_l2, float* pL2) {
    __shared__ __align__(16) char smem[SMEM_MAX];
    const int b = blockIdx.x;
    if (b < 256)
        conv_body<Z2c, Z2c, 8, 32, 2, false, false, 2>(smem, b, trans, nullptr,
            wt_p2, p2_b, l2p, o_e2, p2, nullptr, nullptr);
    else if (b < 512)
        conv_body<Z1c, Z1c, 16, 16, 4, false, false, 2>(smem, b - 256, upl, nullptr,
            wt_p1, p1_b, l1p, o_e1, p1, nullptr, nullptr);
    else if (b < 512 + GL1)
        copysq4_body(smem, b - 512, l1p, o_l1, pL1);
    else
        copysq4_body(smem, b - 512 - GL1, l2p, o_l2, pL2);
}

__global__ __launch_bounds__(256) void tail_k(const float* __restrict__ pF,
                                              const float* __restrict__ p1,
                                              const float* __restrict__ p2,
                                              const float* __restrict__ pL1,
                                              const float* __restrict__ pL2,
                                              const float* __restrict__ all_err,
                                              const int* __restrict__ iters,
                                              float* __restrict__ out_sc) {
    __shared__ float sd[5 * 256];
    float aF = 0.f, a1 = 0.f, a2 = 0.f, aL1 = 0.f, aL2 = 0.f;
    for (int i = threadIdx.x; i < GF; i += 256) aF += pF[i];
    for (int i = threadIdx.x; i < G1; i += 256) a1 += p1[i];
    for (int i = threadIdx.x; i < G2; i += 256) a2 += p2[i];
    for (int i = threadIdx.x; i < GL1; i += 256) aL1 += pL1[i];
    for (int i = threadIdx.x; i < GL2; i += 256) aL2 += pL2[i];
    sd[threadIdx.x] = aF;
    sd[256 + threadIdx.x] = a1;
    sd[512 + threadIdx.x] = a2;
    sd[768 + threadIdx.x] = aL1;
    sd[1024 + threadIdx.x] = aL2;
    __syncthreads();
#pragma unroll
    for (int off = 128; off > 0; off >>= 1) {
        if (threadIdx.x < off) {
            sd[threadIdx.x] += sd[threadIdx.x + off];
            sd[256 + threadIdx.x] += sd[256 + threadIdx.x + off];
            sd[512 + threadIdx.x] += sd[512 + threadIdx.x + off];
            sd[768 + threadIdx.x] += sd[768 + threadIdx.x + off];
            sd[1024 + threadIdx.x] += sd[1024 + threadIdx.x + off];
        }
        __syncthreads();
    }
    if (threadIdx.x == 0) {
        const float eF  = sd[0] / (float)N_FR;
        const float e1  = 0.1f * (sd[256] / (float)N_L1);
        const float e2  = 0.1f * (sd[512] / (float)N_L2);
        const float reg = 1e-4f * (sd[768] / (float)N_L1 + sd[1024] / (float)N_L2);
        out_sc[0] = eF + e1 + e2 + reg;
        out_sc[1] = eF;
        out_sc[2] = e1;
        out_sc[3] = e2;
        out_sc[16] = (float)iters[12];
    }
    if (threadIdx.x < 12) out_sc[4 + threadIdx.x] = all_err[threadIdx.x];
}

// ---------------- host launch ----------------
extern "C" void kernel_launch(void* const* d_in, const int* in_sizes, int n_in,
                              void* d_out, int out_size, void* d_ws, size_t ws_size,
                              hipStream_t stream) {
    const float* frame_cur = (const float*)d_in[0];
    const float* frame_nxt = (const float*)d_in[1];
    const float* enc_w = (const float*)d_in[2];
    const float* enc_b = (const float*)d_in[3];
    const float* dec_w = (const float*)d_in[4];
    const float* dec_b = (const float*)d_in[5];
    const float* dn_w  = (const float*)d_in[6];
    const float* dn_b  = (const float*)d_in[7];
    const float* up_w  = (const float*)d_in[8];
    const float* up_b  = (const float*)d_in[9];
    const float* tr_w  = (const float*)d_in[10];
    const float* tr_b  = (const float*)d_in[11];
    const float* p1_w  = (const float*)d_in[12];
    const float* p1_b  = (const float*)d_in[13];
    const float* p2_w  = (const float*)d_in[14];
    const float* p2_b  = (const float*)d_in[15];
    const float* l11w  = (const float*)d_in[16];
    const float* l11b  = (const float*)d_in[17];
    const float* l12w  = (const float*)d_in[18];
    const float* l12b  = (const float*)d_in[19];
    const float* l21w  = (const float*)d_in[20];
    const float* l21b  = (const float*)d_in[21];
    const float* l22w  = (const float*)d_in[22];
    const float* l22b  = (const float*)d_in[23];

    // workspace layout (floats)
    float* ws = (float*)d_ws;
    float* l1p   = ws;               // N_L1
    float* l2p   = l1p + N_L1;       // N_L2
    float* l2i   = l2p + N_L2;       // N_L2
    float* ef    = l2i + N_L2;       // N_FR
    float* trans = ef + N_FR;        // N_L2
    float* e2    = trans + N_L2;     // N_L2
    float* upl   = e2 + N_L2;        // N_L1
    float* e1    = upl + N_L1;       // N_L1
    float* bu    = e1 + N_L1;        // N_L1
    float* g1    = bu + N_L1;        // N_G1
    float* g2    = g1 + N_G1;        // N_G2
    float* pF    = g2 + N_G2;        // 4096
    float* p1    = pF + 4096;        // 4096
    float* p2    = p1 + 4096;        // 4096
    float* pL1   = p2 + 4096;        // 4096
    float* pL2   = pL1 + 4096;       // 4096
    float* we    = pL2 + 4096;       // 12288
    float* wt_tr  = we + 12288;       // 147456
    float* wt_p2  = wt_tr + 147456;   // 147456
    float* wt_up  = wt_p2 + 147456;   // 73728
    float* wt_p1  = wt_up + 73728;    // 36864
    float* wt_l11 = wt_p1 + 36864;    // 73728
    float* wt_l12 = wt_l11 + 73728;   // 73728
    float* wt_l21 = wt_l12 + 73728;   // 147456
    float* wt_l22 = wt_l21 + 147456;  // 147456
    float* prevE = wt_l22 + 147456;   // 16
    float* aerr  = prevE + 16;        // 16
    int*   conv  = (int*)(aerr + 16);
    int*   iters = conv + 16;

    // output layout (reference return order)
    float* o_fp = (float*)d_out;
    float* o_l1 = o_fp + N_FR;
    float* o_l2 = o_l1 + N_L1;
    float* o_ef = o_l2 + N_L2;
    float* o_e1 = o_ef + N_FR;
    float* o_e2 = o_e1 + N_L1;
    float* o_sc = o_e2 + N_L2;

    prep_k<<<3325, 256, 0, stream>>>(dec_w, we, tr_w, wt_tr, p2_w, wt_p2, up_w, wt_up,
                                     p1_w, wt_p1, l11w, wt_l11, l12w, wt_l12,
                                     l21w, wt_l21, l22w, wt_l22, prevE, conv, iters);
    encode_g<<<256, 256, 0, stream>>>(frame_cur, enc_w, enc_b, l1p);
    down_k<<<GRID_DOWN, 256, 0, stream>>>(l1p, dn_w, dn_b, l2i, l2p);

    for (int s = 0; s < MAXS; ++s) {
        phaseA_k<false><<<704, 256, 0, stream>>>(l1p, we, dec_b, frame_nxt, ef, nullptr,
                                                 pF, l2p, wt_tr, tr_b, trans,
                                                 l2p, wt_up, up_b, upl);
        phaseB_k<<<768, 256, 0, stream>>>(trans, wt_p2, p2_b, l2p, e2, p2,
                                          upl, wt_p1, p1_b, l1p, e1, p1,
                                          ef, enc_w, enc_b, bu);
        phaseC_k<<<768, 256, 0, stream>>>(e1, bu, wt_l11, l11b, g1,
                                          e2, wt_l21, l21b, g2);
        phaseD_k<<<513, 256, 0, stream>>>(g1, wt_l12, l12b, l1p,
                                          g2, wt_l22, l22b, l2p,
                                          pF, p1, p2, prevE, aerr, conv, iters, s);
    }

    // ---- tail (latent2_hat uses INITIAL latent2 = l2i) ----
    phaseA_k<true><<<704, 256, 0, stream>>>(l1p, we, dec_b, frame_nxt, o_ef, o_fp,
                                            pF, l2i, wt_tr, tr_b, trans,
                                            l2p, wt_up, up_b, upl);
    tailB_k<<<512 + GL1 + GL2, 256, 0, stream>>>(trans, wt_p2, p2_b, l2p, o_e2, p2,
                                                 upl, wt_p1, p1_b, l1p, o_e1, p1,
                                                 o_l1, pL1, o_l2, pL2);
    tail_k<<<1, 256, 0, stream>>>(pF, p1, p2, pL1, pL2, aerr, iters, o_sc);
}

// Round 9
// 4033.719 us; speedup vs baseline: 6.2867x; 1.0132x over previous
//
#include <hip/hip_runtime.h>

// ---------------- config (mirrors reference) ----------------
constexpr int NB_  = 64;
constexpr int CC   = 3;
constexpr int IMG  = 64;
constexpr int Z1c  = 64;
constexpr int Z2c  = 128;
constexpr int HIDc = 128;
constexpr int S1c  = 16;
constexpr int S2c  = 8;
constexpr int MAXS = 12;
constexpr int MINS = 3;
constexpr float THRESH_ = 1e-3f;
constexpr float ALPHA_  = 0.1f;
constexpr float CLIP_   = 1.0f;

constexpr int N_L1 = NB_ * Z1c * S1c * S1c;   // 1,048,576
constexpr int N_L2 = NB_ * Z2c * S2c * S2c;   //   524,288
constexpr int N_FR = NB_ * CC * IMG * IMG;    //   786,432
constexpr int N_G1 = NB_ * HIDc * S1c * S1c;  // 2,097,152
constexpr int N_G2 = NB_ * HIDc * S2c * S2c;  //   524,288

constexpr int GF  = NB_ * CC;   // 192 decode blocks
constexpr int G1  = 256;        // p1 partial count
constexpr int G2  = 256;        // p2 partial count
constexpr int GL1 = 1024;       // copysq4 l1 partial count
constexpr int GL2 = 512;        // copysq4 l2 partial count
constexpr int GRID_DOWN = (NB_ / 4) * Z2c;

// LDS budget: S=16 conv (CB=16): 16*18*25*4 + 16*9*16*4 = 38016 B (the max)
//             decode: 28800+4096=32896; S=8 conv CB=16: 8320+18432=26752
constexpr int SMEM_MAX = 38016;   // -> 4 blocks/CU (160 KiB LDS)

// ---------------- reduction (uses caller-provided scratch) ----------------
__device__ __forceinline__ void reduce_write(float* sd, float v, float* dst) {
    sd[threadIdx.x] = v;
    __syncthreads();
#pragma unroll
    for (int off = 128; off > 0; off >>= 1) {
        if (threadIdx.x < off) sd[threadIdx.x] += sd[threadIdx.x + off];
        __syncthreads();
    }
    if (threadIdx.x == 0) *dst = sd[0];
}

// ---------------- prep bodies ----------------
__device__ __forceinline__ void init_body(float* prev_e, int* conv, int* iters) {
    if (threadIdx.x == 0) { prev_e[0] = 1e30f; conv[0] = 0; iters[0] = 0; }
}

__device__ __forceinline__ void wt_body(int vbid, const float* __restrict__ src,
                                        float* __restrict__ dst, int cin, int cout) {
    const int t = vbid * 256 + threadIdx.x;   // grid sized exactly: no bound check
    const int k  = t % 9;
    const int ci = (t / 9) % cin;
    const int co = t / (9 * cin);
    dst[(ci * 9 + k) * cout + co] = src[t];
}

__device__ __forceinline__ void dec_pre_body(int vbid, const float* __restrict__ dw,
                                             float* __restrict__ we) {
    const int t = vbid * 256 + threadIdx.x;   // exactly 12*256 = 3072
    const int px = t & 3, py = (t >> 2) & 3;
    const int ci = (t >> 4) % Z1c, c = t / (16 * Z1c);
    float w4[4] = {0.f, 0.f, 0.f, 0.f};
#pragma unroll
    for (int dy = 0; dy < 3; ++dy)
#pragma unroll
        for (int dx = 0; dx < 3; ++dx) {
            const int r = py + dy - 1, s = px + dx - 1;
            const int ty = (py == 0) ? ((r < 0) ? 0 : 1) : ((r >= 4) ? 1 : 0);
            const int tx = (px == 0) ? ((s < 0) ? 0 : 1) : ((s >= 4) ? 1 : 0);
            w4[ty * 2 + tx] += dw[((c * Z1c + ci) * 3 + dy) * 3 + dx];
        }
#pragma unroll
    for (int k = 0; k < 4; ++k) we[(size_t)t * 4 + k] = w4[k];
}

// ---------------- decode body (LDS-staged, reg-prefetch, phase-folded) ----------------
template <bool TAIL>
__device__ __forceinline__ void decode_body(char* smem, int bid,
                                            const float* __restrict__ l1,
                                            const float* __restrict__ we,
                                            const float* __restrict__ db,
                                            const float* __restrict__ fnext,
                                            float* __restrict__ ef_out,
                                            float* __restrict__ fp_out,
                                            float* __restrict__ partial) {
    constexpr int CB = 16, HR = 18, HSW = 25;
    constexpr int TOT = CB * HR * HR;        // 5184
    constexpr int NLD = (TOT + 255) / 256;   // 21
    float* lds_in = (float*)smem;                        // 28800 B
    float* lds_w  = (float*)(smem + CB * HR * HSW * 4);  // 4096 B

    const int b = bid / CC, c = bid % CC;
    const int tid = threadIdx.x;
    const int ty = tid >> 4, tx = tid & 15;
    const float* ibase = l1 + (size_t)b * Z1c * 256;

    float pf[NLD];
    auto fetch = [&](int cb) {
#pragma unroll
        for (int i = 0; i < NLD; ++i) {
            const int e = tid + i * 256;
            float v = 0.f;
            if (e < TOT) {
                const int cc2 = e / (HR * HR);
                const int rr = e - cc2 * (HR * HR);
                const int r = rr / HR, col = rr - r * HR;
                const int iy = r - 1, ix = col - 1;
                if ((unsigned)iy < 16u && (unsigned)ix < 16u)
                    v = ibase[(size_t)(cb + cc2) * 256 + iy * 16 + ix];
            }
            pf[i] = v;
        }
    };

    float acc[16];
#pragma unroll
    for (int k = 0; k < 16; ++k) acc[k] = 0.f;

    fetch(0);
#pragma unroll 1
    for (int cb = 0; cb < Z1c; cb += CB) {
#pragma unroll
        for (int i = 0; i < NLD; ++i) {
            const int e = tid + i * 256;
            if (e < TOT) {
                const int cc2 = e / (HR * HR);
                const int rr = e - cc2 * (HR * HR);
                const int r = rr / HR, col = rr - r * HR;
                lds_in[cc2 * (HR * HSW) + r * HSW + col] = pf[i];
            }
        }
        {
            const float* wsrc = we + (size_t)(c * Z1c + cb) * 64;
#pragma unroll
            for (int i = 0; i < CB * 64 / 256; ++i) lds_w[tid + i * 256] = wsrc[tid + i * 256];
        }
        __syncthreads();
        if (cb + CB < Z1c) fetch(cb + CB);

#pragma unroll 2
        for (int c2 = 0; c2 < CB; ++c2) {
            const float* lp = lds_in + c2 * (HR * HSW);
            float ld[3][3];
#pragma unroll
            for (int ry = 0; ry < 3; ++ry)
#pragma unroll
                for (int rx = 0; rx < 3; ++rx)
                    ld[ry][rx] = lp[(ty + ry) * HSW + (tx + rx)];
            const float* wb_ = lds_w + c2 * 64;
#pragma unroll
            for (int py = 0; py < 4; ++py) {
                const int ry0 = (py == 0) ? 0 : 1;
#pragma unroll
                for (int px = 0; px < 4; ++px) {
                    const int rx0 = (px == 0) ? 0 : 1;
                    const float4 w4 = *reinterpret_cast<const float4*>(wb_ + (py * 4 + px) * 4);
                    float a = acc[py * 4 + px];
                    a = fmaf(ld[ry0][rx0],         w4.x, a);
                    a = fmaf(ld[ry0][rx0 + 1],     w4.y, a);
                    a = fmaf(ld[ry0 + 1][rx0],     w4.z, a);
                    a = fmaf(ld[ry0 + 1][rx0 + 1], w4.w, a);
                    acc[py * 4 + px] = a;
                }
            }
        }
        __syncthreads();
    }

    const float bias = db[c];
    float esum = 0.f;
#pragma unroll
    for (int py = 0; py < 4; ++py)
#pragma unroll
        for (int px = 0; px < 4; ++px) {
            const float fp = acc[py * 4 + px] + bias;
            const size_t idx = (size_t)bid * 4096 + (ty * 4 + py) * 64 + (tx * 4 + px);
            const float e = fnext[idx] - fp;
            ef_out[idx] = e;
            if (TAIL) fp_out[idx] = fp;
            esum += e * e;
        }
    reduce_write((float*)smem, esum, partial + bid);
}

// ---------------- encode body ----------------
__device__ __forceinline__ void encode_body(int bid, const float* __restrict__ in,
                                            const float* __restrict__ w,
                                            const float* __restrict__ bias,
                                            float* __restrict__ out) {
    constexpr int ECOG = 16;
    constexpr int NCG = Z1c / ECOG;
    const int b = bid / NCG, cg = bid % NCG;
    const int co_base = cg * ECOG;
    const int y = threadIdx.x >> 4, x = threadIdx.x & 15;
    float acc[ECOG];
#pragma unroll
    for (int j = 0; j < ECOG; ++j) acc[j] = bias[co_base + j];
    for (int ci = 0; ci < CC; ++ci) {
        float p[16];
        const float* ip = in + ((size_t)(b * CC + ci) * IMG + y * 4) * IMG + x * 4;
#pragma unroll
        for (int ky = 0; ky < 4; ++ky)
#pragma unroll
            for (int kx = 0; kx < 4; ++kx) p[ky * 4 + kx] = ip[ky * IMG + kx];
        const float* wp = w + (size_t)(co_base * CC + ci) * 16;
#pragma unroll
        for (int j = 0; j < ECOG; ++j) {
            const float* wj = wp + (size_t)j * CC * 16;
            float a = acc[j];
#pragma unroll
            for (int k = 0; k < 16; ++k) a = fmaf(p[k], wj[k], a);
            acc[j] = a;
        }
    }
#pragma unroll
    for (int j = 0; j < ECOG; ++j)
        out[((size_t)(b * Z1c + co_base + j) * S1c + y) * S1c + x] = acc[j];
}

// ---------------- conv body (register-tiled, reg-prefetch + LDS weights) ----------------
// NOTE: accumulation order is ci-ascending then k 0..8 regardless of CB,
// so CB choice does not change results bit-for-bit.
template <int CIN, int COUT, int S, int CB, int P, bool UP2, bool IN2ADD, int EPI>
__device__ __forceinline__ void conv_body(char* smem, int bid,
                                          const float* __restrict__ in,
                                          const float* __restrict__ in2,
                                          const float* __restrict__ wt,
                                          const float* __restrict__ bias,
                                          const float* __restrict__ ref,
                                          float* __restrict__ out,
                                          float* __restrict__ partial,
                                          float* __restrict__ upd,
                                          const int* __restrict__ cflag) {
    constexpr int ACCN = 4;
    constexpr int SP  = S * S;
    constexpr int XB  = S / P;
    constexpr int TPP = S * XB;
    constexpr int NG  = 256 / TPP;
    constexpr int COG = NG * ACCN;
    constexpr int NCG = COUT / COG;
    constexpr int HR  = S + 2;
    constexpr int HSW = (S == 16) ? 25 : 13;   // co-prime with 32 -> conflict-free b32
    constexpr int SIN = UP2 ? (S / 2) : S;
    constexpr int TOT = CB * HR * HR;
    constexpr int NLD = (TOT + 255) / 256;
    constexpr int WTOT = CB * 9 * COG;
    static_assert(TPP * NG == 256 && COG * NCG == COUT && S % P == 0, "bad blocking");
    static_assert(CIN % CB == 0 && (WTOT % 256) == 0, "bad blocking");
    static_assert(CB * HR * HSW * 4 + WTOT * 4 <= SMEM_MAX, "LDS overflow");

    float* lds_in = (float*)smem;
    float* lds_w  = (float*)(smem + (size_t)CB * HR * HSW * 4);

    // XCD-locality swizzle: sub-grid = 64 * NCG (offsets are multiples of 8)
    const int j8 = bid >> 3;
    const int b  = (bid & 7) + 8 * (j8 / NCG);
    const int cg = j8 % NCG;

    const int tid = threadIdx.x;
    const int local = tid % TPP;
    const int g     = tid / TPP;
    const int y  = local / XB;
    const int x0 = (local % XB) * P;
    const int co_base = cg * COG + g * ACCN;

    float pf[NLD];
    auto fetch = [&](int cb) {
#pragma unroll
        for (int i = 0; i < NLD; ++i) {
            const int e = tid + i * 256;
            float v = 0.f;
            if (e < TOT) {
                const int c  = e / (HR * HR);
                const int rr = e - c * (HR * HR);
                const int r  = rr / HR, col = rr - r * HR;
                const int iy = r - 1, ix = col - 1;
                if ((unsigned)iy < (unsigned)S && (unsigned)ix < (unsigned)S) {
                    const int ci = cb + c;
                    if (UP2)
                        v = in[(size_t)(b * CIN + ci) * (SIN * SIN) + (iy >> 1) * SIN + (ix >> 1)];
                    else
                        v = in[(size_t)(b * CIN + ci) * SP + iy * S + ix];
                    if (IN2ADD)
                        v += in2[(size_t)(b * CIN + ci) * SP + iy * S + ix];
                }
            }
            pf[i] = v;
        }
    };

    float acc[ACCN][P];
#pragma unroll
    for (int j = 0; j < ACCN; ++j)
#pragma unroll
        for (int p = 0; p < P; ++p) acc[j][p] = bias[co_base + j];

    int cf = 0;
    if (EPI == 3) cf = *cflag;

    fetch(0);
#pragma unroll 1
    for (int cb = 0; cb < CIN; cb += CB) {
#pragma unroll
        for (int i = 0; i < NLD; ++i) {
            const int e = tid + i * 256;
            if (e < TOT) {
                const int c  = e / (HR * HR);
                const int rr = e - c * (HR * HR);
                const int r  = rr / HR, col = rr - r * HR;
                lds_in[c * (HR * HSW) + r * HSW + col] = pf[i];
            }
        }
        {
            const float* wsrc = wt + (size_t)cb * 9 * COUT + cg * COG;
#pragma unroll
            for (int i = 0; i < WTOT / 256; ++i) {
                const int e = tid + i * 256;
                const int row = e / COG;
                const int col = e - row * COG;
                lds_w[e] = wsrc[(size_t)row * COUT + col];
            }
        }
        __syncthreads();
        if (cb + CB < CIN) fetch(cb + CB);

#pragma unroll 2
        for (int c = 0; c < CB; ++c) {
            const float* lp = lds_in + c * (HR * HSW) + y * HSW + x0;
            float w[3][P + 2];
#pragma unroll
            for (int dy = 0; dy < 3; ++dy)
#pragma unroll
                for (int j = 0; j < P + 2; ++j) w[dy][j] = lp[dy * HSW + j];
            const float* wr = lds_w + c * 9 * COG + g * ACCN;
#pragma unroll
            for (int k = 0; k < 9; ++k) {
                const int dy = k / 3, dx = k % 3;
                const float4 wv = *reinterpret_cast<const float4*>(wr + k * COG);
#pragma unroll
                for (int p = 0; p < P; ++p) {
                    const float v = w[dy][dx + p];
                    acc[0][p] = fmaf(v, wv.x, acc[0][p]);
                    acc[1][p] = fmaf(v, wv.y, acc[1][p]);
                    acc[2][p] = fmaf(v, wv.z, acc[2][p]);
                    acc[3][p] = fmaf(v, wv.w, acc[3][p]);
                }
            }
        }
        __syncthreads();
    }

    float esum = 0.f;
#pragma unroll
    for (int j = 0; j < ACCN; ++j) {
        const int co = co_base + j;
        const size_t ob = (size_t)(b * COUT + co) * SP + y * S + x0;
        if constexpr (EPI == 0 || EPI == 1) {
            if constexpr (P == 4) {
                float4 v;
                v.x = acc[j][0]; v.y = acc[j][1]; v.z = acc[j][2]; v.w = acc[j][3];
                if (EPI == 1) {
                    v.x = fmaxf(v.x, 0.f); v.y = fmaxf(v.y, 0.f);
                    v.z = fmaxf(v.z, 0.f); v.w = fmaxf(v.w, 0.f);
                }
                *reinterpret_cast<float4*>(out + ob) = v;
            } else {
                float2 v;
                v.x = acc[j][0]; v.y = acc[j][1];
                if (EPI == 1) { v.x = fmaxf(v.x, 0.f); v.y = fmaxf(v.y, 0.f); }
                *reinterpret_cast<float2*>(out + ob) = v;
            }
        } else if constexpr (EPI == 2) {
            if constexpr (P == 4) {
                const float4 r = *reinterpret_cast<const float4*>(ref + ob);
                float4 e;
                e.x = r.x - acc[j][0]; e.y = r.y - acc[j][1];
                e.z = r.z - acc[j][2]; e.w = r.w - acc[j][3];
                *reinterpret_cast<float4*>(out + ob) = e;
                esum += e.x * e.x + e.y * e.y + e.z * e.z + e.w * e.w;
            } else {
                const float2 r = *reinterpret_cast<const float2*>(ref + ob);
                float2 e;
                e.x = r.x - acc[j][0]; e.y = r.y - acc[j][1];
                *reinterpret_cast<float2*>(out + ob) = e;
                esum += e.x * e.x + e.y * e.y;
            }
        } else {  // EPI == 3
            const float s = cf ? 0.f : ALPHA_;
            if constexpr (P == 4) {
                float4 u = *reinterpret_cast<float4*>(upd + ob);
                u.x -= s * fminf(fmaxf(acc[j][0], -CLIP_), CLIP_);
                u.y -= s * fminf(fmaxf(acc[j][1], -CLIP_), CLIP_);
                u.z -= s * fminf(fmaxf(acc[j][2], -CLIP_), CLIP_);
                u.w -= s * fminf(fmaxf(acc[j][3], -CLIP_), CLIP_);
                *reinterpret_cast<float4*>(upd + ob) = u;
            } else {
                float2 u = *reinterpret_cast<float2*>(upd + ob);
                u.x -= s * fminf(fmaxf(acc[j][0], -CLIP_), CLIP_);
                u.y -= s * fminf(fmaxf(acc[j][1], -CLIP_), CLIP_);
                *reinterpret_cast<float2*>(upd + ob) = u;
            }
        }
    }
    if (EPI == 2) reduce_write((float*)smem, esum, partial + bid);
}

// ---------------- copysq (float4) ----------------
__device__ __forceinline__ void copysq4_body(char* smem, int bid,
                                             const float* __restrict__ src,
                                             float* __restrict__ dst,
                                             float* __restrict__ partial) {
    const int i = bid * 256 + threadIdx.x;
    const float4 v = reinterpret_cast<const float4*>(src)[i];
    reinterpret_cast<float4*>(dst)[i] = v;
    reduce_write((float*)smem, v.x * v.x + v.y * v.y + v.z * v.z + v.w * v.w,
                 partial + bid);
}

// ---------------- finalize body ----------------
__device__ __forceinline__ void finalize_body(char* smem,
                                              const float* __restrict__ pF,
                                              const float* __restrict__ p1,
                                              const float* __restrict__ p2,
                                              float* __restrict__ prev_e,
                                              float* __restrict__ all_err,
                                              int* __restrict__ conv,
                                              int* __restrict__ iters, int s) {
    float* sd = (float*)smem;   // 3*256 floats
    float aF = 0.f, a1 = 0.f, a2 = 0.f;
    for (int i = threadIdx.x; i < GF; i += 256) aF += pF[i];
    for (int i = threadIdx.x; i < G1; i += 256) a1 += p1[i];
    for (int i = threadIdx.x; i < G2; i += 256) a2 += p2[i];
    sd[threadIdx.x] = aF;
    sd[256 + threadIdx.x] = a1;
    sd[512 + threadIdx.x] = a2;
    __syncthreads();
#pragma unroll
    for (int off = 128; off > 0; off >>= 1) {
        if (threadIdx.x < off) {
            sd[threadIdx.x] += sd[threadIdx.x + off];
            sd[256 + threadIdx.x] += sd[256 + threadIdx.x + off];
            sd[512 + threadIdx.x] += sd[512 + threadIdx.x + off];
        }
        __syncthreads();
    }
    if (threadIdx.x == 0) {
        const float energy = sd[0] / (float)N_FR
                           + 0.1f * (sd[256] / (float)N_L1 + sd[512] / (float)N_L2);
        const int cv = conv[s];
        const float pe = prev_e[s];
        const float rel = fabsf(energy - pe) / (pe + 1e-8f);
        const int newly = (rel < THRESH_) && (iters[s] + 1 >= MINS);
        conv[s + 1] = cv | newly;
        iters[s + 1] = iters[s] + (cv ? 0 : 1);
        prev_e[s + 1] = cv ? pe : energy;
        all_err[s] = energy;
    }
}

// ---------------- fused kernels ----------------
__global__ __launch_bounds__(256) void prep_k(const float* dec_w, float* we,
                                              const float* tr_w, float* wt_tr,
                                              const float* p2_w, float* wt_p2,
                                              const float* up_w, float* wt_up,
                                              const float* p1_w, float* wt_p1,
                                              const float* l11w, float* wt_l11,
                                              const float* l12w, float* wt_l12,
                                              const float* l21w, float* wt_l21,
                                              const float* l22w, float* wt_l22,
                                              float* prevE, int* conv, int* iters) {
    const int b = blockIdx.x;
    if      (b < 576)  wt_body(b,        tr_w,  wt_tr,  128, 128);
    else if (b < 1152) wt_body(b - 576,  p2_w,  wt_p2,  128, 128);
    else if (b < 1440) wt_body(b - 1152, up_w,  wt_up,  128, 64);
    else if (b < 1584) wt_body(b - 1440, p1_w,  wt_p1,  64,  64);
    else if (b < 1872) wt_body(b - 1584, l11w,  wt_l11, 64,  128);
    else if (b < 2160) wt_body(b - 1872, l12w,  wt_l12, 128, 64);
    else if (b < 2736) wt_body(b - 2160, l21w,  wt_l21, 128, 128);
    else if (b < 3312) wt_body(b - 2736, l22w,  wt_l22, 128, 128);
    else if (b < 3324) dec_pre_body(b - 3312, dec_w, we);
    else               init_body(prevE, conv, iters);
}

__global__ __launch_bounds__(256) void encode_g(const float* in, const float* w,
                                                const float* bias, float* out) {
    encode_body(blockIdx.x, in, w, bias, out);
}

__global__ __launch_bounds__(256) void down_k(const float* __restrict__ in,
                                              const float* __restrict__ w,
                                              const float* __restrict__ bias,
                                              float* __restrict__ out1,
                                              float* __restrict__ out2) {
    const int co = blockIdx.x % Z2c;
    const int bg = blockIdx.x / Z2c;
    const int bl = threadIdx.x >> 6;
    const int pos = threadIdx.x & 63;
    const int b = bg * 4 + bl;
    const int y = pos >> 3, x = pos & 7;
    float acc = bias[co];
    const float* wc = w + (size_t)co * Z1c * 9;
    for (int ci = 0; ci < Z1c; ++ci) {
        const float* ip = in + (size_t)(b * Z1c + ci) * 256;
        float wv[9];
#pragma unroll
        for (int t = 0; t < 9; ++t) wv[t] = wc[t];
#pragma unroll
        for (int dy = 0; dy < 3; ++dy) {
            const int yy = 2 * y + dy;
            if (yy < 16) {
#pragma unroll
                for (int dx = 0; dx < 3; ++dx) {
                    const int xx = 2 * x + dx;
                    if (xx < 16) acc = fmaf(ip[yy * 16 + xx], wv[dy * 3 + dx], acc);
                }
            }
        }
        wc += 9;
    }
    const int oidx = ((b * Z2c + co) * S2c + y) * S2c + x;
    out1[oidx] = acc;
    out2[oidx] = acc;
}

// Phase A: upsample(256) || transition(256) || decode(192)  -> grid 704
template <bool TAIL>
__global__ __launch_bounds__(256) void phaseA_k(const float* dec_in, const float* we,
                                                const float* dec_b, const float* fnext,
                                                float* ef_out, float* fp_out, float* pF,
                                                const float* trans_in, const float* wt_tr,
                                                const float* tr_b, float* trans_out,
                                                const float* up_in, const float* wt_up,
                                                const float* up_b, float* upl_out) {
    __shared__ __align__(16) char smem[SMEM_MAX];
    const int b = blockIdx.x;
    if (b < 256)
        conv_body<Z2c, Z1c, 16, 16, 4, true, false, 0>(smem, b, up_in, nullptr,
            wt_up, up_b, nullptr, upl_out, nullptr, nullptr, nullptr);
    else if (b < 512)
        conv_body<Z2c, Z2c, 8, 16, 2, false, false, 0>(smem, b - 256, trans_in, nullptr,
            wt_tr, tr_b, nullptr, trans_out, nullptr, nullptr, nullptr);
    else
        decode_body<TAIL>(smem, b - 512, dec_in, we, dec_b, fnext, ef_out, fp_out, pF);
}

// Phase B: p2/e2(256) || p1/e1(256) || encode bu(256) -> grid 768
__global__ __launch_bounds__(256) void phaseB_k(const float* trans, const float* wt_p2,
                                                const float* p2_b, const float* l2p,
                                                float* e2, float* p2,
                                                const float* upl, const float* wt_p1,
                                                const float* p1_b, const float* l1p,
                                                float* e1, float* p1,
                                                const float* ef, const float* enc_w,
                                                const float* enc_b, float* bu) {
    __shared__ __align__(16) char smem[SMEM_MAX];
    const int b = blockIdx.x;
    if (b < 256)
        conv_body<Z2c, Z2c, 8, 16, 2, false, false, 2>(smem, b, trans, nullptr,
            wt_p2, p2_b, l2p, e2, p2, nullptr, nullptr);
    else if (b < 512)
        conv_body<Z1c, Z1c, 16, 16, 4, false, false, 2>(smem, b - 256, upl, nullptr,
            wt_p1, p1_b, l1p, e1, p1, nullptr, nullptr);
    else
        encode_body(b - 512, ef, enc_w, enc_b, bu);
}

// Phase C: l11 relu(512) || l21 relu(256) -> grid 768
__global__ __launch_bounds__(256) void phaseC_k(const float* e1, const float* bu,
                                                const float* wt_l11, const float* l11b,
                                                float* g1,
                                                const float* e2, const float* wt_l21,
                                                const float* l21b, float* g2) {
    __shared__ __align__(16) char smem[SMEM_MAX];
    const int b = blockIdx.x;
    if (b < 512)
        conv_body<Z1c, HIDc, 16, 16, 4, false, true, 1>(smem, b, e1, bu,
            wt_l11, l11b, nullptr, g1, nullptr, nullptr, nullptr);
    else
        conv_body<Z2c, HIDc, 8, 16, 2, false, false, 1>(smem, b - 512, e2, nullptr,
            wt_l21, l21b, nullptr, g2, nullptr, nullptr, nullptr);
}

// Phase D: l12 update(256) || l22 update(256) || finalize(1) -> grid 513
__global__ __launch_bounds__(256) void phaseD_k(const float* g1, const float* wt_l12,
                                                const float* l12b, float* l1p,
                                                const float* g2, const float* wt_l22,
                                                const float* l22b, float* l2p,
                                                const float* pF, const float* p1,
                                                const float* p2, float* prevE,
                                                float* aerr, int* conv, int* iters,
                                                int s) {
    __shared__ __align__(16) char smem[SMEM_MAX];
    const int b = blockIdx.x;
    if (b < 256)
        conv_body<HIDc, Z1c, 16, 16, 4, false, false, 3>(smem, b, g1, nullptr,
            wt_l12, l12b, nullptr, nullptr, nullptr, l1p, conv + s);
    else if (b < 512)
        conv_body<HIDc, Z2c, 8, 16, 2, false, false, 3>(smem, b - 256, g2, nullptr,
            wt_l22, l22b, nullptr, nullptr, nullptr, l2p, conv + s);
    else
        finalize_body(smem, pF, p1, p2, prevE, aerr, conv, iters, s);
}

// Tail B: e2->out(256) || e1->out(256) || copysq l1(1024) || copysq l2(512) -> 2048
__global__ __launch_bounds__(256) void tailB_k(const float* trans, const float* wt_p2,
                                               const float* p2_b, const float* l2p,
                                               float* o_e2, float* p2,
                                               const float* upl, const float* wt_p1,
                                               const float* p1_b, const float* l1p,
                                               float* o_e1, float* p1,
                                               float* o_l1, float* pL1,
                                               float* o_l2, float* pL2) {
    __shared__ __align__(16) char smem[SMEM_MAX];
    const int b = blockIdx.x;
    if (b < 256)
        conv_body<Z2c, Z2c, 8, 16, 2, false, false, 2>(smem, b, trans, nullptr,
            wt_p2, p2_b, l2p, o_e2, p2, nullptr, nullptr);
    else if (b < 512)
        conv_body<Z1c, Z1c, 16, 16, 4, false, false, 2>(smem, b - 256, upl, nullptr,
            wt_p1, p1_b, l1p, o_e1, p1, nullptr, nullptr);
    else if (b < 512 + GL1)
        copysq4_body(smem, b - 512, l1p, o_l1, pL1);
    else
        copysq4_body(smem, b - 512 - GL1, l2p, o_l2, pL2);
}

__global__ __launch_bounds__(256) void tail_k(const float* __restrict__ pF,
                                              const float* __restrict__ p1,
                                              const float* __restrict__ p2,
                                              const float* __restrict__ pL1,
                                              const float* __restrict__ pL2,
                                              const float* __restrict__ all_err,
                                              const int* __restrict__ iters,
                                              float* __restrict__ out_sc) {
    __shared__ float sd[5 * 256];
    float aF = 0.f, a1 = 0.f, a2 = 0.f, aL1 = 0.f, aL2 = 0.f;
    for (int i = threadIdx.x; i < GF; i += 256) aF += pF[i];
    for (int i = threadIdx.x; i < G1; i += 256) a1 += p1[i];
    for (int i = threadIdx.x; i < G2; i += 256) a2 += p2[i];
    for (int i = threadIdx.x; i < GL1; i += 256) aL1 += pL1[i];
    for (int i = threadIdx.x; i < GL2; i += 256) aL2 += pL2[i];
    sd[threadIdx.x] = aF;
    sd[256 + threadIdx.x] = a1;
    sd[512 + threadIdx.x] = a2;
    sd[768 + threadIdx.x] = aL1;
    sd[1024 + threadIdx.x] = aL2;
    __syncthreads();
#pragma unroll
    for (int off = 128; off > 0; off >>= 1) {
        if (threadIdx.x < off) {
            sd[threadIdx.x] += sd[threadIdx.x + off];
            sd[256 + threadIdx.x] += sd[256 + threadIdx.x + off];
            sd[512 + threadIdx.x] += sd[512 + threadIdx.x + off];
            sd[768 + threadIdx.x] += sd[768 + threadIdx.x + off];
            sd[1024 + threadIdx.x] += sd[1024 + threadIdx.x + off];
        }
        __syncthreads();
    }
    if (threadIdx.x == 0) {
        const float eF  = sd[0] / (float)N_FR;
        const float e1  = 0.1f * (sd[256] / (float)N_L1);
        const float e2  = 0.1f * (sd[512] / (float)N_L2);
        const float reg = 1e-4f * (sd[768] / (float)N_L1 + sd[1024] / (float)N_L2);
        out_sc[0] = eF + e1 + e2 + reg;
        out_sc[1] = eF;
        out_sc[2] = e1;
        out_sc[3] = e2;
        out_sc[16] = (float)iters[12];
    }
    if (threadIdx.x < 12) out_sc[4 + threadIdx.x] = all_err[threadIdx.x];
}

// ---------------- host launch ----------------
extern "C" void kernel_launch(void* const* d_in, const int* in_sizes, int n_in,
                              void* d_out, int out_size, void* d_ws, size_t ws_size,
                              hipStream_t stream) {
    const float* frame_cur = (const float*)d_in[0];
    const float* frame_nxt = (const float*)d_in[1];
    const float* enc_w = (const float*)d_in[2];
    const float* enc_b = (const float*)d_in[3];
    const float* dec_w = (const float*)d_in[4];
    const float* dec_b = (const float*)d_in[5];
    const float* dn_w  = (const float*)d_in[6];
    const float* dn_b  = (const float*)d_in[7];
    const float* up_w  = (const float*)d_in[8];
    const float* up_b  = (const float*)d_in[9];
    const float* tr_w  = (const float*)d_in[10];
    const float* tr_b  = (const float*)d_in[11];
    const float* p1_w  = (const float*)d_in[12];
    const float* p1_b  = (const float*)d_in[13];
    const float* p2_w  = (const float*)d_in[14];
    const float* p2_b  = (const float*)d_in[15];
    const float* l11w  = (const float*)d_in[16];
    const float* l11b  = (const float*)d_in[17];
    const float* l12w  = (const float*)d_in[18];
    const float* l12b  = (const float*)d_in[19];
    const float* l21w  = (const float*)d_in[20];
    const float* l21b  = (const float*)d_in[21];
    const float* l22w  = (const float*)d_in[22];
    const float* l22b  = (const float*)d_in[23];

    // workspace layout (floats)
    float* ws = (float*)d_ws;
    float* l1p   = ws;               // N_L1
    float* l2p   = l1p + N_L1;       // N_L2
    float* l2i   = l2p + N_L2;       // N_L2
    float* ef    = l2i + N_L2;       // N_FR
    float* trans = ef + N_FR;        // N_L2
    float* e2    = trans + N_L2;     // N_L2
    float* upl   = e2 + N_L2;        // N_L1
    float* e1    = upl + N_L1;       // N_L1
    float* bu    = e1 + N_L1;        // N_L1
    float* g1    = bu + N_L1;        // N_G1
    float* g2    = g1 + N_G1;        // N_G2
    float* pF    = g2 + N_G2;        // 4096
    float* p1    = pF + 4096;        // 4096
    float* p2    = p1 + 4096;        // 4096
    float* pL1   = p2 + 4096;        // 4096
    float* pL2   = pL1 + 4096;       // 4096
    float* we    = pL2 + 4096;       // 12288
    float* wt_tr  = we + 12288;       // 147456
    float* wt_p2  = wt_tr + 147456;   // 147456
    float* wt_up  = wt_p2 + 147456;   // 73728
    float* wt_p1  = wt_up + 73728;    // 36864
    float* wt_l11 = wt_p1 + 36864;    // 73728
    float* wt_l12 = wt_l11 + 73728;   // 73728
    float* wt_l21 = wt_l12 + 73728;   // 147456
    float* wt_l22 = wt_l21 + 147456;  // 147456
    float* prevE = wt_l22 + 147456;   // 16
    float* aerr  = prevE + 16;        // 16
    int*   conv  = (int*)(aerr + 16);
    int*   iters = conv + 16;

    // output layout (reference return order)
    float* o_fp = (float*)d_out;
    float* o_l1 = o_fp + N_FR;
    float* o_l2 = o_l1 + N_L1;
    float* o_ef = o_l2 + N_L2;
    float* o_e1 = o_ef + N_FR;
    float* o_e2 = o_e1 + N_L1;
    float* o_sc = o_e2 + N_L2;

    prep_k<<<3325, 256, 0, stream>>>(dec_w, we, tr_w, wt_tr, p2_w, wt_p2, up_w, wt_up,
                                     p1_w, wt_p1, l11w, wt_l11, l12w, wt_l12,
                                     l21w, wt_l21, l22w, wt_l22, prevE, conv, iters);
    encode_g<<<256, 256, 0, stream>>>(frame_cur, enc_w, enc_b, l1p);
    down_k<<<GRID_DOWN, 256, 0, stream>>>(l1p, dn_w, dn_b, l2i, l2p);

    for (int s = 0; s < MAXS; ++s) {
        phaseA_k<false><<<704, 256, 0, stream>>>(l1p, we, dec_b, frame_nxt, ef, nullptr,
                                                 pF, l2p, wt_tr, tr_b, trans,
                                                 l2p, wt_up, up_b, upl);
        phaseB_k<<<768, 256, 0, stream>>>(trans, wt_p2, p2_b, l2p, e2, p2,
                                          upl, wt_p1, p1_b, l1p, e1, p1,
                                          ef, enc_w, enc_b, bu);
        phaseC_k<<<768, 256, 0, stream>>>(e1, bu, wt_l11, l11b, g1,
                                          e2, wt_l21, l21b, g2);
        phaseD_k<<<513, 256, 0, stream>>>(g1, wt_l12, l12b, l1p,
                                          g2, wt_l22, l22b, l2p,
                                          pF, p1, p2, prevE, aerr, conv, iters, s);
    }

    // ---- tail (latent2_hat uses INITIAL latent2 = l2i) ----
    phaseA_k<true><<<704, 256, 0, stream>>>(l1p, we, dec_b, frame_nxt, o_ef, o_fp,
                                            pF, l2i, wt_tr, tr_b, trans,
                                            l2p, wt_up, up_b, upl);
    tailB_k<<<512 + GL1 + GL2, 256, 0, stream>>>(trans, wt_p2, p2_b, l2p, o_e2, p2,
                                                 upl, wt_p1, p1_b, l1p, o_e1, p1,
                                                 o_l1, pL1, o_l2, pL2);
    tail_k<<<1, 256, 0, stream>>>(pF, p1, p2, pL1, pL2, aerr, iters, o_sc);
}